// Round 13
// baseline (4756.467 us; speedup 1.0000x reference)
//
#include <hip/hip_runtime.h>
#include <hip/hip_bf16.h>

#define S_ 64
#define T_ 64
#define B_ 32
#define E_ 512
#define H_ 1024
#define V_ 32000
#define H3 3072
#define H2 2048
#define EH 1536

typedef unsigned short u16;
typedef unsigned int u32;
typedef unsigned long long u64;
typedef __attribute__((ext_vector_type(8))) short bf16x8;
typedef __attribute__((ext_vector_type(4))) float f32x4;

#define MFMA3(ACC, AH_, AL_, BH_, BL_)                                              \
    ACC = __builtin_amdgcn_mfma_f32_16x16x32_bf16(AL_, BH_, ACC, 0, 0, 0);          \
    ACC = __builtin_amdgcn_mfma_f32_16x16x32_bf16(AH_, BL_, ACC, 0, 0, 0);          \
    ACC = __builtin_amdgcn_mfma_f32_16x16x32_bf16(AH_, BH_, ACC, 0, 0, 0);

__device__ __forceinline__ void splitf(float x, u16& h, u16& l) {
    u32 xb = __float_as_uint(x);
    u32 hb = (xb + 0x7FFFu + ((xb >> 16) & 1u)) & 0xFFFF0000u;  // RNE bf16 (as f32 bits)
    h = (u16)(hb >> 16);
    float lf = x - __uint_as_float(hb);                          // exact residual
    u32 lb = __float_as_uint(lf);
    l = (u16)((lb + 0x7FFFu + ((lb >> 16) & 1u)) >> 16);
}

__device__ __forceinline__ float bf2f(u16 v) { return __uint_as_float(((u32)v) << 16); }

__device__ __forceinline__ void load_lds16(const void* g, void* l) {
    __builtin_amdgcn_global_load_lds((const __attribute__((address_space(1))) u32*)g,
                                     (__attribute__((address_space(3))) u32*)l, 16, 0, 0);
}

// ---- system-scope (coherence-point) accessors: bypass L1/L2, no fences needed ----
__device__ __forceinline__ bf16x8 ld_sys16(const u16* p) {
    union { bf16x8 v; u64 q[2]; } u;
    const u64* q = (const u64*)p;
    u.q[0] = __hip_atomic_load(q,     __ATOMIC_RELAXED, __HIP_MEMORY_SCOPE_SYSTEM);
    u.q[1] = __hip_atomic_load(q + 1, __ATOMIC_RELAXED, __HIP_MEMORY_SCOPE_SYSTEM);
    return u.v;
}
__device__ __forceinline__ float ld_sysf(const float* p) {
    return __hip_atomic_load(p, __ATOMIC_RELAXED, __HIP_MEMORY_SCOPE_SYSTEM);
}
__device__ __forceinline__ void st_sysf(float* p, float v) {
    __hip_atomic_store(p, v, __ATOMIC_RELAXED, __HIP_MEMORY_SCOPE_SYSTEM);
}
__device__ __forceinline__ void st_sysu16(u16* p, u16 v) {
    __hip_atomic_store(p, v, __ATOMIC_RELAXED, __HIP_MEMORY_SCOPE_SYSTEM);
}

// Fence-free grid barrier (R11-proven: ~4us). Cross-block data moves via sc0sc1
// system accessors so no L2 flush/invalidate is needed at the barrier.
__device__ __forceinline__ void gbar(int* cnt, int* flag, int nblk, int blk, int& gen) {
    __syncthreads();
    if (threadIdx.x == 0) {
        gen += 1;
        asm volatile("s_waitcnt vmcnt(0)" ::: "memory");
        __hip_atomic_fetch_add(&cnt[(blk & 7) << 5], 1, __ATOMIC_RELAXED,
                               __HIP_MEMORY_SCOPE_SYSTEM);
        if (blk == 0) {
            const int target = nblk * gen;
            for (;;) {
                int sum = 0;
#pragma unroll
                for (int j = 0; j < 8; ++j)
                    sum += __hip_atomic_load(&cnt[j << 5], __ATOMIC_RELAXED,
                                             __HIP_MEMORY_SCOPE_SYSTEM);
                if (sum >= target) break;
                __builtin_amdgcn_s_sleep(2);
            }
#pragma unroll
            for (int j = 0; j < 8; ++j)
                __hip_atomic_store(&flag[j << 5], gen, __ATOMIC_RELAXED,
                                   __HIP_MEMORY_SCOPE_SYSTEM);
        } else {
            while (__hip_atomic_load(&flag[(blk & 7) << 5], __ATOMIC_RELAXED,
                                     __HIP_MEMORY_SCOPE_SYSTEM) < gen)
                __builtin_amdgcn_s_sleep(2);
        }
    }
    __syncthreads();
}

// ---------------- embedding gather + split ----------------
__global__ void k_embed_src_split(const int* __restrict__ src, const float* __restrict__ emb,
                                  u16* __restrict__ hi, u16* __restrict__ lo) {
    int row = blockIdx.x;              // s*B + b
    int tok = src[row];
    int c = threadIdx.x * 4;
    float4 v = *reinterpret_cast<const float4*>(emb + (size_t)tok * E_ + c);
    ushort4 h, l;
    splitf(v.x, h.x, l.x); splitf(v.y, h.y, l.y);
    splitf(v.z, h.z, l.z); splitf(v.w, h.w, l.w);
    *reinterpret_cast<ushort4*>(hi + (size_t)row * E_ + c) = h;
    *reinterpret_cast<ushort4*>(lo + (size_t)row * E_ + c) = l;
}

__global__ void k_embed_dec_split(const int* __restrict__ src, const int* __restrict__ trg,
                                  const float* __restrict__ emb,
                                  u16* __restrict__ hi, u16* __restrict__ lo) {
    int row = blockIdx.x;              // t*B + b
    int t = row >> 5, b = row & 31;
    int tok = (t == 0) ? src[(S_ - 1) * B_ + b] : trg[(t - 1) * B_ + b];
    int c = threadIdx.x * 4;
    float4 v = *reinterpret_cast<const float4*>(emb + (size_t)tok * E_ + c);
    ushort4 h, l;
    splitf(v.x, h.x, l.x); splitf(v.y, h.y, l.y);
    splitf(v.z, h.z, l.z); splitf(v.w, h.w, l.w);
    *reinterpret_cast<ushort4*>(hi + (size_t)row * E_ + c) = h;
    *reinterpret_cast<ushort4*>(lo + (size_t)row * E_ + c) = l;
}

// ---------------- generic f32 -> bf16 hi/lo split ----------------
__global__ __launch_bounds__(256) void k_split(const float* __restrict__ in, int ld, int cols4,
                                               u16* __restrict__ hi, u16* __restrict__ lo) {
    int c4 = blockIdx.x * 256 + threadIdx.x;
    if (c4 >= cols4) return;
    size_t r = blockIdx.y;
    float4 v = *reinterpret_cast<const float4*>(in + r * ld + (size_t)c4 * 4);
    ushort4 h, l;
    splitf(v.x, h.x, l.x); splitf(v.y, h.y, l.y);
    splitf(v.z, h.z, l.z); splitf(v.w, h.w, l.w);
    size_t o = (r * cols4 + c4) * 4;
    *reinterpret_cast<ushort4*>(hi + o) = h;
    *reinterpret_cast<ushort4*>(lo + o) = l;
}

// ---------------- enc = enc_f + enc_b, plus split ----------------
__global__ __launch_bounds__(256) void k_split_sum_enc(
    const float* __restrict__ ef, const float* __restrict__ eb, float* __restrict__ es,
    u16* __restrict__ hi, u16* __restrict__ lo) {
    size_t r = blockIdx.y;
    int c4 = threadIdx.x * 4;
    float4 va = *reinterpret_cast<const float4*>(ef + r * H_ + c4);
    float4 vb = *reinterpret_cast<const float4*>(eb + r * H_ + c4);
    float4 v; v.x = va.x + vb.x; v.y = va.y + vb.y; v.z = va.z + vb.z; v.w = va.w + vb.w;
    *reinterpret_cast<float4*>(es + r * H_ + c4) = v;
    ushort4 h, l;
    splitf(v.x, h.x, l.x); splitf(v.y, h.y, l.y);
    splitf(v.z, h.z, l.z); splitf(v.w, h.w, l.w);
    *reinterpret_cast<ushort4*>(hi + r * H_ + c4) = h;
    *reinterpret_cast<ushort4*>(lo + r * H_ + c4) = l;
}

// ---------------- gate-interleaved weight split: dst row 3i+g = src row g*1024+i ----------------
__global__ void k_wsplit_perm(const float* __restrict__ src, int ld, int coff,
                              u16* __restrict__ hi, u16* __restrict__ lo) {
    int r = blockIdx.x;                // permuted row: 3i+g
    int i = r / 3, g = r - i * 3;
    const float* p = src + (size_t)(g * H_ + i) * ld + coff;
    int c = threadIdx.x * 4;
    float4 v = *reinterpret_cast<const float4*>(p + c);
    ushort4 h, l;
    splitf(v.x, h.x, l.x); splitf(v.y, h.y, l.y);
    splitf(v.z, h.z, l.z); splitf(v.w, h.w, l.w);
    *reinterpret_cast<ushort4*>(hi + (size_t)r * H_ + c) = h;
    *reinterpret_cast<ushort4*>(lo + (size_t)r * H_ + c) = l;
}

// ---------------- big split-bf16 MFMA GEMM (proven R2-R11) ----------------
__global__ __launch_bounds__(256, 2) void k_gemm_mfma3(
    const u16* __restrict__ Ah, const u16* __restrict__ Al,
    const u16* __restrict__ Bh, const u16* __restrict__ Bl,
    const float* __restrict__ bias, float* __restrict__ C,
    int ldc, int K)
{
    __shared__ u16 ls[4][128 * 32];
    const int tid = threadIdx.x;
    const int lane = tid & 63, w = tid >> 6;
    const int wr = w >> 1, wc = w & 1;
    const size_t m0 = (size_t)blockIdx.x * 128, n0 = (size_t)blockIdx.y * 128;

    const int c0 = (w * 2) * 64 + lane;
    const int r0 = c0 >> 2, kc0 = (c0 & 3) << 3;
    const size_t rstep = (size_t)16 * K;
    const u16* gAh = Ah + (m0 + r0) * K + kc0;
    const u16* gAl = Al + (m0 + r0) * K + kc0;
    const u16* gBh = Bh + (n0 + r0) * K + kc0;
    const u16* gBl = Bl + (n0 + r0) * K + kc0;
    const int lo0 = c0 * 8;

    const int frow = lane & 15, fk = (lane >> 4) << 3;
    const int offA = (wr * 64 + frow) * 32 + fk;
    const int offB = (wc * 64 + frow) * 32 + fk;

    f32x4 acc[4][4] = {};

    for (int k0 = 0; k0 < K; k0 += 32) {
        load_lds16(gAh + k0, &ls[0][lo0]);
        load_lds16(gAh + rstep + k0, &ls[0][lo0 + 512]);
        load_lds16(gAl + k0, &ls[1][lo0]);
        load_lds16(gAl + rstep + k0, &ls[1][lo0 + 512]);
        load_lds16(gBh + k0, &ls[2][lo0]);
        load_lds16(gBh + rstep + k0, &ls[2][lo0 + 512]);
        load_lds16(gBl + k0, &ls[3][lo0]);
        load_lds16(gBl + rstep + k0, &ls[3][lo0 + 512]);
        __syncthreads();

        bf16x8 fAh[4], fAl[4], fBh[4], fBl[4];
#pragma unroll
        for (int m = 0; m < 4; ++m) {
            fAh[m] = *reinterpret_cast<const bf16x8*>(&ls[0][offA + m * 512]);
            fAl[m] = *reinterpret_cast<const bf16x8*>(&ls[1][offA + m * 512]);
        }
#pragma unroll
        for (int n = 0; n < 4; ++n) {
            fBh[n] = *reinterpret_cast<const bf16x8*>(&ls[2][offB + n * 512]);
            fBl[n] = *reinterpret_cast<const bf16x8*>(&ls[3][offB + n * 512]);
        }
#pragma unroll
        for (int m = 0; m < 4; ++m)
#pragma unroll
            for (int n = 0; n < 4; ++n) {
                MFMA3(acc[m][n], fAh[m], fAl[m], fBh[n], fBl[n]);
            }
        __syncthreads();
    }

    const int crow0 = wr * 64 + ((lane >> 4) << 2);
    const int ccol0 = wc * 64 + (lane & 15);
#pragma unroll
    for (int n = 0; n < 4; ++n) {
        const size_t col = n0 + ccol0 + n * 16;
        const float bv = bias ? bias[col] : 0.f;
#pragma unroll
        for (int m = 0; m < 4; ++m)
#pragma unroll
            for (int r = 0; r < 4; ++r)
                C[(m0 + crow0 + m * 16 + r) * (size_t)ldc + col] = acc[m][n][r] + bv;
    }
}

// ---------------- head GEMM: 128x256 tile (proven R11) ----------------
__global__ __launch_bounds__(256, 2) void k_gemm_mfma3_n2(
    const u16* __restrict__ Ah, const u16* __restrict__ Al,
    const u16* __restrict__ Bh, const u16* __restrict__ Bl,
    const float* __restrict__ bias, float* __restrict__ C,
    int ldc, int K)
{
    __shared__ u16 lsA[2][128 * 32];
    __shared__ u16 lsB[2][256 * 32];
    const int tid = threadIdx.x;
    const int lane = tid & 63, w = tid >> 6;
    const int wr = w >> 1, wc = w & 1;
    const size_t m0 = (size_t)blockIdx.x * 128, n0 = (size_t)blockIdx.y * 256;

    const int frow = lane & 15, fk = (lane >> 4) << 3;
    const int offA = (wr * 64 + frow) * 32 + fk;
    const int offB = (wc * 128 + frow) * 32 + fk;

    f32x4 acc[4][8] = {};

    for (int k0 = 0; k0 < K; k0 += 32) {
#pragma unroll
        for (int q = 0; q < 12; ++q) {
            const int chunk = (w + q * 4) * 64 + lane;
            const u16* gsrc; u16* ldst;
            if (chunk < 1024) {
                const int local = chunk & 511;
                const u16* A = (chunk < 512) ? Ah : Al;
                gsrc = A + (m0 + (local >> 2)) * K + k0 + ((local & 3) << 3);
                ldst = &lsA[chunk >> 9][local * 8];
            } else {
                const int c2 = chunk - 1024;
                const int local = c2 & 1023;
                const u16* B = (c2 < 1024) ? Bh : Bl;
                gsrc = B + (n0 + (local >> 2)) * K + k0 + ((local & 3) << 3);
                ldst = &lsB[c2 >> 10][local * 8];
            }
            load_lds16(gsrc, ldst);
        }
        __syncthreads();

        bf16x8 fAh[4], fAl[4];
#pragma unroll
        for (int m = 0; m < 4; ++m) {
            fAh[m] = *reinterpret_cast<const bf16x8*>(&lsA[0][offA + m * 512]);
            fAl[m] = *reinterpret_cast<const bf16x8*>(&lsA[1][offA + m * 512]);
        }
#pragma unroll
        for (int n = 0; n < 8; ++n) {
            bf16x8 fBh = *reinterpret_cast<const bf16x8*>(&lsB[0][offB + n * 512]);
            bf16x8 fBl = *reinterpret_cast<const bf16x8*>(&lsB[1][offB + n * 512]);
#pragma unroll
            for (int m = 0; m < 4; ++m) {
                MFMA3(acc[m][n], fAh[m], fAl[m], fBh, fBl);
            }
        }
        __syncthreads();
    }

    const int crow0 = wr * 64 + ((lane >> 4) << 2);
    const int ccol0 = wc * 128 + (lane & 15);
#pragma unroll
    for (int n = 0; n < 8; ++n) {
        const size_t col = n0 + ccol0 + n * 16;
        const float bv = bias ? bias[col] : 0.f;
#pragma unroll
        for (int m = 0; m < 4; ++m)
#pragma unroll
            for (int r = 0; r < 4; ++r)
                C[(m0 + crow0 + m * 16 + r) * (size_t)ldc + col] = acc[m][n][r] + bv;
    }
}

// ================= persistent encoder (R9/R11, proven) =================
__global__ __launch_bounds__(256) void k_enc_persist(
    const u16* __restrict__ whhf_h, const u16* __restrict__ whhf_l,
    const u16* __restrict__ whhb_h, const u16* __restrict__ whhb_l,
    const float* __restrict__ gi_f, const float* __restrict__ gi_b,
    const float* __restrict__ bhh_f, const float* __restrict__ bhh_b,
    u16* __restrict__ hfH0, u16* __restrict__ hfL0,
    u16* __restrict__ hfH1, u16* __restrict__ hfL1,
    u16* __restrict__ hbH0, u16* __restrict__ hbL0,
    u16* __restrict__ hbH1, u16* __restrict__ hbL1,
    float* __restrict__ enc_f, float* __restrict__ enc_b,
    int* __restrict__ cnt, int* __restrict__ flag)
{
    __shared__ __align__(16) char smem[145792];
    u16* lAh  = (u16*)smem;                    // [32][1024] staged h hi, XOR-swizzled
    u16* lAl  = (u16*)(smem + 65536);          // lo
    float* ex0 = (float*)(smem + 131072);      // [48][33] k-half 0
    float* ex1 = (float*)(smem + 137408);      // [48][33] k-half 1
    float* hloc = (float*)(smem + 143744);     // [32][16] f32 state

    const int blk = blockIdx.x, tid = threadIdx.x;
    const int lane = tid & 63, w = tid >> 6;
    const int dir = blk >> 6, c = blk & 63;
    const int i0 = c * 16;
    const u16* WH = (dir ? whhb_h : whhf_h) + (size_t)c * 48 * 1024;
    const u16* WL = (dir ? whhb_l : whhf_l) + (size_t)c * 48 * 1024;
    const float* gi = dir ? gi_b : gi_f;
    const float* bhh = dir ? bhh_b : bhh_f;
    float* encd = dir ? enc_b : enc_f;
    int gen = 0;

    for (int q = tid; q < 512; q += 256) hloc[q] = 0.f;

    const int frow = lane & 15, fk8 = (lane >> 4) << 3;
    const int cb = lane & 15, rb0 = (lane >> 4) << 2;

    for (int t = 0; t < 64; ++t) {
        const int a = t & 1;
        const u16* rH = dir ? (a ? hbH1 : hbH0) : (a ? hfH1 : hfH0);
        const u16* rL = dir ? (a ? hbL1 : hbL0) : (a ? hfL1 : hfL0);
        u16* oH = dir ? (a ? hbH0 : hbH1) : (a ? hfH0 : hfH1);
        u16* oL = dir ? (a ? hbL0 : hbL1) : (a ? hfL0 : hfL1);
        const int s = dir ? 63 - t : t;

#pragma unroll
        for (int ch0 = 0; ch0 < 4096; ch0 += 256) {
            int ch = ch0 + tid;
            int r = ch >> 7, kc = (ch & 127) << 3;
            int sw = kc ^ ((r & 7) << 3);
            *(bf16x8*)&lAh[r * 1024 + sw] = ld_sys16(&rH[r * 1024 + kc]);
            *(bf16x8*)&lAl[r * 1024 + sw] = ld_sys16(&rL[r * 1024 + kc]);
        }
        __syncthreads();

#pragma unroll
        for (int jj = 0; jj < 3; ++jj) {
            const int j = w * 3 + jj;
            const int m = j & 1;
            const int n = (j >> 1) % 3;
            const int kh = j / 6;
            const int arow = m * 16 + frow;
            const int asw = (arow & 7) << 3;
            const u16* gBh = WH + (size_t)(n * 16 + frow) * 1024;
            const u16* gBl = WL + (size_t)(n * 16 + frow) * 1024;
            f32x4 acc = {};
            const int ke = kh * 512 + 512;
#pragma unroll 4
            for (int k0 = kh * 512; k0 < ke; k0 += 32) {
                int kc = k0 + fk8;
                bf16x8 aH = *(const bf16x8*)&lAh[arow * 1024 + (kc ^ asw)];
                bf16x8 aL = *(const bf16x8*)&lAl[arow * 1024 + (kc ^ asw)];
                bf16x8 bH = *(const bf16x8*)&gBh[kc];
                bf16x8 bL = *(const bf16x8*)&gBl[kc];
                MFMA3(acc, aH, aL, bH, bL);
            }
            float* exd = kh ? ex1 : ex0;
            const int pc = n * 16 + cb;
#pragma unroll
            for (int r = 0; r < 4; ++r)
                exd[pc * 33 + m * 16 + rb0 + r] = acc[r];
        }
        __syncthreads();

        {
            const int il = tid & 15, bb = tid >> 4;
            const int i = i0 + il;
#pragma unroll
            for (int q = 0; q < 2; ++q) {
                int b = bb + q * 16;
                float ghr = ex0[(3 * il + 0) * 33 + b] + ex1[(3 * il + 0) * 33 + b] + bhh[i];
                float ghz = ex0[(3 * il + 1) * 33 + b] + ex1[(3 * il + 1) * 33 + b] + bhh[H_ + i];
                float ghn = ex0[(3 * il + 2) * 33 + b] + ex1[(3 * il + 2) * 33 + b] + bhh[2 * H_ + i];
                size_t gio = (size_t)(s * B_ + b) * H3 + i;
                float gir = gi[gio], giz = gi[gio + H_], gin = gi[gio + 2 * H_];
                float rr = 1.f / (1.f + expf(-(gir + ghr)));
                float zz = 1.f / (1.f + expf(-(giz + ghz)));
                float nn = tanhf(gin + rr * ghn);
                float hold = hloc[b * 16 + il];
                float hnew = (1.f - zz) * nn + zz * hold;
                hloc[b * 16 + il] = hnew;
                u16 hh, hl; splitf(hnew, hh, hl);
                st_sysu16(&oH[b * 1024 + i], hh);
                st_sysu16(&oL[b * 1024 + i], hl);
                encd[((size_t)b * 64 + s) * H_ + i] = hnew;
            }
        }
        gbar(cnt, flag, 128, blk, gen);
    }
}

// ================= persistent decoder R13: 3 barriers/step (PhB+PhC merged) =================
// Block bid: b3=bid>>3, sl=bid&7, owns units bid*4..+4. Each block computes ALL 64
// scores for its b3 locally (8x redundant, ep is L2-cached read-only) -> no scores
// round-trip, no BAR between scores and softmax/ctx.
__global__ __launch_bounds__(256) void k_dec_persist(
    const u16* __restrict__ wah, const u16* __restrict__ wal,
    const u16* __restrict__ wgh, const u16* __restrict__ wgl,
    const u16* __restrict__ wdh, const u16* __restrict__ wdl,
    const float* __restrict__ gi_e, const float* __restrict__ bhh_d,
    const float* __restrict__ ep, const float* __restrict__ vvec,
    const float* __restrict__ enc,
    u16* __restrict__ hH, u16* __restrict__ hL,
    float* __restrict__ hwa,
    u16* __restrict__ ctxH, u16* __restrict__ ctxL,
    float* __restrict__ states, int* __restrict__ cnt, int* __restrict__ flag)
{
    __shared__ __align__(16) char smem[140288];
    u16* lWH  = (u16*)smem;                    // [16][1024] rows 0-3 hWa, 4-15 ghd (swizzled)
    u16* lWL  = (u16*)(smem + 32768);
    u16* lDH  = (u16*)(smem + 65536);          // [16][1024] wdc hi (12 + 4 pad)
    float* lenc = (float*)(smem + 98304);      // [64][128]
    float* ex1a = (float*)(smem + 131072);     // [32][16] PhA partial (k-half 0)
    float* ex1b = (float*)(smem + 133120);
    float* ex2a = (float*)(smem + 135168);     // PhD partials
    float* ex2b = (float*)(smem + 137216);
    float* aw   = (float*)(smem + 139264);     // [64] softmax weights
    float* hloc = (float*)(smem + 139520);     // [128] f32 state for owned (b,u)
    float* al   = (float*)(smem + 140032);     // [64] raw scores

    const int bid = blockIdx.x, tid = threadIdx.x;
    const int lane = tid & 63, w = tid >> 6;
    const int frow = lane & 15, fk8 = (lane >> 4) << 3;
    const int b3 = bid >> 3, sl = bid & 7;
    int gen = 0;

    for (int ch = tid; ch < 2048; ch += 256) {
        int r = ch >> 7, kc = (ch & 127) << 3;
        int sw = kc ^ ((r & 7) << 3);
        const u16 *sH, *sL;
        if (r < 4) { sH = wah + ((size_t)bid * 4 + r) * 1024;
                     sL = wal + ((size_t)bid * 4 + r) * 1024; }
        else       { sH = wgh + ((size_t)bid * 12 + r - 4) * 1024;
                     sL = wgl + ((size_t)bid * 12 + r - 4) * 1024; }
        *(bf16x8*)&lWH[r * 1024 + sw] = *(const bf16x8*)&sH[kc];
        *(bf16x8*)&lWL[r * 1024 + sw] = *(const bf16x8*)&sL[kc];
    }
    for (int ch = tid; ch < 2048; ch += 256) {
        int r = ch >> 7, kc = (ch & 127) << 3;
        int sw = kc ^ ((r & 7) << 3);
        int rowg = (r < 12) ? bid * 12 + r : bid * 12;
        *(bf16x8*)&lDH[r * 1024 + sw] = *(const bf16x8*)&wdh[(size_t)rowg * 1024 + kc];
    }
    for (int ch = tid; ch < 2048; ch += 256) {
        int s = ch >> 5, c4 = (ch & 31) << 2;
        *(float4*)&lenc[s * 128 + c4] =
            *(const float4*)&enc[((size_t)b3 * 64 + s) * 1024 + sl * 128 + c4];
    }
    if (tid < 128) {
        int b = tid >> 2, u = bid * 4 + (tid & 3);
        hloc[tid] = bf2f(hH[b * 1024 + u]) + bf2f(hL[b * 1024 + u]);
    }
    float vreg[16];
#pragma unroll
    for (int i = 0; i < 16; ++i) vreg[i] = vvec[lane + i * 64];
    __syncthreads();

    const int mt = w & 1, kh = w >> 1;
    const int bsw = (frow & 7) << 3;
    const int rowg = (frow < 12) ? bid * 12 + frow : bid * 12;
    const u16* gDl = wdl + (size_t)rowg * 1024;
    const int exw = (mt * 16 + ((lane >> 4) << 2)) * 16 + frow;

    for (int t = 0; t < 64; ++t) {
        // ---- PhA: [hWa|ghd](16 cols) = h @ W^T, k-split across wave pairs ----
        {
            float* exA = kh ? ex1b : ex1a;
            f32x4 acc = {};
            const int ar0 = (mt * 16 + frow) * 1024;
            const int ke = kh * 512 + 512;
#pragma unroll 4
            for (int k0 = kh * 512; k0 < ke; k0 += 32) {
                int kc = k0 + fk8;
                bf16x8 aH = ld_sys16(&hH[ar0 + kc]);
                bf16x8 aL = ld_sys16(&hL[ar0 + kc]);
                bf16x8 bH = *(const bf16x8*)&lWH[frow * 1024 + (kc ^ bsw)];
                bf16x8 bL = *(const bf16x8*)&lWL[frow * 1024 + (kc ^ bsw)];
                MFMA3(acc, aH, aL, bH, bL);
            }
#pragma unroll
            for (int r = 0; r < 4; ++r) exA[exw + r * 16] = acc[r];
        }
        __syncthreads();
        if (tid < 128) {
            int b = tid >> 2, col = tid & 3;
            st_sysf(&hwa[b * 1024 + bid * 4 + col],
                    ex1a[b * 16 + col] + ex1b[b * 16 + col]);
        }
        gbar(cnt, flag, 256, bid, gen);   // BAR1: hwa ready

        // ---- PhBC (merged): all 64 scores for b3 + softmax + own ctx slice ----
        {
            float hreg[16];
#pragma unroll
            for (int i = 0; i < 16; ++i)
                hreg[i] = ld_sysf(&hwa[b3 * 1024 + lane + i * 64]);
            for (int ii = 0; ii < 16; ++ii) {
                int s = w * 16 + ii;
                const float* epr = ep + ((size_t)b3 * 64 + s) * 1024;
                float a2 = 0.f;
#pragma unroll
                for (int i = 0; i < 16; ++i) {
                    int j = lane + i * 64;
                    a2 += fmaxf(hreg[i] + epr[j], 0.f) * vreg[i];
                }
                for (int off = 32; off; off >>= 1) a2 += __shfl_down(a2, off);
                if (lane == 0) al[s] = a2;
            }
        }
        __syncthreads();
        if (tid < 64) {
            float sc = al[tid];
            float m = sc;
            for (int off = 32; off; off >>= 1) m = fmaxf(m, __shfl_xor(m, off));
            float e = expf(sc - m);
            float sum = e;
            for (int off = 32; off; off >>= 1) sum += __shfl_xor(sum, off);
            aw[tid] = e / sum;
        }
        __syncthreads();
        if (tid < 128) {
            int c = tid;
            float x = 0.f;
#pragma unroll 8
            for (int s = 0; s < 64; ++s) x += aw[s] * lenc[s * 128 + c];
            states[((size_t)t * 32 + b3) * 2048 + 1024 + sl * 128 + c] = x;
            u16 hh, hl; splitf(x, hh, hl);
            st_sysu16(&ctxH[b3 * 1024 + sl * 128 + c], hh);
            st_sysu16(&ctxL[b3 * 1024 + sl * 128 + c], hl);
        }
        gbar(cnt, flag, 256, bid, gen);   // BAR2: ctx ready

        // ---- PhD: gic = ctx @ wdc^T (12 cols) + fused GRU gates for owned units ----
        {
            float* exD = kh ? ex2b : ex2a;
            f32x4 acc = {};
            const int ar0 = (mt * 16 + frow) * 1024;
            const int ke = kh * 512 + 512;
#pragma unroll 4
            for (int k0 = kh * 512; k0 < ke; k0 += 32) {
                int kc = k0 + fk8;
                bf16x8 aH = ld_sys16(&ctxH[ar0 + kc]);
                bf16x8 aL = ld_sys16(&ctxL[ar0 + kc]);
                bf16x8 bH = *(const bf16x8*)&lDH[frow * 1024 + (kc ^ bsw)];
                bf16x8 bL = *(const bf16x8*)&gDl[kc];
                MFMA3(acc, aH, aL, bH, bL);
            }
#pragma unroll
            for (int r = 0; r < 4; ++r) exD[exw + r * 16] = acc[r];
        }
        __syncthreads();
        if (tid < 128) {
            int b = tid >> 2, ui = tid & 3;
            int u = bid * 4 + ui;
            float gicr = ex2a[b * 16 + 3 * ui + 0] + ex2b[b * 16 + 3 * ui + 0];
            float gicz = ex2a[b * 16 + 3 * ui + 1] + ex2b[b * 16 + 3 * ui + 1];
            float gicn = ex2a[b * 16 + 3 * ui + 2] + ex2b[b * 16 + 3 * ui + 2];
            float ghr = ex1a[b * 16 + 4 + 3 * ui + 0] + ex1b[b * 16 + 4 + 3 * ui + 0] + bhh_d[u];
            float ghz = ex1a[b * 16 + 4 + 3 * ui + 1] + ex1b[b * 16 + 4 + 3 * ui + 1] + bhh_d[H_ + u];
            float ghn = ex1a[b * 16 + 4 + 3 * ui + 2] + ex1b[b * 16 + 4 + 3 * ui + 2] + bhh_d[2 * H_ + u];
            size_t ge = ((size_t)t * 32 + b) * 3072;
            float gir = gi_e[ge + u] + gicr;
            float giz = gi_e[ge + 1024 + u] + gicz;
            float gin = gi_e[ge + 2048 + u] + gicn;
            float rr = 1.f / (1.f + expf(-(gir + ghr)));
            float zz = 1.f / (1.f + expf(-(giz + ghz)));
            float nn = tanhf(gin + rr * ghn);
            float hold = hloc[tid];
            float hnew = (1.f - zz) * nn + zz * hold;
            hloc[tid] = hnew;
            u16 hh, hl; splitf(hnew, hh, hl);
            st_sysu16(&hH[b * 1024 + u], hh);
            st_sysu16(&hL[b * 1024 + u], hl);
            states[((size_t)t * 32 + b) * 2048 + u] = hnew;
        }
        gbar(cnt, flag, 256, bid, gen);   // BAR3: h ready
    }
}

extern "C" void kernel_launch(void* const* d_in, const int* in_sizes, int n_in,
                              void* d_out, int out_size, void* d_ws, size_t ws_size,
                              hipStream_t stream) {
    const int*   src   = (const int*)d_in[0];
    const int*   trg   = (const int*)d_in[1];
    const float* emb   = (const float*)d_in[2];
    const float* Wih_f = (const float*)d_in[3];
    const float* Whh_f = (const float*)d_in[4];
    const float* bih_f = (const float*)d_in[5];
    const float* bhh_f = (const float*)d_in[6];
    const float* Wih_b = (const float*)d_in[7];
    const float* Whh_b = (const float*)d_in[8];
    const float* bih_b = (const float*)d_in[9];
    const float* bhh_b = (const float*)d_in[10];
    const float* Wa    = (const float*)d_in[11];
    const float* ba    = (const float*)d_in[12];
    const float* vv    = (const float*)d_in[13];
    const float* Wih_d = (const float*)d_in[14];
    const float* Whh_d = (const float*)d_in[15];
    const float* bih_d = (const float*)d_in[16];
    const float* bhh_d = (const float*)d_in[17];
    const float* Wout  = (const float*)d_in[18];
    const float* bout  = (const float*)d_in[19];
    float* out = (float*)d_out;
    (void)in_sizes; (void)n_in; (void)out_size; (void)ws_size;

    float* w = (float*)d_ws;
    size_t o = 0;
    auto alloc = [&](size_t n) { float* p = w + o; o += n; return p; };
    float* gi_f  = alloc((size_t)S_ * B_ * H3);      // encoder fwd gi; reused as gi_e
    float* gi_b  = alloc((size_t)S_ * B_ * H3);      // encoder bwd gi; reused as states
    float* enc_f = alloc((size_t)B_ * S_ * H_);
    float* enc_b = alloc((size_t)B_ * S_ * H_);
    float* enc   = alloc((size_t)B_ * S_ * H_);
    float* ep    = alloc((size_t)B_ * S_ * H_);
    float* hwa   = alloc((size_t)B_ * H_);
    float* barf  = alloc(1024);
    int* cntE  = (int*)barf;
    int* flagE = cntE + 256;
    int* cntD  = cntE + 512;
    int* flagD = cntE + 768;
    float* gi_e   = gi_f;
    float* states = gi_b;

    u16* wu = (u16*)(w + o);
    size_t ou = 0;
    auto alloc16 = [&](size_t n) { u16* p = wu + ou; ou += n; return p; };
    u16* semb_h  = alloc16((size_t)S_ * B_ * E_);  u16* semb_l  = alloc16((size_t)S_ * B_ * E_);
    u16* demb_h  = alloc16((size_t)T_ * B_ * E_);  u16* demb_l  = alloc16((size_t)T_ * B_ * E_);
    u16* wihf_h  = alloc16((size_t)H3 * E_);       u16* wihf_l  = alloc16((size_t)H3 * E_);
    u16* wihb_h  = alloc16((size_t)H3 * E_);       u16* wihb_l  = alloc16((size_t)H3 * E_);
    u16* wihd_h  = alloc16((size_t)H3 * E_);       u16* wihd_l  = alloc16((size_t)H3 * E_);
    u16* wae_h   = alloc16((size_t)H_ * H_);       u16* wae_l   = alloc16((size_t)H_ * H_);
    u16* enc_h   = alloc16((size_t)B_ * S_ * H_);  u16* enc_l   = alloc16((size_t)B_ * S_ * H_);
    u16* st_h    = alloc16((size_t)T_ * B_ * H2);  u16* st_l    = alloc16((size_t)T_ * B_ * H2);
    u16* wout_h  = alloc16((size_t)6400 * H2);     u16* wout_l  = alloc16((size_t)6400 * H2);
    u16* whhf_h  = alloc16((size_t)H3 * H_);       u16* whhf_l  = alloc16((size_t)H3 * H_);
    u16* whhb_h  = alloc16((size_t)H3 * H_);       u16* whhb_l  = alloc16((size_t)H3 * H_);
    u16* wgh     = alloc16((size_t)H3 * H_);       u16* wgl     = alloc16((size_t)H3 * H_);   // Whh_d perm
    u16* wdh     = alloc16((size_t)H3 * H_);       u16* wdl     = alloc16((size_t)H3 * H_);   // Wihd ctx perm
    u16* wah     = alloc16((size_t)H_ * H_);       u16* wal     = alloc16((size_t)H_ * H_);   // Wa h-part
    u16* hsf_h[2] = {alloc16(B_ * H_), alloc16(B_ * H_)};
    u16* hsf_l[2] = {alloc16(B_ * H_), alloc16(B_ * H_)};
    u16* hsb_h[2] = {alloc16(B_ * H_), alloc16(B_ * H_)};
    u16* hsb_l[2] = {alloc16(B_ * H_), alloc16(B_ * H_)};
    u16* ctx_h   = alloc16(B_ * H_);               u16* ctx_l   = alloc16(B_ * H_);

    // ---- init ----
    hipMemsetAsync(barf, 0, 1024 * sizeof(float), stream);
    hipMemsetAsync(hsf_h[0], 0, B_ * H_ * sizeof(u16), stream);
    hipMemsetAsync(hsf_l[0], 0, B_ * H_ * sizeof(u16), stream);
    hipMemsetAsync(hsb_h[0], 0, B_ * H_ * sizeof(u16), stream);
    hipMemsetAsync(hsb_l[0], 0, B_ * H_ * sizeof(u16), stream);

    // ---- embeddings ----
    k_embed_src_split<<<S_ * B_, 128, 0, stream>>>(src, emb, semb_h, semb_l);
    k_embed_dec_split<<<T_ * B_, 128, 0, stream>>>(src, trg, emb, demb_h, demb_l);

    // ---- weight splits ----
    k_split<<<dim3(1, H3), 256, 0, stream>>>(Wih_f, E_, E_ / 4, wihf_h, wihf_l);
    k_split<<<dim3(1, H3), 256, 0, stream>>>(Wih_b, E_, E_ / 4, wihb_h, wihb_l);
    k_split<<<dim3(1, H3), 256, 0, stream>>>(Wih_d, EH, E_ / 4, wihd_h, wihd_l);
    k_split<<<dim3(1, H_), 256, 0, stream>>>(Wa + H_, H2, H_ / 4, wae_h, wae_l);
    k_split<<<dim3(1, H_), 256, 0, stream>>>(Wa, H2, H_ / 4, wah, wal);
    k_wsplit_perm<<<H3, 256, 0, stream>>>(Whh_f, H_, 0, whhf_h, whhf_l);
    k_wsplit_perm<<<H3, 256, 0, stream>>>(Whh_b, H_, 0, whhb_h, whhb_l);
    k_wsplit_perm<<<H3, 256, 0, stream>>>(Whh_d, H_, 0, wgh, wgl);
    k_wsplit_perm<<<H3, 256, 0, stream>>>(Wih_d, EH, E_, wdh, wdl);

    // ---- encoder input projections ----
    k_gemm_mfma3<<<dim3(16, 24), 256, 0, stream>>>(semb_h, semb_l, wihf_h, wihf_l,
                                                   bih_f, gi_f, H3, E_);
    k_gemm_mfma3<<<dim3(16, 24), 256, 0, stream>>>(semb_h, semb_l, wihb_h, wihb_l,
                                                   bih_b, gi_b, H3, E_);

    // ---- encoder: persistent, LDS-staged h ----
    k_enc_persist<<<128, 256, 0, stream>>>(
        whhf_h, whhf_l, whhb_h, whhb_l, gi_f, gi_b, bhh_f, bhh_b,
        hsf_h[0], hsf_l[0], hsf_h[1], hsf_l[1],
        hsb_h[0], hsb_l[0], hsb_h[1], hsb_l[1],
        enc_f, enc_b, cntE, flagE);

    // ---- merge enc dirs + split; ep precompute; decoder emb projection ----
    k_split_sum_enc<<<dim3(1, B_ * S_), 256, 0, stream>>>(enc_f, enc_b, enc, enc_h, enc_l);
    k_gemm_mfma3<<<dim3(16, 8), 256, 0, stream>>>(enc_h, enc_l, wae_h, wae_l,
                                                  ba, ep, H_, H_);
    k_gemm_mfma3<<<dim3(16, 24), 256, 0, stream>>>(demb_h, demb_l, wihd_h, wihd_l,
                                                   bih_d, gi_e, H3, E_);

    // ---- decoder: persistent, 3 barriers/step (R13) ----
    k_dec_persist<<<256, 256, 0, stream>>>(
        wah, wal, wgh, wgl, wdh, wdl, gi_e, bhh_d, ep, vv, enc,
        hsf_h[0], hsf_l[0], hwa, ctx_h, ctx_l, states, cntD, flagD);

    // ---- output head: 5 passes, 128x256-tile head GEMM ----
    k_split<<<dim3(2, T_ * B_), 256, 0, stream>>>(states, H2, H2 / 4, st_h, st_l);
    for (int p = 0; p < 5; ++p) {
        k_split<<<dim3(2, 6400), 256, 0, stream>>>(Wout + (size_t)p * 6400 * H2, H2,
                                                   H2 / 4, wout_h, wout_l);
        k_gemm_mfma3_n2<<<dim3(16, 25), 256, 0, stream>>>(st_h, st_l, wout_h, wout_l,
                                                          bout + p * 6400,
                                                          out + (size_t)p * 6400, V_, H2);
    }
}

// Round 14
// 4280.827 us; speedup vs baseline: 1.1111x; 1.1111x over previous
//
#include <hip/hip_runtime.h>
#include <hip/hip_bf16.h>

#define S_ 64
#define T_ 64
#define B_ 32
#define E_ 512
#define H_ 1024
#define V_ 32000
#define H3 3072
#define H2 2048
#define EH 1536

typedef unsigned short u16;
typedef unsigned int u32;
typedef unsigned long long u64;
typedef __attribute__((ext_vector_type(8))) short bf16x8;
typedef __attribute__((ext_vector_type(4))) float f32x4;

#define MFMA3(ACC, AH_, AL_, BH_, BL_)                                              \
    ACC = __builtin_amdgcn_mfma_f32_16x16x32_bf16(AL_, BH_, ACC, 0, 0, 0);          \
    ACC = __builtin_amdgcn_mfma_f32_16x16x32_bf16(AH_, BL_, ACC, 0, 0, 0);          \
    ACC = __builtin_amdgcn_mfma_f32_16x16x32_bf16(AH_, BH_, ACC, 0, 0, 0);

__device__ __forceinline__ void splitf(float x, u16& h, u16& l) {
    u32 xb = __float_as_uint(x);
    u32 hb = (xb + 0x7FFFu + ((xb >> 16) & 1u)) & 0xFFFF0000u;  // RNE bf16 (as f32 bits)
    h = (u16)(hb >> 16);
    float lf = x - __uint_as_float(hb);                          // exact residual
    u32 lb = __float_as_uint(lf);
    l = (u16)((lb + 0x7FFFu + ((lb >> 16) & 1u)) >> 16);
}

__device__ __forceinline__ float bf2f(u16 v) { return __uint_as_float(((u32)v) << 16); }

__device__ __forceinline__ void load_lds16(const void* g, void* l) {
    __builtin_amdgcn_global_load_lds((const __attribute__((address_space(1))) u32*)g,
                                     (__attribute__((address_space(3))) u32*)l, 16, 0, 0);
}

// ---- system-scope (coherence-point) accessors: bypass L1/L2, no fences needed ----
__device__ __forceinline__ bf16x8 ld_sys16(const u16* p) {
    union { bf16x8 v; u64 q[2]; } u;
    const u64* q = (const u64*)p;
    u.q[0] = __hip_atomic_load(q,     __ATOMIC_RELAXED, __HIP_MEMORY_SCOPE_SYSTEM);
    u.q[1] = __hip_atomic_load(q + 1, __ATOMIC_RELAXED, __HIP_MEMORY_SCOPE_SYSTEM);
    return u.v;
}
__device__ __forceinline__ float ld_sysf(const float* p) {
    return __hip_atomic_load(p, __ATOMIC_RELAXED, __HIP_MEMORY_SCOPE_SYSTEM);
}
__device__ __forceinline__ void st_sysf(float* p, float v) {
    __hip_atomic_store(p, v, __ATOMIC_RELAXED, __HIP_MEMORY_SCOPE_SYSTEM);
}
__device__ __forceinline__ void st_sysu16(u16* p, u16 v) {
    __hip_atomic_store(p, v, __ATOMIC_RELAXED, __HIP_MEMORY_SCOPE_SYSTEM);
}

// Fence-free grid barrier (R11-proven: ~4us). Cross-block data moves via sc0sc1
// system accessors so no L2 flush/invalidate is needed at the barrier.
__device__ __forceinline__ void gbar(int* cnt, int* flag, int nblk, int blk, int& gen) {
    __syncthreads();
    if (threadIdx.x == 0) {
        gen += 1;
        asm volatile("s_waitcnt vmcnt(0)" ::: "memory");
        __hip_atomic_fetch_add(&cnt[(blk & 7) << 5], 1, __ATOMIC_RELAXED,
                               __HIP_MEMORY_SCOPE_SYSTEM);
        if (blk == 0) {
            const int target = nblk * gen;
            for (;;) {
                int sum = 0;
#pragma unroll
                for (int j = 0; j < 8; ++j)
                    sum += __hip_atomic_load(&cnt[j << 5], __ATOMIC_RELAXED,
                                             __HIP_MEMORY_SCOPE_SYSTEM);
                if (sum >= target) break;
                __builtin_amdgcn_s_sleep(2);
            }
#pragma unroll
            for (int j = 0; j < 8; ++j)
                __hip_atomic_store(&flag[j << 5], gen, __ATOMIC_RELAXED,
                                   __HIP_MEMORY_SCOPE_SYSTEM);
        } else {
            while (__hip_atomic_load(&flag[(blk & 7) << 5], __ATOMIC_RELAXED,
                                     __HIP_MEMORY_SCOPE_SYSTEM) < gen)
                __builtin_amdgcn_s_sleep(2);
        }
    }
    __syncthreads();
}

// ---------------- embedding gather + split ----------------
__global__ void k_embed_src_split(const int* __restrict__ src, const float* __restrict__ emb,
                                  u16* __restrict__ hi, u16* __restrict__ lo) {
    int row = blockIdx.x;              // s*B + b
    int tok = src[row];
    int c = threadIdx.x * 4;
    float4 v = *reinterpret_cast<const float4*>(emb + (size_t)tok * E_ + c);
    ushort4 h, l;
    splitf(v.x, h.x, l.x); splitf(v.y, h.y, l.y);
    splitf(v.z, h.z, l.z); splitf(v.w, h.w, l.w);
    *reinterpret_cast<ushort4*>(hi + (size_t)row * E_ + c) = h;
    *reinterpret_cast<ushort4*>(lo + (size_t)row * E_ + c) = l;
}

__global__ void k_embed_dec_split(const int* __restrict__ src, const int* __restrict__ trg,
                                  const float* __restrict__ emb,
                                  u16* __restrict__ hi, u16* __restrict__ lo) {
    int row = blockIdx.x;              // t*B + b
    int t = row >> 5, b = row & 31;
    int tok = (t == 0) ? src[(S_ - 1) * B_ + b] : trg[(t - 1) * B_ + b];
    int c = threadIdx.x * 4;
    float4 v = *reinterpret_cast<const float4*>(emb + (size_t)tok * E_ + c);
    ushort4 h, l;
    splitf(v.x, h.x, l.x); splitf(v.y, h.y, l.y);
    splitf(v.z, h.z, l.z); splitf(v.w, h.w, l.w);
    *reinterpret_cast<ushort4*>(hi + (size_t)row * E_ + c) = h;
    *reinterpret_cast<ushort4*>(lo + (size_t)row * E_ + c) = l;
}

// ---------------- generic f32 -> bf16 hi/lo split ----------------
__global__ __launch_bounds__(256) void k_split(const float* __restrict__ in, int ld, int cols4,
                                               u16* __restrict__ hi, u16* __restrict__ lo) {
    int c4 = blockIdx.x * 256 + threadIdx.x;
    if (c4 >= cols4) return;
    size_t r = blockIdx.y;
    float4 v = *reinterpret_cast<const float4*>(in + r * ld + (size_t)c4 * 4);
    ushort4 h, l;
    splitf(v.x, h.x, l.x); splitf(v.y, h.y, l.y);
    splitf(v.z, h.z, l.z); splitf(v.w, h.w, l.w);
    size_t o = (r * cols4 + c4) * 4;
    *reinterpret_cast<ushort4*>(hi + o) = h;
    *reinterpret_cast<ushort4*>(lo + o) = l;
}

// ---------------- enc = enc_f + enc_b, plus split ----------------
__global__ __launch_bounds__(256) void k_split_sum_enc(
    const float* __restrict__ ef, const float* __restrict__ eb, float* __restrict__ es,
    u16* __restrict__ hi, u16* __restrict__ lo) {
    size_t r = blockIdx.y;
    int c4 = threadIdx.x * 4;
    float4 va = *reinterpret_cast<const float4*>(ef + r * H_ + c4);
    float4 vb = *reinterpret_cast<const float4*>(eb + r * H_ + c4);
    float4 v; v.x = va.x + vb.x; v.y = va.y + vb.y; v.z = va.z + vb.z; v.w = va.w + vb.w;
    *reinterpret_cast<float4*>(es + r * H_ + c4) = v;
    ushort4 h, l;
    splitf(v.x, h.x, l.x); splitf(v.y, h.y, l.y);
    splitf(v.z, h.z, l.z); splitf(v.w, h.w, l.w);
    *reinterpret_cast<ushort4*>(hi + r * H_ + c4) = h;
    *reinterpret_cast<ushort4*>(lo + r * H_ + c4) = l;
}

// ---------------- gate-interleaved weight split: dst row 3i+g = src row g*1024+i ----------------
__global__ void k_wsplit_perm(const float* __restrict__ src, int ld, int coff,
                              u16* __restrict__ hi, u16* __restrict__ lo) {
    int r = blockIdx.x;                // permuted row: 3i+g
    int i = r / 3, g = r - i * 3;
    const float* p = src + (size_t)(g * H_ + i) * ld + coff;
    int c = threadIdx.x * 4;
    float4 v = *reinterpret_cast<const float4*>(p + c);
    ushort4 h, l;
    splitf(v.x, h.x, l.x); splitf(v.y, h.y, l.y);
    splitf(v.z, h.z, l.z); splitf(v.w, h.w, l.w);
    *reinterpret_cast<ushort4*>(hi + (size_t)r * H_ + c) = h;
    *reinterpret_cast<ushort4*>(lo + (size_t)r * H_ + c) = l;
}

// ---------------- big split-bf16 MFMA GEMM (proven R2-R11) ----------------
__global__ __launch_bounds__(256, 2) void k_gemm_mfma3(
    const u16* __restrict__ Ah, const u16* __restrict__ Al,
    const u16* __restrict__ Bh, const u16* __restrict__ Bl,
    const float* __restrict__ bias, float* __restrict__ C,
    int ldc, int K)
{
    __shared__ u16 ls[4][128 * 32];
    const int tid = threadIdx.x;
    const int lane = tid & 63, w = tid >> 6;
    const int wr = w >> 1, wc = w & 1;
    const size_t m0 = (size_t)blockIdx.x * 128, n0 = (size_t)blockIdx.y * 128;

    const int c0 = (w * 2) * 64 + lane;
    const int r0 = c0 >> 2, kc0 = (c0 & 3) << 3;
    const size_t rstep = (size_t)16 * K;
    const u16* gAh = Ah + (m0 + r0) * K + kc0;
    const u16* gAl = Al + (m0 + r0) * K + kc0;
    const u16* gBh = Bh + (n0 + r0) * K + kc0;
    const u16* gBl = Bl + (n0 + r0) * K + kc0;
    const int lo0 = c0 * 8;

    const int frow = lane & 15, fk = (lane >> 4) << 3;
    const int offA = (wr * 64 + frow) * 32 + fk;
    const int offB = (wc * 64 + frow) * 32 + fk;

    f32x4 acc[4][4] = {};

    for (int k0 = 0; k0 < K; k0 += 32) {
        load_lds16(gAh + k0, &ls[0][lo0]);
        load_lds16(gAh + rstep + k0, &ls[0][lo0 + 512]);
        load_lds16(gAl + k0, &ls[1][lo0]);
        load_lds16(gAl + rstep + k0, &ls[1][lo0 + 512]);
        load_lds16(gBh + k0, &ls[2][lo0]);
        load_lds16(gBh + rstep + k0, &ls[2][lo0 + 512]);
        load_lds16(gBl + k0, &ls[3][lo0]);
        load_lds16(gBl + rstep + k0, &ls[3][lo0 + 512]);
        __syncthreads();

        bf16x8 fAh[4], fAl[4], fBh[4], fBl[4];
#pragma unroll
        for (int m = 0; m < 4; ++m) {
            fAh[m] = *reinterpret_cast<const bf16x8*>(&ls[0][offA + m * 512]);
            fAl[m] = *reinterpret_cast<const bf16x8*>(&ls[1][offA + m * 512]);
        }
#pragma unroll
        for (int n = 0; n < 4; ++n) {
            fBh[n] = *reinterpret_cast<const bf16x8*>(&ls[2][offB + n * 512]);
            fBl[n] = *reinterpret_cast<const bf16x8*>(&ls[3][offB + n * 512]);
        }
#pragma unroll
        for (int m = 0; m < 4; ++m)
#pragma unroll
            for (int n = 0; n < 4; ++n) {
                MFMA3(acc[m][n], fAh[m], fAl[m], fBh[n], fBl[n]);
            }
        __syncthreads();
    }

    const int crow0 = wr * 64 + ((lane >> 4) << 2);
    const int ccol0 = wc * 64 + (lane & 15);
#pragma unroll
    for (int n = 0; n < 4; ++n) {
        const size_t col = n0 + ccol0 + n * 16;
        const float bv = bias ? bias[col] : 0.f;
#pragma unroll
        for (int m = 0; m < 4; ++m)
#pragma unroll
            for (int r = 0; r < 4; ++r)
                C[(m0 + crow0 + m * 16 + r) * (size_t)ldc + col] = acc[m][n][r] + bv;
    }
}

// ---------------- head GEMM R14: 128x256 tile, B read as f32 + split in-kernel ----------------
// A (states) from pre-split bf16 hi/lo via global_load_lds; B (Wout) f32 reg-staged:
// load f32x8/thread, splitf, ds_write 16B hi + 16B lo. Eliminates the separate
// k_split(Wout) passes. Same MFMA/accumulation order as R11's n2 kernel.
__global__ __launch_bounds__(256, 2) void k_gemm_n2f(
    const u16* __restrict__ Ah, const u16* __restrict__ Al,
    const float* __restrict__ Bf,
    const float* __restrict__ bias, float* __restrict__ C,
    int ldc, int K)
{
    __shared__ u16 lsA[2][128 * 32];       // 8 KB each
    __shared__ u16 lsBh[256 * 32];         // 16 KB
    __shared__ u16 lsBl[256 * 32];         // 16 KB
    const int tid = threadIdx.x;
    const int lane = tid & 63, w = tid >> 6;
    const int wr = w >> 1, wc = w & 1;
    const size_t m0 = (size_t)blockIdx.x * 128, n0 = (size_t)blockIdx.y * 256;

    const int frow = lane & 15, fk = (lane >> 4) << 3;
    const int offA = (wr * 64 + frow) * 32 + fk;
    const int offB = (wc * 128 + frow) * 32 + fk;

    f32x4 acc[4][8] = {};

    for (int k0 = 0; k0 < K; k0 += 32) {
        // ---- A: 1024 16B chunks via global_load_lds (wave-uniform base + lane*16) ----
#pragma unroll
        for (int q = 0; q < 4; ++q) {
            const int chunk = (w + q * 4) * 64 + lane;
            const int local = chunk & 511;
            const u16* A = (chunk < 512) ? Ah : Al;
            load_lds16(A + (m0 + (local >> 2)) * K + k0 + ((local & 3) << 3),
                       &lsA[chunk >> 9][local * 8]);
        }
        // ---- B: 1024 chunks of 8 f32, reg-split -> LDS hi/lo ----
#pragma unroll
        for (int q = 0; q < 4; ++q) {
            const int c = tid + q * 256;
            const int row = c >> 2, k8 = (c & 3) << 3;
            const float* src = Bf + (size_t)(n0 + row) * K + k0 + k8;
            float4 v0 = *reinterpret_cast<const float4*>(src);
            float4 v1 = *reinterpret_cast<const float4*>(src + 4);
            union { ushort4 s[2]; bf16x8 v; } hh, ll;
            splitf(v0.x, hh.s[0].x, ll.s[0].x); splitf(v0.y, hh.s[0].y, ll.s[0].y);
            splitf(v0.z, hh.s[0].z, ll.s[0].z); splitf(v0.w, hh.s[0].w, ll.s[0].w);
            splitf(v1.x, hh.s[1].x, ll.s[1].x); splitf(v1.y, hh.s[1].y, ll.s[1].y);
            splitf(v1.z, hh.s[1].z, ll.s[1].z); splitf(v1.w, hh.s[1].w, ll.s[1].w);
            *reinterpret_cast<bf16x8*>(&lsBh[row * 32 + k8]) = hh.v;
            *reinterpret_cast<bf16x8*>(&lsBl[row * 32 + k8]) = ll.v;
        }
        __syncthreads();

        bf16x8 fAh[4], fAl[4];
#pragma unroll
        for (int m = 0; m < 4; ++m) {
            fAh[m] = *reinterpret_cast<const bf16x8*>(&lsA[0][offA + m * 512]);
            fAl[m] = *reinterpret_cast<const bf16x8*>(&lsA[1][offA + m * 512]);
        }
#pragma unroll
        for (int n = 0; n < 8; ++n) {
            bf16x8 fBh = *reinterpret_cast<const bf16x8*>(&lsBh[offB + n * 512]);
            bf16x8 fBl = *reinterpret_cast<const bf16x8*>(&lsBl[offB + n * 512]);
#pragma unroll
            for (int m = 0; m < 4; ++m) {
                MFMA3(acc[m][n], fAh[m], fAl[m], fBh, fBl);
            }
        }
        __syncthreads();
    }

    const int crow0 = wr * 64 + ((lane >> 4) << 2);
    const int ccol0 = wc * 128 + (lane & 15);
#pragma unroll
    for (int n = 0; n < 8; ++n) {
        const size_t col = n0 + ccol0 + n * 16;
        const float bv = bias ? bias[col] : 0.f;
#pragma unroll
        for (int m = 0; m < 4; ++m)
#pragma unroll
            for (int r = 0; r < 4; ++r)
                C[(m0 + crow0 + m * 16 + r) * (size_t)ldc + col] = acc[m][n][r] + bv;
    }
}

// ================= persistent encoder (R9/R11, proven) =================
__global__ __launch_bounds__(256) void k_enc_persist(
    const u16* __restrict__ whhf_h, const u16* __restrict__ whhf_l,
    const u16* __restrict__ whhb_h, const u16* __restrict__ whhb_l,
    const float* __restrict__ gi_f, const float* __restrict__ gi_b,
    const float* __restrict__ bhh_f, const float* __restrict__ bhh_b,
    u16* __restrict__ hfH0, u16* __restrict__ hfL0,
    u16* __restrict__ hfH1, u16* __restrict__ hfL1,
    u16* __restrict__ hbH0, u16* __restrict__ hbL0,
    u16* __restrict__ hbH1, u16* __restrict__ hbL1,
    float* __restrict__ enc_f, float* __restrict__ enc_b,
    int* __restrict__ cnt, int* __restrict__ flag)
{
    __shared__ __align__(16) char smem[145792];
    u16* lAh  = (u16*)smem;                    // [32][1024] staged h hi, XOR-swizzled
    u16* lAl  = (u16*)(smem + 65536);          // lo
    float* ex0 = (float*)(smem + 131072);      // [48][33] k-half 0
    float* ex1 = (float*)(smem + 137408);      // [48][33] k-half 1
    float* hloc = (float*)(smem + 143744);     // [32][16] f32 state

    const int blk = blockIdx.x, tid = threadIdx.x;
    const int lane = tid & 63, w = tid >> 6;
    const int dir = blk >> 6, c = blk & 63;
    const int i0 = c * 16;
    const u16* WH = (dir ? whhb_h : whhf_h) + (size_t)c * 48 * 1024;
    const u16* WL = (dir ? whhb_l : whhf_l) + (size_t)c * 48 * 1024;
    const float* gi = dir ? gi_b : gi_f;
    const float* bhh = dir ? bhh_b : bhh_f;
    float* encd = dir ? enc_b : enc_f;
    int gen = 0;

    for (int q = tid; q < 512; q += 256) hloc[q] = 0.f;

    const int frow = lane & 15, fk8 = (lane >> 4) << 3;
    const int cb = lane & 15, rb0 = (lane >> 4) << 2;

    for (int t = 0; t < 64; ++t) {
        const int a = t & 1;
        const u16* rH = dir ? (a ? hbH1 : hbH0) : (a ? hfH1 : hfH0);
        const u16* rL = dir ? (a ? hbL1 : hbL0) : (a ? hfL1 : hfL0);
        u16* oH = dir ? (a ? hbH0 : hbH1) : (a ? hfH0 : hfH1);
        u16* oL = dir ? (a ? hbL0 : hbL1) : (a ? hfL0 : hfL1);
        const int s = dir ? 63 - t : t;

#pragma unroll
        for (int ch0 = 0; ch0 < 4096; ch0 += 256) {
            int ch = ch0 + tid;
            int r = ch >> 7, kc = (ch & 127) << 3;
            int sw = kc ^ ((r & 7) << 3);
            *(bf16x8*)&lAh[r * 1024 + sw] = ld_sys16(&rH[r * 1024 + kc]);
            *(bf16x8*)&lAl[r * 1024 + sw] = ld_sys16(&rL[r * 1024 + kc]);
        }
        __syncthreads();

#pragma unroll
        for (int jj = 0; jj < 3; ++jj) {
            const int j = w * 3 + jj;
            const int m = j & 1;
            const int n = (j >> 1) % 3;
            const int kh = j / 6;
            const int arow = m * 16 + frow;
            const int asw = (arow & 7) << 3;
            const u16* gBh = WH + (size_t)(n * 16 + frow) * 1024;
            const u16* gBl = WL + (size_t)(n * 16 + frow) * 1024;
            f32x4 acc = {};
            const int ke = kh * 512 + 512;
#pragma unroll 4
            for (int k0 = kh * 512; k0 < ke; k0 += 32) {
                int kc = k0 + fk8;
                bf16x8 aH = *(const bf16x8*)&lAh[arow * 1024 + (kc ^ asw)];
                bf16x8 aL = *(const bf16x8*)&lAl[arow * 1024 + (kc ^ asw)];
                bf16x8 bH = *(const bf16x8*)&gBh[kc];
                bf16x8 bL = *(const bf16x8*)&gBl[kc];
                MFMA3(acc, aH, aL, bH, bL);
            }
            float* exd = kh ? ex1 : ex0;
            const int pc = n * 16 + cb;
#pragma unroll
            for (int r = 0; r < 4; ++r)
                exd[pc * 33 + m * 16 + rb0 + r] = acc[r];
        }
        __syncthreads();

        {
            const int il = tid & 15, bb = tid >> 4;
            const int i = i0 + il;
#pragma unroll
            for (int q = 0; q < 2; ++q) {
                int b = bb + q * 16;
                float ghr = ex0[(3 * il + 0) * 33 + b] + ex1[(3 * il + 0) * 33 + b] + bhh[i];
                float ghz = ex0[(3 * il + 1) * 33 + b] + ex1[(3 * il + 1) * 33 + b] + bhh[H_ + i];
                float ghn = ex0[(3 * il + 2) * 33 + b] + ex1[(3 * il + 2) * 33 + b] + bhh[2 * H_ + i];
                size_t gio = (size_t)(s * B_ + b) * H3 + i;
                float gir = gi[gio], giz = gi[gio + H_], gin = gi[gio + 2 * H_];
                float rr = 1.f / (1.f + expf(-(gir + ghr)));
                float zz = 1.f / (1.f + expf(-(giz + ghz)));
                float nn = tanhf(gin + rr * ghn);
                float hold = hloc[b * 16 + il];
                float hnew = (1.f - zz) * nn + zz * hold;
                hloc[b * 16 + il] = hnew;
                u16 hh, hl; splitf(hnew, hh, hl);
                st_sysu16(&oH[b * 1024 + i], hh);
                st_sysu16(&oL[b * 1024 + i], hl);
                encd[((size_t)b * 64 + s) * H_ + i] = hnew;
            }
        }
        gbar(cnt, flag, 128, blk, gen);
    }
}

// ================= persistent decoder (R11, proven) =================
__global__ __launch_bounds__(256) void k_dec_persist(
    const u16* __restrict__ wah, const u16* __restrict__ wal,
    const u16* __restrict__ wgh, const u16* __restrict__ wgl,
    const u16* __restrict__ wdh, const u16* __restrict__ wdl,
    const float* __restrict__ gi_e, const float* __restrict__ bhh_d,
    const float* __restrict__ ep, const float* __restrict__ vvec,
    const float* __restrict__ enc,
    u16* __restrict__ hH, u16* __restrict__ hL,
    float* __restrict__ hwa, float* __restrict__ scores,
    u16* __restrict__ ctxH, u16* __restrict__ ctxL,
    float* __restrict__ states, int* __restrict__ cnt, int* __restrict__ flag)
{
    __shared__ __align__(16) char smem[140288];
    u16* lWH  = (u16*)smem;                    // [16][1024] rows 0-3 hWa, 4-15 ghd (swizzled)
    u16* lWL  = (u16*)(smem + 32768);
    u16* lDH  = (u16*)(smem + 65536);          // [16][1024] wdc hi (12 + 4 pad)
    float* lenc = (float*)(smem + 98304);      // [64][128]
    float* ex1a = (float*)(smem + 131072);     // [32][16] PhA partial (k-half 0)
    float* ex1b = (float*)(smem + 133120);
    float* ex2a = (float*)(smem + 135168);     // PhD partials
    float* ex2b = (float*)(smem + 137216);
    float* aw   = (float*)(smem + 139264);     // [64]
    float* hloc = (float*)(smem + 139520);     // [128] f32 state for owned (b,u)

    const int bid = blockIdx.x, tid = threadIdx.x;
    const int lane = tid & 63, w = tid >> 6;
    const int frow = lane & 15, fk8 = (lane >> 4) << 3;
    const int b3 = bid >> 3, sl = bid & 7;
    int gen = 0;

    for (int ch = tid; ch < 2048; ch += 256) {
        int r = ch >> 7, kc = (ch & 127) << 3;
        int sw = kc ^ ((r & 7) << 3);
        const u16 *sH, *sL;
        if (r < 4) { sH = wah + ((size_t)bid * 4 + r) * 1024;
                     sL = wal + ((size_t)bid * 4 + r) * 1024; }
        else       { sH = wgh + ((size_t)bid * 12 + r - 4) * 1024;
                     sL = wgl + ((size_t)bid * 12 + r - 4) * 1024; }
        *(bf16x8*)&lWH[r * 1024 + sw] = *(const bf16x8*)&sH[kc];
        *(bf16x8*)&lWL[r * 1024 + sw] = *(const bf16x8*)&sL[kc];
    }
    for (int ch = tid; ch < 2048; ch += 256) {
        int r = ch >> 7, kc = (ch & 127) << 3;
        int sw = kc ^ ((r & 7) << 3);
        int rowg = (r < 12) ? bid * 12 + r : bid * 12;
        *(bf16x8*)&lDH[r * 1024 + sw] = *(const bf16x8*)&wdh[(size_t)rowg * 1024 + kc];
    }
    for (int ch = tid; ch < 2048; ch += 256) {
        int s = ch >> 5, c4 = (ch & 31) << 2;
        *(float4*)&lenc[s * 128 + c4] =
            *(const float4*)&enc[((size_t)b3 * 64 + s) * 1024 + sl * 128 + c4];
    }
    if (tid < 128) {
        int b = tid >> 2, u = bid * 4 + (tid & 3);
        hloc[tid] = bf2f(hH[b * 1024 + u]) + bf2f(hL[b * 1024 + u]);
    }
    float vreg[16];
#pragma unroll
    for (int i = 0; i < 16; ++i) vreg[i] = vvec[lane + i * 64];
    __syncthreads();

    const int mt = w & 1, kh = w >> 1;
    const int bsw = (frow & 7) << 3;
    const int rowg = (frow < 12) ? bid * 12 + frow : bid * 12;
    const u16* gDl = wdl + (size_t)rowg * 1024;
    const int exw = (mt * 16 + ((lane >> 4) << 2)) * 16 + frow;

    for (int t = 0; t < 64; ++t) {
        // ---- PhA ----
        {
            float* exA = kh ? ex1b : ex1a;
            f32x4 acc = {};
            const int ar0 = (mt * 16 + frow) * 1024;
            const int ke = kh * 512 + 512;
#pragma unroll 4
            for (int k0 = kh * 512; k0 < ke; k0 += 32) {
                int kc = k0 + fk8;
                bf16x8 aH = ld_sys16(&hH[ar0 + kc]);
                bf16x8 aL = ld_sys16(&hL[ar0 + kc]);
                bf16x8 bH = *(const bf16x8*)&lWH[frow * 1024 + (kc ^ bsw)];
                bf16x8 bL = *(const bf16x8*)&lWL[frow * 1024 + (kc ^ bsw)];
                MFMA3(acc, aH, aL, bH, bL);
            }
#pragma unroll
            for (int r = 0; r < 4; ++r) exA[exw + r * 16] = acc[r];
        }
        __syncthreads();
        if (tid < 128) {
            int b = tid >> 2, col = tid & 3;
            st_sysf(&hwa[b * 1024 + bid * 4 + col],
                    ex1a[b * 16 + col] + ex1b[b * 16 + col]);
        }
        gbar(cnt, flag, 256, bid, gen);

        // ---- PhB ----
#pragma unroll
        for (int q2 = 0; q2 < 2; ++q2) {
            int s = sl * 8 + w * 2 + q2;
            const float* epr = ep + ((size_t)b3 * 64 + s) * 1024;
            const float* hr = hwa + b3 * 1024;
            float a2 = 0.f;
#pragma unroll
            for (int i = 0; i < 16; ++i) {
                int j = lane + i * 64;
                a2 += fmaxf(ld_sysf(&hr[j]) + epr[j], 0.f) * vreg[i];
            }
            for (int off = 32; off; off >>= 1) a2 += __shfl_down(a2, off);
            if (lane == 0) st_sysf(&scores[b3 * 64 + s], a2);
        }
        gbar(cnt, flag, 256, bid, gen);

        // ---- PhC ----
        if (tid < 64) {
            float sc = ld_sysf(&scores[b3 * 64 + tid]);
            float m = sc;
            for (int off = 32; off; off >>= 1) m = fmaxf(m, __shfl_xor(m, off));
            float e = expf(sc - m);
            float sum = e;
            for (int off = 32; off; off >>= 1) sum += __shfl_xor(sum, off);
            aw[tid] = e / sum;
        }
        __syncthreads();
        if (tid < 128) {
            int c = tid;
            float x = 0.f;
#pragma unroll 8
            for (int s = 0; s < 64; ++s) x += aw[s] * lenc[s * 128 + c];
            states[((size_t)t * 32 + b3) * 2048 + 1024 + sl * 128 + c] = x;
            u16 hh, hl; splitf(x, hh, hl);
            st_sysu16(&ctxH[b3 * 1024 + sl * 128 + c], hh);
            st_sysu16(&ctxL[b3 * 1024 + sl * 128 + c], hl);
        }
        gbar(cnt, flag, 256, bid, gen);

        // ---- PhD ----
        {
            float* exD = kh ? ex2b : ex2a;
            f32x4 acc = {};
            const int ar0 = (mt * 16 + frow) * 1024;
            const int ke = kh * 512 + 512;
#pragma unroll 4
            for (int k0 = kh * 512; k0 < ke; k0 += 32) {
                int kc = k0 + fk8;
                bf16x8 aH = ld_sys16(&ctxH[ar0 + kc]);
                bf16x8 aL = ld_sys16(&ctxL[ar0 + kc]);
                bf16x8 bH = *(const bf16x8*)&lDH[frow * 1024 + (kc ^ bsw)];
                bf16x8 bL = *(const bf16x8*)&gDl[kc];
                MFMA3(acc, aH, aL, bH, bL);
            }
#pragma unroll
            for (int r = 0; r < 4; ++r) exD[exw + r * 16] = acc[r];
        }
        __syncthreads();
        if (tid < 128) {
            int b = tid >> 2, ui = tid & 3;
            int u = bid * 4 + ui;
            float gicr = ex2a[b * 16 + 3 * ui + 0] + ex2b[b * 16 + 3 * ui + 0];
            float gicz = ex2a[b * 16 + 3 * ui + 1] + ex2b[b * 16 + 3 * ui + 1];
            float gicn = ex2a[b * 16 + 3 * ui + 2] + ex2b[b * 16 + 3 * ui + 2];
            float ghr = ex1a[b * 16 + 4 + 3 * ui + 0] + ex1b[b * 16 + 4 + 3 * ui + 0] + bhh_d[u];
            float ghz = ex1a[b * 16 + 4 + 3 * ui + 1] + ex1b[b * 16 + 4 + 3 * ui + 1] + bhh_d[H_ + u];
            float ghn = ex1a[b * 16 + 4 + 3 * ui + 2] + ex1b[b * 16 + 4 + 3 * ui + 2] + bhh_d[2 * H_ + u];
            size_t ge = ((size_t)t * 32 + b) * 3072;
            float gir = gi_e[ge + u] + gicr;
            float giz = gi_e[ge + 1024 + u] + gicz;
            float gin = gi_e[ge + 2048 + u] + gicn;
            float rr = 1.f / (1.f + expf(-(gir + ghr)));
            float zz = 1.f / (1.f + expf(-(giz + ghz)));
            float nn = tanhf(gin + rr * ghn);
            float hold = hloc[tid];
            float hnew = (1.f - zz) * nn + zz * hold;
            hloc[tid] = hnew;
            u16 hh, hl; splitf(hnew, hh, hl);
            st_sysu16(&hH[b * 1024 + u], hh);
            st_sysu16(&hL[b * 1024 + u], hl);
            states[((size_t)t * 32 + b) * 2048 + u] = hnew;
        }
        gbar(cnt, flag, 256, bid, gen);
    }
}

extern "C" void kernel_launch(void* const* d_in, const int* in_sizes, int n_in,
                              void* d_out, int out_size, void* d_ws, size_t ws_size,
                              hipStream_t stream) {
    const int*   src   = (const int*)d_in[0];
    const int*   trg   = (const int*)d_in[1];
    const float* emb   = (const float*)d_in[2];
    const float* Wih_f = (const float*)d_in[3];
    const float* Whh_f = (const float*)d_in[4];
    const float* bih_f = (const float*)d_in[5];
    const float* bhh_f = (const float*)d_in[6];
    const float* Wih_b = (const float*)d_in[7];
    const float* Whh_b = (const float*)d_in[8];
    const float* bih_b = (const float*)d_in[9];
    const float* bhh_b = (const float*)d_in[10];
    const float* Wa    = (const float*)d_in[11];
    const float* ba    = (const float*)d_in[12];
    const float* vv    = (const float*)d_in[13];
    const float* Wih_d = (const float*)d_in[14];
    const float* Whh_d = (const float*)d_in[15];
    const float* bih_d = (const float*)d_in[16];
    const float* bhh_d = (const float*)d_in[17];
    const float* Wout  = (const float*)d_in[18];
    const float* bout  = (const float*)d_in[19];
    float* out = (float*)d_out;
    (void)in_sizes; (void)n_in; (void)out_size; (void)ws_size;

    float* w = (float*)d_ws;
    size_t o = 0;
    auto alloc = [&](size_t n) { float* p = w + o; o += n; return p; };
    float* gi_f  = alloc((size_t)S_ * B_ * H3);      // encoder fwd gi; reused as gi_e
    float* gi_b  = alloc((size_t)S_ * B_ * H3);      // encoder bwd gi; reused as states
    float* enc_f = alloc((size_t)B_ * S_ * H_);
    float* enc_b = alloc((size_t)B_ * S_ * H_);
    float* enc   = alloc((size_t)B_ * S_ * H_);
    float* ep    = alloc((size_t)B_ * S_ * H_);
    float* hwa   = alloc((size_t)B_ * H_);
    float* scores = alloc(B_ * S_);
    float* barf  = alloc(1024);
    int* cntE  = (int*)barf;
    int* flagE = cntE + 256;
    int* cntD  = cntE + 512;
    int* flagD = cntE + 768;
    float* gi_e   = gi_f;
    float* states = gi_b;

    u16* wu = (u16*)(w + o);
    size_t ou = 0;
    auto alloc16 = [&](size_t n) { u16* p = wu + ou; ou += n; return p; };
    u16* semb_h  = alloc16((size_t)S_ * B_ * E_);  u16* semb_l  = alloc16((size_t)S_ * B_ * E_);
    u16* demb_h  = alloc16((size_t)T_ * B_ * E_);  u16* demb_l  = alloc16((size_t)T_ * B_ * E_);
    u16* wihf_h  = alloc16((size_t)H3 * E_);       u16* wihf_l  = alloc16((size_t)H3 * E_);
    u16* wihb_h  = alloc16((size_t)H3 * E_);       u16* wihb_l  = alloc16((size_t)H3 * E_);
    u16* wihd_h  = alloc16((size_t)H3 * E_);       u16* wihd_l  = alloc16((size_t)H3 * E_);
    u16* wae_h   = alloc16((size_t)H_ * H_);       u16* wae_l   = alloc16((size_t)H_ * H_);
    u16* enc_h   = alloc16((size_t)B_ * S_ * H_);  u16* enc_l   = alloc16((size_t)B_ * S_ * H_);
    u16* st_h    = alloc16((size_t)T_ * B_ * H2);  u16* st_l    = alloc16((size_t)T_ * B_ * H2);
    u16* whhf_h  = alloc16((size_t)H3 * H_);       u16* whhf_l  = alloc16((size_t)H3 * H_);
    u16* whhb_h  = alloc16((size_t)H3 * H_);       u16* whhb_l  = alloc16((size_t)H3 * H_);
    u16* wgh     = alloc16((size_t)H3 * H_);       u16* wgl     = alloc16((size_t)H3 * H_);   // Whh_d perm
    u16* wdh     = alloc16((size_t)H3 * H_);       u16* wdl     = alloc16((size_t)H3 * H_);   // Wihd ctx perm
    u16* wah     = alloc16((size_t)H_ * H_);       u16* wal     = alloc16((size_t)H_ * H_);   // Wa h-part
    u16* hsf_h[2] = {alloc16(B_ * H_), alloc16(B_ * H_)};
    u16* hsf_l[2] = {alloc16(B_ * H_), alloc16(B_ * H_)};
    u16* hsb_h[2] = {alloc16(B_ * H_), alloc16(B_ * H_)};
    u16* hsb_l[2] = {alloc16(B_ * H_), alloc16(B_ * H_)};
    u16* ctx_h   = alloc16(B_ * H_);               u16* ctx_l   = alloc16(B_ * H_);

    // ---- init ----
    hipMemsetAsync(barf, 0, 1024 * sizeof(float), stream);
    hipMemsetAsync(hsf_h[0], 0, B_ * H_ * sizeof(u16), stream);
    hipMemsetAsync(hsf_l[0], 0, B_ * H_ * sizeof(u16), stream);
    hipMemsetAsync(hsb_h[0], 0, B_ * H_ * sizeof(u16), stream);
    hipMemsetAsync(hsb_l[0], 0, B_ * H_ * sizeof(u16), stream);

    // ---- embeddings ----
    k_embed_src_split<<<S_ * B_, 128, 0, stream>>>(src, emb, semb_h, semb_l);
    k_embed_dec_split<<<T_ * B_, 128, 0, stream>>>(src, trg, emb, demb_h, demb_l);

    // ---- weight splits ----
    k_split<<<dim3(1, H3), 256, 0, stream>>>(Wih_f, E_, E_ / 4, wihf_h, wihf_l);
    k_split<<<dim3(1, H3), 256, 0, stream>>>(Wih_b, E_, E_ / 4, wihb_h, wihb_l);
    k_split<<<dim3(1, H3), 256, 0, stream>>>(Wih_d, EH, E_ / 4, wihd_h, wihd_l);
    k_split<<<dim3(1, H_), 256, 0, stream>>>(Wa + H_, H2, H_ / 4, wae_h, wae_l);
    k_split<<<dim3(1, H_), 256, 0, stream>>>(Wa, H2, H_ / 4, wah, wal);
    k_wsplit_perm<<<H3, 256, 0, stream>>>(Whh_f, H_, 0, whhf_h, whhf_l);
    k_wsplit_perm<<<H3, 256, 0, stream>>>(Whh_b, H_, 0, whhb_h, whhb_l);
    k_wsplit_perm<<<H3, 256, 0, stream>>>(Whh_d, H_, 0, wgh, wgl);
    k_wsplit_perm<<<H3, 256, 0, stream>>>(Wih_d, EH, E_, wdh, wdl);

    // ---- encoder input projections ----
    k_gemm_mfma3<<<dim3(16, 24), 256, 0, stream>>>(semb_h, semb_l, wihf_h, wihf_l,
                                                   bih_f, gi_f, H3, E_);
    k_gemm_mfma3<<<dim3(16, 24), 256, 0, stream>>>(semb_h, semb_l, wihb_h, wihb_l,
                                                   bih_b, gi_b, H3, E_);

    // ---- encoder: persistent, LDS-staged h ----
    k_enc_persist<<<128, 256, 0, stream>>>(
        whhf_h, whhf_l, whhb_h, whhb_l, gi_f, gi_b, bhh_f, bhh_b,
        hsf_h[0], hsf_l[0], hsf_h[1], hsf_l[1],
        hsb_h[0], hsb_l[0], hsb_h[1], hsb_l[1],
        enc_f, enc_b, cntE, flagE);

    // ---- merge enc dirs + split; ep precompute; decoder emb projection ----
    k_split_sum_enc<<<dim3(1, B_ * S_), 256, 0, stream>>>(enc_f, enc_b, enc, enc_h, enc_l);
    k_gemm_mfma3<<<dim3(16, 8), 256, 0, stream>>>(enc_h, enc_l, wae_h, wae_l,
                                                  ba, ep, H_, H_);
    k_gemm_mfma3<<<dim3(16, 24), 256, 0, stream>>>(demb_h, demb_l, wihd_h, wihd_l,
                                                   bih_d, gi_e, H3, E_);

    // ---- decoder: persistent, fence-free sc1 protocol (R11) ----
    k_dec_persist<<<256, 256, 0, stream>>>(
        wah, wal, wgh, wgl, wdh, wdl, gi_e, bhh_d, ep, vv, enc,
        hsf_h[0], hsf_l[0], hwa, scores, ctx_h, ctx_l, states, cntD, flagD);

    // ---- output head: 5 passes, fused-split 128x256 head GEMM (R14) ----
    k_split<<<dim3(2, T_ * B_), 256, 0, stream>>>(states, H2, H2 / 4, st_h, st_l);
    for (int p = 0; p < 5; ++p) {
        k_gemm_n2f<<<dim3(16, 25), 256, 0, stream>>>(st_h, st_l,
                                                     Wout + (size_t)p * 6400 * H2,
                                                     bout + p * 6400,
                                                     out + (size_t)p * 6400, V_, H2);
    }
}

// Round 15
// 4069.493 us; speedup vs baseline: 1.1688x; 1.0519x over previous
//
#include <hip/hip_runtime.h>
#include <hip/hip_bf16.h>

#define S_ 64
#define T_ 64
#define B_ 32
#define E_ 512
#define H_ 1024
#define V_ 32000
#define H3 3072
#define H2 2048
#define EH 1536

typedef unsigned short u16;
typedef unsigned int u32;
typedef unsigned long long u64;
typedef __attribute__((ext_vector_type(8))) short bf16x8;
typedef __attribute__((ext_vector_type(4))) float f32x4;

#define MFMA3(ACC, AH_, AL_, BH_, BL_)                                              \
    ACC = __builtin_amdgcn_mfma_f32_16x16x32_bf16(AL_, BH_, ACC, 0, 0, 0);          \
    ACC = __builtin_amdgcn_mfma_f32_16x16x32_bf16(AH_, BL_, ACC, 0, 0, 0);          \
    ACC = __builtin_amdgcn_mfma_f32_16x16x32_bf16(AH_, BH_, ACC, 0, 0, 0);

__device__ __forceinline__ void splitf(float x, u16& h, u16& l) {
    u32 xb = __float_as_uint(x);
    u32 hb = (xb + 0x7FFFu + ((xb >> 16) & 1u)) & 0xFFFF0000u;  // RNE bf16 (as f32 bits)
    h = (u16)(hb >> 16);
    float lf = x - __uint_as_float(hb);                          // exact residual
    u32 lb = __float_as_uint(lf);
    l = (u16)((lb + 0x7FFFu + ((lb >> 16) & 1u)) >> 16);
}

__device__ __forceinline__ float bf2f(u16 v) { return __uint_as_float(((u32)v) << 16); }

__device__ __forceinline__ void load_lds16(const void* g, void* l) {
    __builtin_amdgcn_global_load_lds((const __attribute__((address_space(1))) u32*)g,
                                     (__attribute__((address_space(3))) u32*)l, 16, 0, 0);
}

// ---- system-scope (coherence-point) accessors: bypass L1/L2, no fences needed ----
__device__ __forceinline__ bf16x8 ld_sys16(const u16* p) {
    union { bf16x8 v; u64 q[2]; } u;
    const u64* q = (const u64*)p;
    u.q[0] = __hip_atomic_load(q,     __ATOMIC_RELAXED, __HIP_MEMORY_SCOPE_SYSTEM);
    u.q[1] = __hip_atomic_load(q + 1, __ATOMIC_RELAXED, __HIP_MEMORY_SCOPE_SYSTEM);
    return u.v;
}
__device__ __forceinline__ float ld_sysf(const float* p) {
    return __hip_atomic_load(p, __ATOMIC_RELAXED, __HIP_MEMORY_SCOPE_SYSTEM);
}
__device__ __forceinline__ void st_sysf(float* p, float v) {
    __hip_atomic_store(p, v, __ATOMIC_RELAXED, __HIP_MEMORY_SCOPE_SYSTEM);
}
__device__ __forceinline__ void st_sysu16(u16* p, u16 v) {
    __hip_atomic_store(p, v, __ATOMIC_RELAXED, __HIP_MEMORY_SCOPE_SYSTEM);
}

// Fence-free grid barrier (R11-proven: ~4us). Cross-block data moves via sc0sc1
// system accessors so no L2 flush/invalidate is needed at the barrier.
__device__ __forceinline__ void gbar(int* cnt, int* flag, int nblk, int blk, int& gen) {
    __syncthreads();
    if (threadIdx.x == 0) {
        gen += 1;
        asm volatile("s_waitcnt vmcnt(0)" ::: "memory");
        __hip_atomic_fetch_add(&cnt[(blk & 7) << 5], 1, __ATOMIC_RELAXED,
                               __HIP_MEMORY_SCOPE_SYSTEM);
        if (blk == 0) {
            const int target = nblk * gen;
            for (;;) {
                int sum = 0;
#pragma unroll
                for (int j = 0; j < 8; ++j)
                    sum += __hip_atomic_load(&cnt[j << 5], __ATOMIC_RELAXED,
                                             __HIP_MEMORY_SCOPE_SYSTEM);
                if (sum >= target) break;
                __builtin_amdgcn_s_sleep(2);
            }
#pragma unroll
            for (int j = 0; j < 8; ++j)
                __hip_atomic_store(&flag[j << 5], gen, __ATOMIC_RELAXED,
                                   __HIP_MEMORY_SCOPE_SYSTEM);
        } else {
            while (__hip_atomic_load(&flag[(blk & 7) << 5], __ATOMIC_RELAXED,
                                     __HIP_MEMORY_SCOPE_SYSTEM) < gen)
                __builtin_amdgcn_s_sleep(2);
        }
    }
    __syncthreads();
}

// ---------------- embedding gather + split ----------------
__global__ void k_embed_src_split(const int* __restrict__ src, const float* __restrict__ emb,
                                  u16* __restrict__ hi, u16* __restrict__ lo) {
    int row = blockIdx.x;              // s*B + b
    int tok = src[row];
    int c = threadIdx.x * 4;
    float4 v = *reinterpret_cast<const float4*>(emb + (size_t)tok * E_ + c);
    ushort4 h, l;
    splitf(v.x, h.x, l.x); splitf(v.y, h.y, l.y);
    splitf(v.z, h.z, l.z); splitf(v.w, h.w, l.w);
    *reinterpret_cast<ushort4*>(hi + (size_t)row * E_ + c) = h;
    *reinterpret_cast<ushort4*>(lo + (size_t)row * E_ + c) = l;
}

__global__ void k_embed_dec_split(const int* __restrict__ src, const int* __restrict__ trg,
                                  const float* __restrict__ emb,
                                  u16* __restrict__ hi, u16* __restrict__ lo) {
    int row = blockIdx.x;              // t*B + b
    int t = row >> 5, b = row & 31;
    int tok = (t == 0) ? src[(S_ - 1) * B_ + b] : trg[(t - 1) * B_ + b];
    int c = threadIdx.x * 4;
    float4 v = *reinterpret_cast<const float4*>(emb + (size_t)tok * E_ + c);
    ushort4 h, l;
    splitf(v.x, h.x, l.x); splitf(v.y, h.y, l.y);
    splitf(v.z, h.z, l.z); splitf(v.w, h.w, l.w);
    *reinterpret_cast<ushort4*>(hi + (size_t)row * E_ + c) = h;
    *reinterpret_cast<ushort4*>(lo + (size_t)row * E_ + c) = l;
}

// ---------------- generic f32 -> bf16 hi/lo split ----------------
__global__ __launch_bounds__(256) void k_split(const float* __restrict__ in, int ld, int cols4,
                                               u16* __restrict__ hi, u16* __restrict__ lo) {
    int c4 = blockIdx.x * 256 + threadIdx.x;
    if (c4 >= cols4) return;
    size_t r = blockIdx.y;
    float4 v = *reinterpret_cast<const float4*>(in + r * ld + (size_t)c4 * 4);
    ushort4 h, l;
    splitf(v.x, h.x, l.x); splitf(v.y, h.y, l.y);
    splitf(v.z, h.z, l.z); splitf(v.w, h.w, l.w);
    size_t o = (r * cols4 + c4) * 4;
    *reinterpret_cast<ushort4*>(hi + o) = h;
    *reinterpret_cast<ushort4*>(lo + o) = l;
}

// ---------------- enc = enc_f + enc_b, plus split ----------------
__global__ __launch_bounds__(256) void k_split_sum_enc(
    const float* __restrict__ ef, const float* __restrict__ eb, float* __restrict__ es,
    u16* __restrict__ hi, u16* __restrict__ lo) {
    size_t r = blockIdx.y;
    int c4 = threadIdx.x * 4;
    float4 va = *reinterpret_cast<const float4*>(ef + r * H_ + c4);
    float4 vb = *reinterpret_cast<const float4*>(eb + r * H_ + c4);
    float4 v; v.x = va.x + vb.x; v.y = va.y + vb.y; v.z = va.z + vb.z; v.w = va.w + vb.w;
    *reinterpret_cast<float4*>(es + r * H_ + c4) = v;
    ushort4 h, l;
    splitf(v.x, h.x, l.x); splitf(v.y, h.y, l.y);
    splitf(v.z, h.z, l.z); splitf(v.w, h.w, l.w);
    *reinterpret_cast<ushort4*>(hi + r * H_ + c4) = h;
    *reinterpret_cast<ushort4*>(lo + r * H_ + c4) = l;
}

// ---------------- gate-interleaved weight split: dst row 3i+g = src row g*1024+i ----------------
__global__ void k_wsplit_perm(const float* __restrict__ src, int ld, int coff,
                              u16* __restrict__ hi, u16* __restrict__ lo) {
    int r = blockIdx.x;                // permuted row: 3i+g
    int i = r / 3, g = r - i * 3;
    const float* p = src + (size_t)(g * H_ + i) * ld + coff;
    int c = threadIdx.x * 4;
    float4 v = *reinterpret_cast<const float4*>(p + c);
    ushort4 h, l;
    splitf(v.x, h.x, l.x); splitf(v.y, h.y, l.y);
    splitf(v.z, h.z, l.z); splitf(v.w, h.w, l.w);
    *reinterpret_cast<ushort4*>(hi + (size_t)r * H_ + c) = h;
    *reinterpret_cast<ushort4*>(lo + (size_t)r * H_ + c) = l;
}

// ---------------- big split-bf16 MFMA GEMM (proven R2-R14) ----------------
__global__ __launch_bounds__(256, 2) void k_gemm_mfma3(
    const u16* __restrict__ Ah, const u16* __restrict__ Al,
    const u16* __restrict__ Bh, const u16* __restrict__ Bl,
    const float* __restrict__ bias, float* __restrict__ C,
    int ldc, int K)
{
    __shared__ u16 ls[4][128 * 32];
    const int tid = threadIdx.x;
    const int lane = tid & 63, w = tid >> 6;
    const int wr = w >> 1, wc = w & 1;
    const size_t m0 = (size_t)blockIdx.x * 128, n0 = (size_t)blockIdx.y * 128;

    const int c0 = (w * 2) * 64 + lane;
    const int r0 = c0 >> 2, kc0 = (c0 & 3) << 3;
    const size_t rstep = (size_t)16 * K;
    const u16* gAh = Ah + (m0 + r0) * K + kc0;
    const u16* gAl = Al + (m0 + r0) * K + kc0;
    const u16* gBh = Bh + (n0 + r0) * K + kc0;
    const u16* gBl = Bl + (n0 + r0) * K + kc0;
    const int lo0 = c0 * 8;

    const int frow = lane & 15, fk = (lane >> 4) << 3;
    const int offA = (wr * 64 + frow) * 32 + fk;
    const int offB = (wc * 64 + frow) * 32 + fk;

    f32x4 acc[4][4] = {};

    for (int k0 = 0; k0 < K; k0 += 32) {
        load_lds16(gAh + k0, &ls[0][lo0]);
        load_lds16(gAh + rstep + k0, &ls[0][lo0 + 512]);
        load_lds16(gAl + k0, &ls[1][lo0]);
        load_lds16(gAl + rstep + k0, &ls[1][lo0 + 512]);
        load_lds16(gBh + k0, &ls[2][lo0]);
        load_lds16(gBh + rstep + k0, &ls[2][lo0 + 512]);
        load_lds16(gBl + k0, &ls[3][lo0]);
        load_lds16(gBl + rstep + k0, &ls[3][lo0 + 512]);
        __syncthreads();

        bf16x8 fAh[4], fAl[4], fBh[4], fBl[4];
#pragma unroll
        for (int m = 0; m < 4; ++m) {
            fAh[m] = *reinterpret_cast<const bf16x8*>(&ls[0][offA + m * 512]);
            fAl[m] = *reinterpret_cast<const bf16x8*>(&ls[1][offA + m * 512]);
        }
#pragma unroll
        for (int n = 0; n < 4; ++n) {
            fBh[n] = *reinterpret_cast<const bf16x8*>(&ls[2][offB + n * 512]);
            fBl[n] = *reinterpret_cast<const bf16x8*>(&ls[3][offB + n * 512]);
        }
#pragma unroll
        for (int m = 0; m < 4; ++m)
#pragma unroll
            for (int n = 0; n < 4; ++n) {
                MFMA3(acc[m][n], fAh[m], fAl[m], fBh[n], fBl[n]);
            }
        __syncthreads();
    }

    const int crow0 = wr * 64 + ((lane >> 4) << 2);
    const int ccol0 = wc * 64 + (lane & 15);
#pragma unroll
    for (int n = 0; n < 4; ++n) {
        const size_t col = n0 + ccol0 + n * 16;
        const float bv = bias ? bias[col] : 0.f;
#pragma unroll
        for (int m = 0; m < 4; ++m)
#pragma unroll
            for (int r = 0; r < 4; ++r)
                C[(m0 + crow0 + m * 16 + r) * (size_t)ldc + col] = acc[m][n][r] + bv;
    }
}

// ---------------- head GEMM (R14, proven): 128x256 tile, B f32 + split in-kernel ----------------
__global__ __launch_bounds__(256, 2) void k_gemm_n2f(
    const u16* __restrict__ Ah, const u16* __restrict__ Al,
    const float* __restrict__ Bf,
    const float* __restrict__ bias, float* __restrict__ C,
    int ldc, int K)
{
    __shared__ u16 lsA[2][128 * 32];
    __shared__ u16 lsBh[256 * 32];
    __shared__ u16 lsBl[256 * 32];
    const int tid = threadIdx.x;
    const int lane = tid & 63, w = tid >> 6;
    const int wr = w >> 1, wc = w & 1;
    const size_t m0 = (size_t)blockIdx.x * 128, n0 = (size_t)blockIdx.y * 256;

    const int frow = lane & 15, fk = (lane >> 4) << 3;
    const int offA = (wr * 64 + frow) * 32 + fk;
    const int offB = (wc * 128 + frow) * 32 + fk;

    f32x4 acc[4][8] = {};

    for (int k0 = 0; k0 < K; k0 += 32) {
#pragma unroll
        for (int q = 0; q < 4; ++q) {
            const int chunk = (w + q * 4) * 64 + lane;
            const int local = chunk & 511;
            const u16* A = (chunk < 512) ? Ah : Al;
            load_lds16(A + (m0 + (local >> 2)) * K + k0 + ((local & 3) << 3),
                       &lsA[chunk >> 9][local * 8]);
        }
#pragma unroll
        for (int q = 0; q < 4; ++q) {
            const int c = tid + q * 256;
            const int row = c >> 2, k8 = (c & 3) << 3;
            const float* src = Bf + (size_t)(n0 + row) * K + k0 + k8;
            float4 v0 = *reinterpret_cast<const float4*>(src);
            float4 v1 = *reinterpret_cast<const float4*>(src + 4);
            union { ushort4 s[2]; bf16x8 v; } hh, ll;
            splitf(v0.x, hh.s[0].x, ll.s[0].x); splitf(v0.y, hh.s[0].y, ll.s[0].y);
            splitf(v0.z, hh.s[0].z, ll.s[0].z); splitf(v0.w, hh.s[0].w, ll.s[0].w);
            splitf(v1.x, hh.s[1].x, ll.s[1].x); splitf(v1.y, hh.s[1].y, ll.s[1].y);
            splitf(v1.z, hh.s[1].z, ll.s[1].z); splitf(v1.w, hh.s[1].w, ll.s[1].w);
            *reinterpret_cast<bf16x8*>(&lsBh[row * 32 + k8]) = hh.v;
            *reinterpret_cast<bf16x8*>(&lsBl[row * 32 + k8]) = ll.v;
        }
        __syncthreads();

        bf16x8 fAh[4], fAl[4];
#pragma unroll
        for (int m = 0; m < 4; ++m) {
            fAh[m] = *reinterpret_cast<const bf16x8*>(&lsA[0][offA + m * 512]);
            fAl[m] = *reinterpret_cast<const bf16x8*>(&lsA[1][offA + m * 512]);
        }
#pragma unroll
        for (int n = 0; n < 8; ++n) {
            bf16x8 fBh = *reinterpret_cast<const bf16x8*>(&lsBh[offB + n * 512]);
            bf16x8 fBl = *reinterpret_cast<const bf16x8*>(&lsBl[offB + n * 512]);
#pragma unroll
            for (int m = 0; m < 4; ++m) {
                MFMA3(acc[m][n], fAh[m], fAl[m], fBh, fBl);
            }
        }
        __syncthreads();
    }

    const int crow0 = wr * 64 + ((lane >> 4) << 2);
    const int ccol0 = wc * 128 + (lane & 15);
#pragma unroll
    for (int n = 0; n < 8; ++n) {
        const size_t col = n0 + ccol0 + n * 16;
        const float bv = bias ? bias[col] : 0.f;
#pragma unroll
        for (int m = 0; m < 4; ++m)
#pragma unroll
            for (int r = 0; r < 4; ++r)
                C[(m0 + crow0 + m * 16 + r) * (size_t)ldc + col] = acc[m][n][r] + bv;
    }
}

// ================= persistent encoder (R9/R11, proven) =================
__global__ __launch_bounds__(256) void k_enc_persist(
    const u16* __restrict__ whhf_h, const u16* __restrict__ whhf_l,
    const u16* __restrict__ whhb_h, const u16* __restrict__ whhb_l,
    const float* __restrict__ gi_f, const float* __restrict__ gi_b,
    const float* __restrict__ bhh_f, const float* __restrict__ bhh_b,
    u16* __restrict__ hfH0, u16* __restrict__ hfL0,
    u16* __restrict__ hfH1, u16* __restrict__ hfL1,
    u16* __restrict__ hbH0, u16* __restrict__ hbL0,
    u16* __restrict__ hbH1, u16* __restrict__ hbL1,
    float* __restrict__ enc_f, float* __restrict__ enc_b,
    int* __restrict__ cnt, int* __restrict__ flag)
{
    __shared__ __align__(16) char smem[145792];
    u16* lAh  = (u16*)smem;                    // [32][1024] staged h hi, XOR-swizzled
    u16* lAl  = (u16*)(smem + 65536);          // lo
    float* ex0 = (float*)(smem + 131072);      // [48][33] k-half 0
    float* ex1 = (float*)(smem + 137408);      // [48][33] k-half 1
    float* hloc = (float*)(smem + 143744);     // [32][16] f32 state

    const int blk = blockIdx.x, tid = threadIdx.x;
    const int lane = tid & 63, w = tid >> 6;
    const int dir = blk >> 6, c = blk & 63;
    const int i0 = c * 16;
    const u16* WH = (dir ? whhb_h : whhf_h) + (size_t)c * 48 * 1024;
    const u16* WL = (dir ? whhb_l : whhf_l) + (size_t)c * 48 * 1024;
    const float* gi = dir ? gi_b : gi_f;
    const float* bhh = dir ? bhh_b : bhh_f;
    float* encd = dir ? enc_b : enc_f;
    int gen = 0;

    for (int q = tid; q < 512; q += 256) hloc[q] = 0.f;

    const int frow = lane & 15, fk8 = (lane >> 4) << 3;
    const int cb = lane & 15, rb0 = (lane >> 4) << 2;

    for (int t = 0; t < 64; ++t) {
        const int a = t & 1;
        const u16* rH = dir ? (a ? hbH1 : hbH0) : (a ? hfH1 : hfH0);
        const u16* rL = dir ? (a ? hbL1 : hbL0) : (a ? hfL1 : hfL0);
        u16* oH = dir ? (a ? hbH0 : hbH1) : (a ? hfH0 : hfH1);
        u16* oL = dir ? (a ? hbL0 : hbL1) : (a ? hfL0 : hfL1);
        const int s = dir ? 63 - t : t;

#pragma unroll
        for (int ch0 = 0; ch0 < 4096; ch0 += 256) {
            int ch = ch0 + tid;
            int r = ch >> 7, kc = (ch & 127) << 3;
            int sw = kc ^ ((r & 7) << 3);
            *(bf16x8*)&lAh[r * 1024 + sw] = ld_sys16(&rH[r * 1024 + kc]);
            *(bf16x8*)&lAl[r * 1024 + sw] = ld_sys16(&rL[r * 1024 + kc]);
        }
        __syncthreads();

#pragma unroll
        for (int jj = 0; jj < 3; ++jj) {
            const int j = w * 3 + jj;
            const int m = j & 1;
            const int n = (j >> 1) % 3;
            const int kh = j / 6;
            const int arow = m * 16 + frow;
            const int asw = (arow & 7) << 3;
            const u16* gBh = WH + (size_t)(n * 16 + frow) * 1024;
            const u16* gBl = WL + (size_t)(n * 16 + frow) * 1024;
            f32x4 acc = {};
            const int ke = kh * 512 + 512;
#pragma unroll 4
            for (int k0 = kh * 512; k0 < ke; k0 += 32) {
                int kc = k0 + fk8;
                bf16x8 aH = *(const bf16x8*)&lAh[arow * 1024 + (kc ^ asw)];
                bf16x8 aL = *(const bf16x8*)&lAl[arow * 1024 + (kc ^ asw)];
                bf16x8 bH = *(const bf16x8*)&gBh[kc];
                bf16x8 bL = *(const bf16x8*)&gBl[kc];
                MFMA3(acc, aH, aL, bH, bL);
            }
            float* exd = kh ? ex1 : ex0;
            const int pc = n * 16 + cb;
#pragma unroll
            for (int r = 0; r < 4; ++r)
                exd[pc * 33 + m * 16 + rb0 + r] = acc[r];
        }
        __syncthreads();

        {
            const int il = tid & 15, bb = tid >> 4;
            const int i = i0 + il;
#pragma unroll
            for (int q = 0; q < 2; ++q) {
                int b = bb + q * 16;
                float ghr = ex0[(3 * il + 0) * 33 + b] + ex1[(3 * il + 0) * 33 + b] + bhh[i];
                float ghz = ex0[(3 * il + 1) * 33 + b] + ex1[(3 * il + 1) * 33 + b] + bhh[H_ + i];
                float ghn = ex0[(3 * il + 2) * 33 + b] + ex1[(3 * il + 2) * 33 + b] + bhh[2 * H_ + i];
                size_t gio = (size_t)(s * B_ + b) * H3 + i;
                float gir = gi[gio], giz = gi[gio + H_], gin = gi[gio + 2 * H_];
                float rr = 1.f / (1.f + expf(-(gir + ghr)));
                float zz = 1.f / (1.f + expf(-(giz + ghz)));
                float nn = tanhf(gin + rr * ghn);
                float hold = hloc[b * 16 + il];
                float hnew = (1.f - zz) * nn + zz * hold;
                hloc[b * 16 + il] = hnew;
                u16 hh, hl; splitf(hnew, hh, hl);
                st_sysu16(&oH[b * 1024 + i], hh);
                st_sysu16(&oL[b * 1024 + i], hl);
                encd[((size_t)b * 64 + s) * H_ + i] = hnew;
            }
        }
        gbar(cnt, flag, 128, blk, gen);
    }
}

// ================= persistent decoder (R11 structure + R15 ep-prefetch/hwa-hoist) =================
__global__ __launch_bounds__(256) void k_dec_persist(
    const u16* __restrict__ wah, const u16* __restrict__ wal,
    const u16* __restrict__ wgh, const u16* __restrict__ wgl,
    const u16* __restrict__ wdh, const u16* __restrict__ wdl,
    const float* __restrict__ gi_e, const float* __restrict__ bhh_d,
    const float* __restrict__ ep, const float* __restrict__ vvec,
    const float* __restrict__ enc,
    u16* __restrict__ hH, u16* __restrict__ hL,
    float* __restrict__ hwa, float* __restrict__ scores,
    u16* __restrict__ ctxH, u16* __restrict__ ctxL,
    float* __restrict__ states, int* __restrict__ cnt, int* __restrict__ flag)
{
    __shared__ __align__(16) char smem[140288];
    u16* lWH  = (u16*)smem;                    // [16][1024] rows 0-3 hWa, 4-15 ghd (swizzled)
    u16* lWL  = (u16*)(smem + 32768);
    u16* lDH  = (u16*)(smem + 65536);          // [16][1024] wdc hi (12 + 4 pad)
    float* lenc = (float*)(smem + 98304);      // [64][128]
    float* ex1a = (float*)(smem + 131072);     // [32][16] PhA partial (k-half 0)
    float* ex1b = (float*)(smem + 133120);
    float* ex2a = (float*)(smem + 135168);     // PhD partials
    float* ex2b = (float*)(smem + 137216);
    float* aw   = (float*)(smem + 139264);     // [64]
    float* hloc = (float*)(smem + 139520);     // [128] f32 state for owned (b,u)

    const int bid = blockIdx.x, tid = threadIdx.x;
    const int lane = tid & 63, w = tid >> 6;
    const int frow = lane & 15, fk8 = (lane >> 4) << 3;
    const int b3 = bid >> 3, sl = bid & 7;
    int gen = 0;

    for (int ch = tid; ch < 2048; ch += 256) {
        int r = ch >> 7, kc = (ch & 127) << 3;
        int sw = kc ^ ((r & 7) << 3);
        const u16 *sH, *sL;
        if (r < 4) { sH = wah + ((size_t)bid * 4 + r) * 1024;
                     sL = wal + ((size_t)bid * 4 + r) * 1024; }
        else       { sH = wgh + ((size_t)bid * 12 + r - 4) * 1024;
                     sL = wgl + ((size_t)bid * 12 + r - 4) * 1024; }
        *(bf16x8*)&lWH[r * 1024 + sw] = *(const bf16x8*)&sH[kc];
        *(bf16x8*)&lWL[r * 1024 + sw] = *(const bf16x8*)&sL[kc];
    }
    for (int ch = tid; ch < 2048; ch += 256) {
        int r = ch >> 7, kc = (ch & 127) << 3;
        int sw = kc ^ ((r & 7) << 3);
        int rowg = (r < 12) ? bid * 12 + r : bid * 12;
        *(bf16x8*)&lDH[r * 1024 + sw] = *(const bf16x8*)&wdh[(size_t)rowg * 1024 + kc];
    }
    for (int ch = tid; ch < 2048; ch += 256) {
        int s = ch >> 5, c4 = (ch & 31) << 2;
        *(float4*)&lenc[s * 128 + c4] =
            *(const float4*)&enc[((size_t)b3 * 64 + s) * 1024 + sl * 128 + c4];
    }
    if (tid < 128) {
        int b = tid >> 2, u = bid * 4 + (tid & 3);
        hloc[tid] = bf2f(hH[b * 1024 + u]) + bf2f(hL[b * 1024 + u]);
    }
    float vreg[16];
#pragma unroll
    for (int i = 0; i < 16; ++i) vreg[i] = vvec[lane + i * 64];
    __syncthreads();

    const int mt = w & 1, kh = w >> 1;
    const int bsw = (frow & 7) << 3;
    const int rowg = (frow < 12) ? bid * 12 + frow : bid * 12;
    const u16* gDl = wdl + (size_t)rowg * 1024;
    const int exw = (mt * 16 + ((lane >> 4) << 2)) * 16 + frow;
    // ep rows this block scores each step (step-invariant addresses)
    const float* epr0 = ep + ((size_t)b3 * 64 + sl * 8 + w * 2) * 1024;
    const float* epr1 = epr0 + 1024;

    for (int t = 0; t < 64; ++t) {
        // ---- PhA (+ overlapped ep prefetch for PhB) ----
        float pe0[16], pe1[16];
#pragma unroll
        for (int i = 0; i < 16; ++i) pe0[i] = epr0[lane + i * 64];
#pragma unroll
        for (int i = 0; i < 16; ++i) pe1[i] = epr1[lane + i * 64];
        {
            float* exA = kh ? ex1b : ex1a;
            f32x4 acc = {};
            const int ar0 = (mt * 16 + frow) * 1024;
            const int ke = kh * 512 + 512;
#pragma unroll 4
            for (int k0 = kh * 512; k0 < ke; k0 += 32) {
                int kc = k0 + fk8;
                bf16x8 aH = ld_sys16(&hH[ar0 + kc]);
                bf16x8 aL = ld_sys16(&hL[ar0 + kc]);
                bf16x8 bH = *(const bf16x8*)&lWH[frow * 1024 + (kc ^ bsw)];
                bf16x8 bL = *(const bf16x8*)&lWL[frow * 1024 + (kc ^ bsw)];
                MFMA3(acc, aH, aL, bH, bL);
            }
#pragma unroll
            for (int r = 0; r < 4; ++r) exA[exw + r * 16] = acc[r];
        }
        __syncthreads();
        if (tid < 128) {
            int b = tid >> 2, col = tid & 3;
            st_sysf(&hwa[b * 1024 + bid * 4 + col],
                    ex1a[b * 16 + col] + ex1b[b * 16 + col]);
        }
        gbar(cnt, flag, 256, bid, gen);

        // ---- PhB (hwa hoisted; ep from prefetched registers) ----
        {
            float hreg[16];
#pragma unroll
            for (int i = 0; i < 16; ++i)
                hreg[i] = ld_sysf(&hwa[b3 * 1024 + lane + i * 64]);
            float a2 = 0.f, a3 = 0.f;
#pragma unroll
            for (int i = 0; i < 16; ++i) {
                a2 += fmaxf(hreg[i] + pe0[i], 0.f) * vreg[i];
                a3 += fmaxf(hreg[i] + pe1[i], 0.f) * vreg[i];
            }
            for (int off = 32; off; off >>= 1) a2 += __shfl_down(a2, off);
            for (int off = 32; off; off >>= 1) a3 += __shfl_down(a3, off);
            if (lane == 0) {
                st_sysf(&scores[b3 * 64 + sl * 8 + w * 2], a2);
                st_sysf(&scores[b3 * 64 + sl * 8 + w * 2 + 1], a3);
            }
        }
        gbar(cnt, flag, 256, bid, gen);

        // ---- PhC ----
        if (tid < 64) {
            float sc = ld_sysf(&scores[b3 * 64 + tid]);
            float m = sc;
            for (int off = 32; off; off >>= 1) m = fmaxf(m, __shfl_xor(m, off));
            float e = expf(sc - m);
            float sum = e;
            for (int off = 32; off; off >>= 1) sum += __shfl_xor(sum, off);
            aw[tid] = e / sum;
        }
        __syncthreads();
        if (tid < 128) {
            int c = tid;
            float x = 0.f;
#pragma unroll 8
            for (int s = 0; s < 64; ++s) x += aw[s] * lenc[s * 128 + c];
            states[((size_t)t * 32 + b3) * 2048 + 1024 + sl * 128 + c] = x;
            u16 hh, hl; splitf(x, hh, hl);
            st_sysu16(&ctxH[b3 * 1024 + sl * 128 + c], hh);
            st_sysu16(&ctxL[b3 * 1024 + sl * 128 + c], hl);
        }
        gbar(cnt, flag, 256, bid, gen);

        // ---- PhD ----
        {
            float* exD = kh ? ex2b : ex2a;
            f32x4 acc = {};
            const int ar0 = (mt * 16 + frow) * 1024;
            const int ke = kh * 512 + 512;
#pragma unroll 4
            for (int k0 = kh * 512; k0 < ke; k0 += 32) {
                int kc = k0 + fk8;
                bf16x8 aH = ld_sys16(&ctxH[ar0 + kc]);
                bf16x8 aL = ld_sys16(&ctxL[ar0 + kc]);
                bf16x8 bH = *(const bf16x8*)&lDH[frow * 1024 + (kc ^ bsw)];
                bf16x8 bL = *(const bf16x8*)&gDl[kc];
                MFMA3(acc, aH, aL, bH, bL);
            }
#pragma unroll
            for (int r = 0; r < 4; ++r) exD[exw + r * 16] = acc[r];
        }
        __syncthreads();
        if (tid < 128) {
            int b = tid >> 2, ui = tid & 3;
            int u = bid * 4 + ui;
            float gicr = ex2a[b * 16 + 3 * ui + 0] + ex2b[b * 16 + 3 * ui + 0];
            float gicz = ex2a[b * 16 + 3 * ui + 1] + ex2b[b * 16 + 3 * ui + 1];
            float gicn = ex2a[b * 16 + 3 * ui + 2] + ex2b[b * 16 + 3 * ui + 2];
            float ghr = ex1a[b * 16 + 4 + 3 * ui + 0] + ex1b[b * 16 + 4 + 3 * ui + 0] + bhh_d[u];
            float ghz = ex1a[b * 16 + 4 + 3 * ui + 1] + ex1b[b * 16 + 4 + 3 * ui + 1] + bhh_d[H_ + u];
            float ghn = ex1a[b * 16 + 4 + 3 * ui + 2] + ex1b[b * 16 + 4 + 3 * ui + 2] + bhh_d[2 * H_ + u];
            size_t ge = ((size_t)t * 32 + b) * 3072;
            float gir = gi_e[ge + u] + gicr;
            float giz = gi_e[ge + 1024 + u] + gicz;
            float gin = gi_e[ge + 2048 + u] + gicn;
            float rr = 1.f / (1.f + expf(-(gir + ghr)));
            float zz = 1.f / (1.f + expf(-(giz + ghz)));
            float nn = tanhf(gin + rr * ghn);
            float hold = hloc[tid];
            float hnew = (1.f - zz) * nn + zz * hold;
            hloc[tid] = hnew;
            u16 hh, hl; splitf(hnew, hh, hl);
            st_sysu16(&hH[b * 1024 + u], hh);
            st_sysu16(&hL[b * 1024 + u], hl);
            states[((size_t)t * 32 + b) * 2048 + u] = hnew;
        }
        gbar(cnt, flag, 256, bid, gen);
    }
}

extern "C" void kernel_launch(void* const* d_in, const int* in_sizes, int n_in,
                              void* d_out, int out_size, void* d_ws, size_t ws_size,
                              hipStream_t stream) {
    const int*   src   = (const int*)d_in[0];
    const int*   trg   = (const int*)d_in[1];
    const float* emb   = (const float*)d_in[2];
    const float* Wih_f = (const float*)d_in[3];
    const float* Whh_f = (const float*)d_in[4];
    const float* bih_f = (const float*)d_in[5];
    const float* bhh_f = (const float*)d_in[6];
    const float* Wih_b = (const float*)d_in[7];
    const float* Whh_b = (const float*)d_in[8];
    const float* bih_b = (const float*)d_in[9];
    const float* bhh_b = (const float*)d_in[10];
    const float* Wa    = (const float*)d_in[11];
    const float* ba    = (const float*)d_in[12];
    const float* vv    = (const float*)d_in[13];
    const float* Wih_d = (const float*)d_in[14];
    const float* Whh_d = (const float*)d_in[15];
    const float* bih_d = (const float*)d_in[16];
    const float* bhh_d = (const float*)d_in[17];
    const float* Wout  = (const float*)d_in[18];
    const float* bout  = (const float*)d_in[19];
    float* out = (float*)d_out;
    (void)in_sizes; (void)n_in; (void)out_size; (void)ws_size;

    float* w = (float*)d_ws;
    size_t o = 0;
    auto alloc = [&](size_t n) { float* p = w + o; o += n; return p; };
    float* gi_f  = alloc((size_t)S_ * B_ * H3);      // encoder fwd gi; reused as gi_e
    float* gi_b  = alloc((size_t)S_ * B_ * H3);      // encoder bwd gi; reused as states
    float* enc_f = alloc((size_t)B_ * S_ * H_);
    float* enc_b = alloc((size_t)B_ * S_ * H_);
    float* enc   = alloc((size_t)B_ * S_ * H_);
    float* ep    = alloc((size_t)B_ * S_ * H_);
    float* hwa   = alloc((size_t)B_ * H_);
    float* scores = alloc(B_ * S_);
    float* barf  = alloc(1024);
    int* cntE  = (int*)barf;
    int* flagE = cntE + 256;
    int* cntD  = cntE + 512;
    int* flagD = cntE + 768;
    float* gi_e   = gi_f;
    float* states = gi_b;

    u16* wu = (u16*)(w + o);
    size_t ou = 0;
    auto alloc16 = [&](size_t n) { u16* p = wu + ou; ou += n; return p; };
    u16* semb_h  = alloc16((size_t)S_ * B_ * E_);  u16* semb_l  = alloc16((size_t)S_ * B_ * E_);
    u16* demb_h  = alloc16((size_t)T_ * B_ * E_);  u16* demb_l  = alloc16((size_t)T_ * B_ * E_);
    u16* wihf_h  = alloc16((size_t)H3 * E_);       u16* wihf_l  = alloc16((size_t)H3 * E_);
    u16* wihb_h  = alloc16((size_t)H3 * E_);       u16* wihb_l  = alloc16((size_t)H3 * E_);
    u16* wihd_h  = alloc16((size_t)H3 * E_);       u16* wihd_l  = alloc16((size_t)H3 * E_);
    u16* wae_h   = alloc16((size_t)H_ * H_);       u16* wae_l   = alloc16((size_t)H_ * H_);
    u16* enc_h   = alloc16((size_t)B_ * S_ * H_);  u16* enc_l   = alloc16((size_t)B_ * S_ * H_);
    u16* st_h    = alloc16((size_t)T_ * B_ * H2);  u16* st_l    = alloc16((size_t)T_ * B_ * H2);
    u16* whhf_h  = alloc16((size_t)H3 * H_);       u16* whhf_l  = alloc16((size_t)H3 * H_);
    u16* whhb_h  = alloc16((size_t)H3 * H_);       u16* whhb_l  = alloc16((size_t)H3 * H_);
    u16* wgh     = alloc16((size_t)H3 * H_);       u16* wgl     = alloc16((size_t)H3 * H_);   // Whh_d perm
    u16* wdh     = alloc16((size_t)H3 * H_);       u16* wdl     = alloc16((size_t)H3 * H_);   // Wihd ctx perm
    u16* wah     = alloc16((size_t)H_ * H_);       u16* wal     = alloc16((size_t)H_ * H_);   // Wa h-part
    u16* hsf_h[2] = {alloc16(B_ * H_), alloc16(B_ * H_)};
    u16* hsf_l[2] = {alloc16(B_ * H_), alloc16(B_ * H_)};
    u16* hsb_h[2] = {alloc16(B_ * H_), alloc16(B_ * H_)};
    u16* hsb_l[2] = {alloc16(B_ * H_), alloc16(B_ * H_)};
    u16* ctx_h   = alloc16(B_ * H_);               u16* ctx_l   = alloc16(B_ * H_);

    // ---- init ----
    hipMemsetAsync(barf, 0, 1024 * sizeof(float), stream);
    hipMemsetAsync(hsf_h[0], 0, B_ * H_ * sizeof(u16), stream);
    hipMemsetAsync(hsf_l[0], 0, B_ * H_ * sizeof(u16), stream);
    hipMemsetAsync(hsb_h[0], 0, B_ * H_ * sizeof(u16), stream);
    hipMemsetAsync(hsb_l[0], 0, B_ * H_ * sizeof(u16), stream);

    // ---- embeddings ----
    k_embed_src_split<<<S_ * B_, 128, 0, stream>>>(src, emb, semb_h, semb_l);
    k_embed_dec_split<<<T_ * B_, 128, 0, stream>>>(src, trg, emb, demb_h, demb_l);

    // ---- weight splits ----
    k_split<<<dim3(1, H3), 256, 0, stream>>>(Wih_f, E_, E_ / 4, wihf_h, wihf_l);
    k_split<<<dim3(1, H3), 256, 0, stream>>>(Wih_b, E_, E_ / 4, wihb_h, wihb_l);
    k_split<<<dim3(1, H3), 256, 0, stream>>>(Wih_d, EH, E_ / 4, wihd_h, wihd_l);
    k_split<<<dim3(1, H_), 256, 0, stream>>>(Wa + H_, H2, H_ / 4, wae_h, wae_l);
    k_split<<<dim3(1, H_), 256, 0, stream>>>(Wa, H2, H_ / 4, wah, wal);
    k_wsplit_perm<<<H3, 256, 0, stream>>>(Whh_f, H_, 0, whhf_h, whhf_l);
    k_wsplit_perm<<<H3, 256, 0, stream>>>(Whh_b, H_, 0, whhb_h, whhb_l);
    k_wsplit_perm<<<H3, 256, 0, stream>>>(Whh_d, H_, 0, wgh, wgl);
    k_wsplit_perm<<<H3, 256, 0, stream>>>(Wih_d, EH, E_, wdh, wdl);

    // ---- encoder input projections ----
    k_gemm_mfma3<<<dim3(16, 24), 256, 0, stream>>>(semb_h, semb_l, wihf_h, wihf_l,
                                                   bih_f, gi_f, H3, E_);
    k_gemm_mfma3<<<dim3(16, 24), 256, 0, stream>>>(semb_h, semb_l, wihb_h, wihb_l,
                                                   bih_b, gi_b, H3, E_);

    // ---- encoder: persistent, LDS-staged h ----
    k_enc_persist<<<128, 256, 0, stream>>>(
        whhf_h, whhf_l, whhb_h, whhb_l, gi_f, gi_b, bhh_f, bhh_b,
        hsf_h[0], hsf_l[0], hsf_h[1], hsf_l[1],
        hsb_h[0], hsb_l[0], hsb_h[1], hsb_l[1],
        enc_f, enc_b, cntE, flagE);

    // ---- merge enc dirs + split; ep precompute; decoder emb projection ----
    k_split_sum_enc<<<dim3(1, B_ * S_), 256, 0, stream>>>(enc_f, enc_b, enc, enc_h, enc_l);
    k_gemm_mfma3<<<dim3(16, 8), 256, 0, stream>>>(enc_h, enc_l, wae_h, wae_l,
                                                  ba, ep, H_, H_);
    k_gemm_mfma3<<<dim3(16, 24), 256, 0, stream>>>(demb_h, demb_l, wihd_h, wihd_l,
                                                   bih_d, gi_e, H3, E_);

    // ---- decoder: persistent, fence-free sc1 protocol (R11+R15) ----
    k_dec_persist<<<256, 256, 0, stream>>>(
        wah, wal, wgh, wgl, wdh, wdl, gi_e, bhh_d, ep, vv, enc,
        hsf_h[0], hsf_l[0], hwa, scores, ctx_h, ctx_l, states, cntD, flagD);

    // ---- output head: single launch over full vocab (R15) ----
    k_split<<<dim3(2, T_ * B_), 256, 0, stream>>>(states, H2, H2 / 4, st_h, st_l);
    k_gemm_n2f<<<dim3(16, 125), 256, 0, stream>>>(st_h, st_l, Wout, bout, out, V_, H2);
}

// Round 16
// 3997.862 us; speedup vs baseline: 1.1898x; 1.0179x over previous
//
#include <hip/hip_runtime.h>
#include <hip/hip_bf16.h>

#define S_ 64
#define T_ 64
#define B_ 32
#define E_ 512
#define H_ 1024
#define V_ 32000
#define H3 3072
#define H2 2048
#define EH 1536

typedef unsigned short u16;
typedef unsigned int u32;
typedef unsigned long long u64;
typedef __attribute__((ext_vector_type(8))) short bf16x8;
typedef __attribute__((ext_vector_type(4))) float f32x4;

#define MFMA3(ACC, AH_, AL_, BH_, BL_)                                              \
    ACC = __builtin_amdgcn_mfma_f32_16x16x32_bf16(AL_, BH_, ACC, 0, 0, 0);          \
    ACC = __builtin_amdgcn_mfma_f32_16x16x32_bf16(AH_, BL_, ACC, 0, 0, 0);          \
    ACC = __builtin_amdgcn_mfma_f32_16x16x32_bf16(AH_, BH_, ACC, 0, 0, 0);

__device__ __forceinline__ void splitf(float x, u16& h, u16& l) {
    u32 xb = __float_as_uint(x);
    u32 hb = (xb + 0x7FFFu + ((xb >> 16) & 1u)) & 0xFFFF0000u;  // RNE bf16 (as f32 bits)
    h = (u16)(hb >> 16);
    float lf = x - __uint_as_float(hb);                          // exact residual
    u32 lb = __float_as_uint(lf);
    l = (u16)((lb + 0x7FFFu + ((lb >> 16) & 1u)) >> 16);
}

__device__ __forceinline__ float bf2f(u16 v) { return __uint_as_float(((u32)v) << 16); }

__device__ __forceinline__ void load_lds16(const void* g, void* l) {
    __builtin_amdgcn_global_load_lds((const __attribute__((address_space(1))) u32*)g,
                                     (__attribute__((address_space(3))) u32*)l, 16, 0, 0);
}

// ---- system-scope (coherence-point) accessors: bypass L1/L2, no fences needed ----
__device__ __forceinline__ bf16x8 ld_sys16(const u16* p) {
    union { bf16x8 v; u64 q[2]; } u;
    const u64* q = (const u64*)p;
    u.q[0] = __hip_atomic_load(q,     __ATOMIC_RELAXED, __HIP_MEMORY_SCOPE_SYSTEM);
    u.q[1] = __hip_atomic_load(q + 1, __ATOMIC_RELAXED, __HIP_MEMORY_SCOPE_SYSTEM);
    return u.v;
}
__device__ __forceinline__ float ld_sysf(const float* p) {
    return __hip_atomic_load(p, __ATOMIC_RELAXED, __HIP_MEMORY_SCOPE_SYSTEM);
}
__device__ __forceinline__ void st_sysf(float* p, float v) {
    __hip_atomic_store(p, v, __ATOMIC_RELAXED, __HIP_MEMORY_SCOPE_SYSTEM);
}
__device__ __forceinline__ void st_sysu16(u16* p, u16 v) {
    __hip_atomic_store(p, v, __ATOMIC_RELAXED, __HIP_MEMORY_SCOPE_SYSTEM);
}

// Fence-free GLOBAL grid barrier (R11-proven: ~4us).
__device__ __forceinline__ void gbar(int* cnt, int* flag, int nblk, int blk, int& gen) {
    __syncthreads();
    if (threadIdx.x == 0) {
        gen += 1;
        asm volatile("s_waitcnt vmcnt(0)" ::: "memory");
        __hip_atomic_fetch_add(&cnt[(blk & 7) << 5], 1, __ATOMIC_RELAXED,
                               __HIP_MEMORY_SCOPE_SYSTEM);
        if (blk == 0) {
            const int target = nblk * gen;
            for (;;) {
                int sum = 0;
#pragma unroll
                for (int j = 0; j < 8; ++j)
                    sum += __hip_atomic_load(&cnt[j << 5], __ATOMIC_RELAXED,
                                             __HIP_MEMORY_SCOPE_SYSTEM);
                if (sum >= target) break;
                __builtin_amdgcn_s_sleep(2);
            }
#pragma unroll
            for (int j = 0; j < 8; ++j)
                __hip_atomic_store(&flag[j << 5], gen, __ATOMIC_RELAXED,
                                   __HIP_MEMORY_SCOPE_SYSTEM);
        } else {
            while (__hip_atomic_load(&flag[(blk & 7) << 5], __ATOMIC_RELAXED,
                                     __HIP_MEMORY_SCOPE_SYSTEM) < gen)
                __builtin_amdgcn_s_sleep(2);
        }
    }
    __syncthreads();
}

// GROUP barrier (R16): n blocks of one group arrive+poll a single cacheline.
// Valid when the data synced is produced AND consumed only within the group.
__device__ __forceinline__ void gbar_grp(int* cnt, int grp, int n, int& gen) {
    __syncthreads();
    if (threadIdx.x == 0) {
        gen += 1;
        asm volatile("s_waitcnt vmcnt(0)" ::: "memory");
        __hip_atomic_fetch_add(&cnt[grp << 5], 1, __ATOMIC_RELAXED,
                               __HIP_MEMORY_SCOPE_SYSTEM);
        const int target = n * gen;
        while (__hip_atomic_load(&cnt[grp << 5], __ATOMIC_RELAXED,
                                 __HIP_MEMORY_SCOPE_SYSTEM) < target)
            __builtin_amdgcn_s_sleep(1);
    }
    __syncthreads();
}

// ---------------- embedding gather + split ----------------
__global__ void k_embed_src_split(const int* __restrict__ src, const float* __restrict__ emb,
                                  u16* __restrict__ hi, u16* __restrict__ lo) {
    int row = blockIdx.x;              // s*B + b
    int tok = src[row];
    int c = threadIdx.x * 4;
    float4 v = *reinterpret_cast<const float4*>(emb + (size_t)tok * E_ + c);
    ushort4 h, l;
    splitf(v.x, h.x, l.x); splitf(v.y, h.y, l.y);
    splitf(v.z, h.z, l.z); splitf(v.w, h.w, l.w);
    *reinterpret_cast<ushort4*>(hi + (size_t)row * E_ + c) = h;
    *reinterpret_cast<ushort4*>(lo + (size_t)row * E_ + c) = l;
}

__global__ void k_embed_dec_split(const int* __restrict__ src, const int* __restrict__ trg,
                                  const float* __restrict__ emb,
                                  u16* __restrict__ hi, u16* __restrict__ lo) {
    int row = blockIdx.x;              // t*B + b
    int t = row >> 5, b = row & 31;
    int tok = (t == 0) ? src[(S_ - 1) * B_ + b] : trg[(t - 1) * B_ + b];
    int c = threadIdx.x * 4;
    float4 v = *reinterpret_cast<const float4*>(emb + (size_t)tok * E_ + c);
    ushort4 h, l;
    splitf(v.x, h.x, l.x); splitf(v.y, h.y, l.y);
    splitf(v.z, h.z, l.z); splitf(v.w, h.w, l.w);
    *reinterpret_cast<ushort4*>(hi + (size_t)row * E_ + c) = h;
    *reinterpret_cast<ushort4*>(lo + (size_t)row * E_ + c) = l;
}

// ---------------- generic f32 -> bf16 hi/lo split ----------------
__global__ __launch_bounds__(256) void k_split(const float* __restrict__ in, int ld, int cols4,
                                               u16* __restrict__ hi, u16* __restrict__ lo) {
    int c4 = blockIdx.x * 256 + threadIdx.x;
    if (c4 >= cols4) return;
    size_t r = blockIdx.y;
    float4 v = *reinterpret_cast<const float4*>(in + r * ld + (size_t)c4 * 4);
    ushort4 h, l;
    splitf(v.x, h.x, l.x); splitf(v.y, h.y, l.y);
    splitf(v.z, h.z, l.z); splitf(v.w, h.w, l.w);
    size_t o = (r * cols4 + c4) * 4;
    *reinterpret_cast<ushort4*>(hi + o) = h;
    *reinterpret_cast<ushort4*>(lo + o) = l;
}

// ---------------- enc = enc_f + enc_b, plus split ----------------
__global__ __launch_bounds__(256) void k_split_sum_enc(
    const float* __restrict__ ef, const float* __restrict__ eb, float* __restrict__ es,
    u16* __restrict__ hi, u16* __restrict__ lo) {
    size_t r = blockIdx.y;
    int c4 = threadIdx.x * 4;
    float4 va = *reinterpret_cast<const float4*>(ef + r * H_ + c4);
    float4 vb = *reinterpret_cast<const float4*>(eb + r * H_ + c4);
    float4 v; v.x = va.x + vb.x; v.y = va.y + vb.y; v.z = va.z + vb.z; v.w = va.w + vb.w;
    *reinterpret_cast<float4*>(es + r * H_ + c4) = v;
    ushort4 h, l;
    splitf(v.x, h.x, l.x); splitf(v.y, h.y, l.y);
    splitf(v.z, h.z, l.z); splitf(v.w, h.w, l.w);
    *reinterpret_cast<ushort4*>(hi + r * H_ + c4) = h;
    *reinterpret_cast<ushort4*>(lo + r * H_ + c4) = l;
}

// ---------------- gate-interleaved weight split: dst row 3i+g = src row g*1024+i ----------------
__global__ void k_wsplit_perm(const float* __restrict__ src, int ld, int coff,
                              u16* __restrict__ hi, u16* __restrict__ lo) {
    int r = blockIdx.x;                // permuted row: 3i+g
    int i = r / 3, g = r - i * 3;
    const float* p = src + (size_t)(g * H_ + i) * ld + coff;
    int c = threadIdx.x * 4;
    float4 v = *reinterpret_cast<const float4*>(p + c);
    ushort4 h, l;
    splitf(v.x, h.x, l.x); splitf(v.y, h.y, l.y);
    splitf(v.z, h.z, l.z); splitf(v.w, h.w, l.w);
    *reinterpret_cast<ushort4*>(hi + (size_t)r * H_ + c) = h;
    *reinterpret_cast<ushort4*>(lo + (size_t)r * H_ + c) = l;
}

// ---------------- big split-bf16 MFMA GEMM (proven R2-R15) ----------------
__global__ __launch_bounds__(256, 2) void k_gemm_mfma3(
    const u16* __restrict__ Ah, const u16* __restrict__ Al,
    const u16* __restrict__ Bh, const u16* __restrict__ Bl,
    const float* __restrict__ bias, float* __restrict__ C,
    int ldc, int K)
{
    __shared__ u16 ls[4][128 * 32];
    const int tid = threadIdx.x;
    const int lane = tid & 63, w = tid >> 6;
    const int wr = w >> 1, wc = w & 1;
    const size_t m0 = (size_t)blockIdx.x * 128, n0 = (size_t)blockIdx.y * 128;

    const int c0 = (w * 2) * 64 + lane;
    const int r0 = c0 >> 2, kc0 = (c0 & 3) << 3;
    const size_t rstep = (size_t)16 * K;
    const u16* gAh = Ah + (m0 + r0) * K + kc0;
    const u16* gAl = Al + (m0 + r0) * K + kc0;
    const u16* gBh = Bh + (n0 + r0) * K + kc0;
    const u16* gBl = Bl + (n0 + r0) * K + kc0;
    const int lo0 = c0 * 8;

    const int frow = lane & 15, fk = (lane >> 4) << 3;
    const int offA = (wr * 64 + frow) * 32 + fk;
    const int offB = (wc * 64 + frow) * 32 + fk;

    f32x4 acc[4][4] = {};

    for (int k0 = 0; k0 < K; k0 += 32) {
        load_lds16(gAh + k0, &ls[0][lo0]);
        load_lds16(gAh + rstep + k0, &ls[0][lo0 + 512]);
        load_lds16(gAl + k0, &ls[1][lo0]);
        load_lds16(gAl + rstep + k0, &ls[1][lo0 + 512]);
        load_lds16(gBh + k0, &ls[2][lo0]);
        load_lds16(gBh + rstep + k0, &ls[2][lo0 + 512]);
        load_lds16(gBl + k0, &ls[3][lo0]);
        load_lds16(gBl + rstep + k0, &ls[3][lo0 + 512]);
        __syncthreads();

        bf16x8 fAh[4], fAl[4], fBh[4], fBl[4];
#pragma unroll
        for (int m = 0; m < 4; ++m) {
            fAh[m] = *reinterpret_cast<const bf16x8*>(&ls[0][offA + m * 512]);
            fAl[m] = *reinterpret_cast<const bf16x8*>(&ls[1][offA + m * 512]);
        }
#pragma unroll
        for (int n = 0; n < 4; ++n) {
            fBh[n] = *reinterpret_cast<const bf16x8*>(&ls[2][offB + n * 512]);
            fBl[n] = *reinterpret_cast<const bf16x8*>(&ls[3][offB + n * 512]);
        }
#pragma unroll
        for (int m = 0; m < 4; ++m)
#pragma unroll
            for (int n = 0; n < 4; ++n) {
                MFMA3(acc[m][n], fAh[m], fAl[m], fBh[n], fBl[n]);
            }
        __syncthreads();
    }

    const int crow0 = wr * 64 + ((lane >> 4) << 2);
    const int ccol0 = wc * 64 + (lane & 15);
#pragma unroll
    for (int n = 0; n < 4; ++n) {
        const size_t col = n0 + ccol0 + n * 16;
        const float bv = bias ? bias[col] : 0.f;
#pragma unroll
        for (int m = 0; m < 4; ++m)
#pragma unroll
            for (int r = 0; r < 4; ++r)
                C[(m0 + crow0 + m * 16 + r) * (size_t)ldc + col] = acc[m][n][r] + bv;
    }
}

// ---------------- head GEMM (R14/R15, proven): 128x256 tile, B f32 + split in-kernel ----------------
__global__ __launch_bounds__(256, 2) void k_gemm_n2f(
    const u16* __restrict__ Ah, const u16* __restrict__ Al,
    const float* __restrict__ Bf,
    const float* __restrict__ bias, float* __restrict__ C,
    int ldc, int K)
{
    __shared__ u16 lsA[2][128 * 32];
    __shared__ u16 lsBh[256 * 32];
    __shared__ u16 lsBl[256 * 32];
    const int tid = threadIdx.x;
    const int lane = tid & 63, w = tid >> 6;
    const int wr = w >> 1, wc = w & 1;
    const size_t m0 = (size_t)blockIdx.x * 128, n0 = (size_t)blockIdx.y * 256;

    const int frow = lane & 15, fk = (lane >> 4) << 3;
    const int offA = (wr * 64 + frow) * 32 + fk;
    const int offB = (wc * 128 + frow) * 32 + fk;

    f32x4 acc[4][8] = {};

    for (int k0 = 0; k0 < K; k0 += 32) {
#pragma unroll
        for (int q = 0; q < 4; ++q) {
            const int chunk = (w + q * 4) * 64 + lane;
            const int local = chunk & 511;
            const u16* A = (chunk < 512) ? Ah : Al;
            load_lds16(A + (m0 + (local >> 2)) * K + k0 + ((local & 3) << 3),
                       &lsA[chunk >> 9][local * 8]);
        }
#pragma unroll
        for (int q = 0; q < 4; ++q) {
            const int c = tid + q * 256;
            const int row = c >> 2, k8 = (c & 3) << 3;
            const float* src = Bf + (size_t)(n0 + row) * K + k0 + k8;
            float4 v0 = *reinterpret_cast<const float4*>(src);
            float4 v1 = *reinterpret_cast<const float4*>(src + 4);
            union { ushort4 s[2]; bf16x8 v; } hh, ll;
            splitf(v0.x, hh.s[0].x, ll.s[0].x); splitf(v0.y, hh.s[0].y, ll.s[0].y);
            splitf(v0.z, hh.s[0].z, ll.s[0].z); splitf(v0.w, hh.s[0].w, ll.s[0].w);
            splitf(v1.x, hh.s[1].x, ll.s[1].x); splitf(v1.y, hh.s[1].y, ll.s[1].y);
            splitf(v1.z, hh.s[1].z, ll.s[1].z); splitf(v1.w, hh.s[1].w, ll.s[1].w);
            *reinterpret_cast<bf16x8*>(&lsBh[row * 32 + k8]) = hh.v;
            *reinterpret_cast<bf16x8*>(&lsBl[row * 32 + k8]) = ll.v;
        }
        __syncthreads();

        bf16x8 fAh[4], fAl[4];
#pragma unroll
        for (int m = 0; m < 4; ++m) {
            fAh[m] = *reinterpret_cast<const bf16x8*>(&lsA[0][offA + m * 512]);
            fAl[m] = *reinterpret_cast<const bf16x8*>(&lsA[1][offA + m * 512]);
        }
#pragma unroll
        for (int n = 0; n < 8; ++n) {
            bf16x8 fBh = *reinterpret_cast<const bf16x8*>(&lsBh[offB + n * 512]);
            bf16x8 fBl = *reinterpret_cast<const bf16x8*>(&lsBl[offB + n * 512]);
#pragma unroll
            for (int m = 0; m < 4; ++m) {
                MFMA3(acc[m][n], fAh[m], fAl[m], fBh, fBl);
            }
        }
        __syncthreads();
    }

    const int crow0 = wr * 64 + ((lane >> 4) << 2);
    const int ccol0 = wc * 128 + (lane & 15);
#pragma unroll
    for (int n = 0; n < 8; ++n) {
        const size_t col = n0 + ccol0 + n * 16;
        const float bv = bias ? bias[col] : 0.f;
#pragma unroll
        for (int m = 0; m < 4; ++m)
#pragma unroll
            for (int r = 0; r < 4; ++r)
                C[(m0 + crow0 + m * 16 + r) * (size_t)ldc + col] = acc[m][n][r] + bv;
    }
}

// ================= persistent encoder (R9/R11 body, R16 direction-local barrier) =================
__global__ __launch_bounds__(256) void k_enc_persist(
    const u16* __restrict__ whhf_h, const u16* __restrict__ whhf_l,
    const u16* __restrict__ whhb_h, const u16* __restrict__ whhb_l,
    const float* __restrict__ gi_f, const float* __restrict__ gi_b,
    const float* __restrict__ bhh_f, const float* __restrict__ bhh_b,
    u16* __restrict__ hfH0, u16* __restrict__ hfL0,
    u16* __restrict__ hfH1, u16* __restrict__ hfL1,
    u16* __restrict__ hbH0, u16* __restrict__ hbL0,
    u16* __restrict__ hbH1, u16* __restrict__ hbL1,
    float* __restrict__ enc_f, float* __restrict__ enc_b,
    int* __restrict__ cnt, int* __restrict__ flag)
{
    __shared__ __align__(16) char smem[145792];
    u16* lAh  = (u16*)smem;                    // [32][1024] staged h hi, XOR-swizzled
    u16* lAl  = (u16*)(smem + 65536);          // lo
    float* ex0 = (float*)(smem + 131072);      // [48][33] k-half 0
    float* ex1 = (float*)(smem + 137408);      // [48][33] k-half 1
    float* hloc = (float*)(smem + 143744);     // [32][16] f32 state

    const int blk = blockIdx.x, tid = threadIdx.x;
    const int lane = tid & 63, w = tid >> 6;
    const int dir = blk >> 6, c = blk & 63;
    const int i0 = c * 16;
    const u16* WH = (dir ? whhb_h : whhf_h) + (size_t)c * 48 * 1024;
    const u16* WL = (dir ? whhb_l : whhf_l) + (size_t)c * 48 * 1024;
    const float* gi = dir ? gi_b : gi_f;
    const float* bhh = dir ? bhh_b : bhh_f;
    float* encd = dir ? enc_b : enc_f;
    int* cntd  = cnt + dir * 256;              // direction-local barrier arrays
    int* flagd = flag + dir * 256;
    int gen = 0;

    for (int q = tid; q < 512; q += 256) hloc[q] = 0.f;

    const int frow = lane & 15, fk8 = (lane >> 4) << 3;
    const int cb = lane & 15, rb0 = (lane >> 4) << 2;

    for (int t = 0; t < 64; ++t) {
        const int a = t & 1;
        const u16* rH = dir ? (a ? hbH1 : hbH0) : (a ? hfH1 : hfH0);
        const u16* rL = dir ? (a ? hbL1 : hbL0) : (a ? hfL1 : hfL0);
        u16* oH = dir ? (a ? hbH0 : hbH1) : (a ? hfH0 : hfH1);
        u16* oL = dir ? (a ? hbL0 : hbL1) : (a ? hfL0 : hfL1);
        const int s = dir ? 63 - t : t;

#pragma unroll
        for (int ch0 = 0; ch0 < 4096; ch0 += 256) {
            int ch = ch0 + tid;
            int r = ch >> 7, kc = (ch & 127) << 3;
            int sw = kc ^ ((r & 7) << 3);
            *(bf16x8*)&lAh[r * 1024 + sw] = ld_sys16(&rH[r * 1024 + kc]);
            *(bf16x8*)&lAl[r * 1024 + sw] = ld_sys16(&rL[r * 1024 + kc]);
        }
        __syncthreads();

#pragma unroll
        for (int jj = 0; jj < 3; ++jj) {
            const int j = w * 3 + jj;
            const int m = j & 1;
            const int n = (j >> 1) % 3;
            const int kh = j / 6;
            const int arow = m * 16 + frow;
            const int asw = (arow & 7) << 3;
            const u16* gBh = WH + (size_t)(n * 16 + frow) * 1024;
            const u16* gBl = WL + (size_t)(n * 16 + frow) * 1024;
            f32x4 acc = {};
            const int ke = kh * 512 + 512;
#pragma unroll 4
            for (int k0 = kh * 512; k0 < ke; k0 += 32) {
                int kc = k0 + fk8;
                bf16x8 aH = *(const bf16x8*)&lAh[arow * 1024 + (kc ^ asw)];
                bf16x8 aL = *(const bf16x8*)&lAl[arow * 1024 + (kc ^ asw)];
                bf16x8 bH = *(const bf16x8*)&gBh[kc];
                bf16x8 bL = *(const bf16x8*)&gBl[kc];
                MFMA3(acc, aH, aL, bH, bL);
            }
            float* exd = kh ? ex1 : ex0;
            const int pc = n * 16 + cb;
#pragma unroll
            for (int r = 0; r < 4; ++r)
                exd[pc * 33 + m * 16 + rb0 + r] = acc[r];
        }
        __syncthreads();

        {
            const int il = tid & 15, bb = tid >> 4;
            const int i = i0 + il;
#pragma unroll
            for (int q = 0; q < 2; ++q) {
                int b = bb + q * 16;
                float ghr = ex0[(3 * il + 0) * 33 + b] + ex1[(3 * il + 0) * 33 + b] + bhh[i];
                float ghz = ex0[(3 * il + 1) * 33 + b] + ex1[(3 * il + 1) * 33 + b] + bhh[H_ + i];
                float ghn = ex0[(3 * il + 2) * 33 + b] + ex1[(3 * il + 2) * 33 + b] + bhh[2 * H_ + i];
                size_t gio = (size_t)(s * B_ + b) * H3 + i;
                float gir = gi[gio], giz = gi[gio + H_], gin = gi[gio + 2 * H_];
                float rr = 1.f / (1.f + expf(-(gir + ghr)));
                float zz = 1.f / (1.f + expf(-(giz + ghz)));
                float nn = tanhf(gin + rr * ghn);
                float hold = hloc[b * 16 + il];
                float hnew = (1.f - zz) * nn + zz * hold;
                hloc[b * 16 + il] = hnew;
                u16 hh, hl; splitf(hnew, hh, hl);
                st_sysu16(&oH[b * 1024 + i], hh);
                st_sysu16(&oL[b * 1024 + i], hl);
                encd[((size_t)b * 64 + s) * H_ + i] = hnew;
            }
        }
        gbar(cntd, flagd, 64, c, gen);   // direction-local: fwd/bwd share no state
    }
}

// ================= persistent decoder (R15 body, R16 group barriers for BAR2/BAR3) =================
__global__ __launch_bounds__(256) void k_dec_persist(
    const u16* __restrict__ wah, const u16* __restrict__ wal,
    const u16* __restrict__ wgh, const u16* __restrict__ wgl,
    const u16* __restrict__ wdh, const u16* __restrict__ wdl,
    const float* __restrict__ gi_e, const float* __restrict__ bhh_d,
    const float* __restrict__ ep, const float* __restrict__ vvec,
    const float* __restrict__ enc,
    u16* __restrict__ hH, u16* __restrict__ hL,
    float* __restrict__ hwa, float* __restrict__ scores,
    u16* __restrict__ ctxH, u16* __restrict__ ctxL,
    float* __restrict__ states, int* __restrict__ cnt, int* __restrict__ flag,
    int* __restrict__ grpc)
{
    __shared__ __align__(16) char smem[140288];
    u16* lWH  = (u16*)smem;                    // [16][1024] rows 0-3 hWa, 4-15 ghd (swizzled)
    u16* lWL  = (u16*)(smem + 32768);
    u16* lDH  = (u16*)(smem + 65536);          // [16][1024] wdc hi (12 + 4 pad)
    float* lenc = (float*)(smem + 98304);      // [64][128]
    float* ex1a = (float*)(smem + 131072);     // [32][16] PhA partial (k-half 0)
    float* ex1b = (float*)(smem + 133120);
    float* ex2a = (float*)(smem + 135168);     // PhD partials
    float* ex2b = (float*)(smem + 137216);
    float* aw   = (float*)(smem + 139264);     // [64]
    float* hloc = (float*)(smem + 139520);     // [128] f32 state for owned (b,u)

    const int bid = blockIdx.x, tid = threadIdx.x;
    const int lane = tid & 63, w = tid >> 6;
    const int frow = lane & 15, fk8 = (lane >> 4) << 3;
    const int b3 = bid >> 3, sl = bid & 7;
    int gen = 0, genG = 0;

    for (int ch = tid; ch < 2048; ch += 256) {
        int r = ch >> 7, kc = (ch & 127) << 3;
        int sw = kc ^ ((r & 7) << 3);
        const u16 *sH, *sL;
        if (r < 4) { sH = wah + ((size_t)bid * 4 + r) * 1024;
                     sL = wal + ((size_t)bid * 4 + r) * 1024; }
        else       { sH = wgh + ((size_t)bid * 12 + r - 4) * 1024;
                     sL = wgl + ((size_t)bid * 12 + r - 4) * 1024; }
        *(bf16x8*)&lWH[r * 1024 + sw] = *(const bf16x8*)&sH[kc];
        *(bf16x8*)&lWL[r * 1024 + sw] = *(const bf16x8*)&sL[kc];
    }
    for (int ch = tid; ch < 2048; ch += 256) {
        int r = ch >> 7, kc = (ch & 127) << 3;
        int sw = kc ^ ((r & 7) << 3);
        int rowg = (r < 12) ? bid * 12 + r : bid * 12;
        *(bf16x8*)&lDH[r * 1024 + sw] = *(const bf16x8*)&wdh[(size_t)rowg * 1024 + kc];
    }
    for (int ch = tid; ch < 2048; ch += 256) {
        int s = ch >> 5, c4 = (ch & 31) << 2;
        *(float4*)&lenc[s * 128 + c4] =
            *(const float4*)&enc[((size_t)b3 * 64 + s) * 1024 + sl * 128 + c4];
    }
    if (tid < 128) {
        int b = tid >> 2, u = bid * 4 + (tid & 3);
        hloc[tid] = bf2f(hH[b * 1024 + u]) + bf2f(hL[b * 1024 + u]);
    }
    float vreg[16];
#pragma unroll
    for (int i = 0; i < 16; ++i) vreg[i] = vvec[lane + i * 64];
    __syncthreads();

    const int mt = w & 1, kh = w >> 1;
    const int bsw = (frow & 7) << 3;
    const int rowg = (frow < 12) ? bid * 12 + frow : bid * 12;
    const u16* gDl = wdl + (size_t)rowg * 1024;
    const int exw = (mt * 16 + ((lane >> 4) << 2)) * 16 + frow;
    const float* epr0 = ep + ((size_t)b3 * 64 + sl * 8 + w * 2) * 1024;
    const float* epr1 = epr0 + 1024;

    for (int t = 0; t < 64; ++t) {
        // ---- PhA (+ overlapped ep prefetch for PhB) ----
        float pe0[16], pe1[16];
#pragma unroll
        for (int i = 0; i < 16; ++i) pe0[i] = epr0[lane + i * 64];
#pragma unroll
        for (int i = 0; i < 16; ++i) pe1[i] = epr1[lane + i * 64];
        {
            float* exA = kh ? ex1b : ex1a;
            f32x4 acc = {};
            const int ar0 = (mt * 16 + frow) * 1024;
            const int ke = kh * 512 + 512;
#pragma unroll 4
            for (int k0 = kh * 512; k0 < ke; k0 += 32) {
                int kc = k0 + fk8;
                bf16x8 aH = ld_sys16(&hH[ar0 + kc]);
                bf16x8 aL = ld_sys16(&hL[ar0 + kc]);
                bf16x8 bH = *(const bf16x8*)&lWH[frow * 1024 + (kc ^ bsw)];
                bf16x8 bL = *(const bf16x8*)&lWL[frow * 1024 + (kc ^ bsw)];
                MFMA3(acc, aH, aL, bH, bL);
            }
#pragma unroll
            for (int r = 0; r < 4; ++r) exA[exw + r * 16] = acc[r];
        }
        __syncthreads();
        if (tid < 128) {
            int b = tid >> 2, col = tid & 3;
            st_sysf(&hwa[b * 1024 + bid * 4 + col],
                    ex1a[b * 16 + col] + ex1b[b * 16 + col]);
        }
        gbar(cnt, flag, 256, bid, gen);      // BAR1 (global): hwa all-to-all

        // ---- PhB (hwa hoisted; ep from prefetched registers) ----
        {
            float hreg[16];
#pragma unroll
            for (int i = 0; i < 16; ++i)
                hreg[i] = ld_sysf(&hwa[b3 * 1024 + lane + i * 64]);
            float a2 = 0.f, a3 = 0.f;
#pragma unroll
            for (int i = 0; i < 16; ++i) {
                a2 += fmaxf(hreg[i] + pe0[i], 0.f) * vreg[i];
                a3 += fmaxf(hreg[i] + pe1[i], 0.f) * vreg[i];
            }
            for (int off = 32; off; off >>= 1) a2 += __shfl_down(a2, off);
            for (int off = 32; off; off >>= 1) a3 += __shfl_down(a3, off);
            if (lane == 0) {
                st_sysf(&scores[b3 * 64 + sl * 8 + w * 2], a2);
                st_sysf(&scores[b3 * 64 + sl * 8 + w * 2 + 1], a3);
            }
        }
        gbar_grp(grpc, b3, 8, genG);         // BAR2 (group): scores group-internal

        // ---- PhC ----
        if (tid < 64) {
            float sc = ld_sysf(&scores[b3 * 64 + tid]);
            float m = sc;
            for (int off = 32; off; off >>= 1) m = fmaxf(m, __shfl_xor(m, off));
            float e = expf(sc - m);
            float sum = e;
            for (int off = 32; off; off >>= 1) sum += __shfl_xor(sum, off);
            aw[tid] = e / sum;
        }
        __syncthreads();
        if (tid < 128) {
            int c = tid;
            float x = 0.f;
#pragma unroll 8
            for (int s = 0; s < 64; ++s) x += aw[s] * lenc[s * 128 + c];
            states[((size_t)t * 32 + b3) * 2048 + 1024 + sl * 128 + c] = x;
            u16 hh, hl; splitf(x, hh, hl);
            st_sysu16(&ctxH[b3 * 1024 + sl * 128 + c], hh);
            st_sysu16(&ctxL[b3 * 1024 + sl * 128 + c], hl);
        }
        gbar_grp(grpc, b3, 8, genG);         // BAR3 (group): ctx group-internal

        // ---- PhD ----
        {
            float* exD = kh ? ex2b : ex2a;
            f32x4 acc = {};
            const int ar0 = (mt * 16 + frow) * 1024;
            const int ke = kh * 512 + 512;
#pragma unroll 4
            for (int k0 = kh * 512; k0 < ke; k0 += 32) {
                int kc = k0 + fk8;
                bf16x8 aH = ld_sys16(&ctxH[ar0 + kc]);
                bf16x8 aL = ld_sys16(&ctxL[ar0 + kc]);
                bf16x8 bH = *(const bf16x8*)&lDH[frow * 1024 + (kc ^ bsw)];
                bf16x8 bL = *(const bf16x8*)&gDl[kc];
                MFMA3(acc, aH, aL, bH, bL);
            }
#pragma unroll
            for (int r = 0; r < 4; ++r) exD[exw + r * 16] = acc[r];
        }
        __syncthreads();
        if (tid < 128) {
            int b = tid >> 2, ui = tid & 3;
            int u = bid * 4 + ui;
            float gicr = ex2a[b * 16 + 3 * ui + 0] + ex2b[b * 16 + 3 * ui + 0];
            float gicz = ex2a[b * 16 + 3 * ui + 1] + ex2b[b * 16 + 3 * ui + 1];
            float gicn = ex2a[b * 16 + 3 * ui + 2] + ex2b[b * 16 + 3 * ui + 2];
            float ghr = ex1a[b * 16 + 4 + 3 * ui + 0] + ex1b[b * 16 + 4 + 3 * ui + 0] + bhh_d[u];
            float ghz = ex1a[b * 16 + 4 + 3 * ui + 1] + ex1b[b * 16 + 4 + 3 * ui + 1] + bhh_d[H_ + u];
            float ghn = ex1a[b * 16 + 4 + 3 * ui + 2] + ex1b[b * 16 + 4 + 3 * ui + 2] + bhh_d[2 * H_ + u];
            size_t ge = ((size_t)t * 32 + b) * 3072;
            float gir = gi_e[ge + u] + gicr;
            float giz = gi_e[ge + 1024 + u] + gicz;
            float gin = gi_e[ge + 2048 + u] + gicn;
            float rr = 1.f / (1.f + expf(-(gir + ghr)));
            float zz = 1.f / (1.f + expf(-(giz + ghz)));
            float nn = tanhf(gin + rr * ghn);
            float hold = hloc[tid];
            float hnew = (1.f - zz) * nn + zz * hold;
            hloc[tid] = hnew;
            u16 hh, hl; splitf(hnew, hh, hl);
            st_sysu16(&hH[b * 1024 + u], hh);
            st_sysu16(&hL[b * 1024 + u], hl);
            states[((size_t)t * 32 + b) * 2048 + u] = hnew;
        }
        gbar(cnt, flag, 256, bid, gen);      // BAR4 (global): h all-to-all
    }
}

extern "C" void kernel_launch(void* const* d_in, const int* in_sizes, int n_in,
                              void* d_out, int out_size, void* d_ws, size_t ws_size,
                              hipStream_t stream) {
    const int*   src   = (const int*)d_in[0];
    const int*   trg   = (const int*)d_in[1];
    const float* emb   = (const float*)d_in[2];
    const float* Wih_f = (const float*)d_in[3];
    const float* Whh_f = (const float*)d_in[4];
    const float* bih_f = (const float*)d_in[5];
    const float* bhh_f = (const float*)d_in[6];
    const float* Wih_b = (const float*)d_in[7];
    const float* Whh_b = (const float*)d_in[8];
    const float* bih_b = (const float*)d_in[9];
    const float* bhh_b = (const float*)d_in[10];
    const float* Wa    = (const float*)d_in[11];
    const float* ba    = (const float*)d_in[12];
    const float* vv    = (const float*)d_in[13];
    const float* Wih_d = (const float*)d_in[14];
    const float* Whh_d = (const float*)d_in[15];
    const float* bih_d = (const float*)d_in[16];
    const float* bhh_d = (const float*)d_in[17];
    const float* Wout  = (const float*)d_in[18];
    const float* bout  = (const float*)d_in[19];
    float* out = (float*)d_out;
    (void)in_sizes; (void)n_in; (void)out_size; (void)ws_size;

    float* w = (float*)d_ws;
    size_t o = 0;
    auto alloc = [&](size_t n) { float* p = w + o; o += n; return p; };
    float* gi_f  = alloc((size_t)S_ * B_ * H3);      // encoder fwd gi; reused as gi_e
    float* gi_b  = alloc((size_t)S_ * B_ * H3);      // encoder bwd gi; reused as states
    float* enc_f = alloc((size_t)B_ * S_ * H_);
    float* enc_b = alloc((size_t)B_ * S_ * H_);
    float* enc   = alloc((size_t)B_ * S_ * H_);
    float* ep    = alloc((size_t)B_ * S_ * H_);
    float* hwa   = alloc((size_t)B_ * H_);
    float* scores = alloc(B_ * S_);
    float* barf  = alloc(4096);
    int* cntE  = (int*)barf;          // 16 lines (8 per direction)
    int* flagE = cntE + 512;          // 16 lines
    int* cntD  = cntE + 1024;         // 8 lines
    int* flagD = cntE + 1280;         // 8 lines
    int* grpD  = cntE + 1536;         // 32 lines (1 per decoder group)
    float* gi_e   = gi_f;
    float* states = gi_b;

    u16* wu = (u16*)(w + o);
    size_t ou = 0;
    auto alloc16 = [&](size_t n) { u16* p = wu + ou; ou += n; return p; };
    u16* semb_h  = alloc16((size_t)S_ * B_ * E_);  u16* semb_l  = alloc16((size_t)S_ * B_ * E_);
    u16* demb_h  = alloc16((size_t)T_ * B_ * E_);  u16* demb_l  = alloc16((size_t)T_ * B_ * E_);
    u16* wihf_h  = alloc16((size_t)H3 * E_);       u16* wihf_l  = alloc16((size_t)H3 * E_);
    u16* wihb_h  = alloc16((size_t)H3 * E_);       u16* wihb_l  = alloc16((size_t)H3 * E_);
    u16* wihd_h  = alloc16((size_t)H3 * E_);       u16* wihd_l  = alloc16((size_t)H3 * E_);
    u16* wae_h   = alloc16((size_t)H_ * H_);       u16* wae_l   = alloc16((size_t)H_ * H_);
    u16* enc_h   = alloc16((size_t)B_ * S_ * H_);  u16* enc_l   = alloc16((size_t)B_ * S_ * H_);
    u16* st_h    = alloc16((size_t)T_ * B_ * H2);  u16* st_l    = alloc16((size_t)T_ * B_ * H2);
    u16* whhf_h  = alloc16((size_t)H3 * H_);       u16* whhf_l  = alloc16((size_t)H3 * H_);
    u16* whhb_h  = alloc16((size_t)H3 * H_);       u16* whhb_l  = alloc16((size_t)H3 * H_);
    u16* wgh     = alloc16((size_t)H3 * H_);       u16* wgl     = alloc16((size_t)H3 * H_);   // Whh_d perm
    u16* wdh     = alloc16((size_t)H3 * H_);       u16* wdl     = alloc16((size_t)H3 * H_);   // Wihd ctx perm
    u16* wah     = alloc16((size_t)H_ * H_);       u16* wal     = alloc16((size_t)H_ * H_);   // Wa h-part
    u16* hsf_h[2] = {alloc16(B_ * H_), alloc16(B_ * H_)};
    u16* hsf_l[2] = {alloc16(B_ * H_), alloc16(B_ * H_)};
    u16* hsb_h[2] = {alloc16(B_ * H_), alloc16(B_ * H_)};
    u16* hsb_l[2] = {alloc16(B_ * H_), alloc16(B_ * H_)};
    u16* ctx_h   = alloc16(B_ * H_);               u16* ctx_l   = alloc16(B_ * H_);

    // ---- init ----
    hipMemsetAsync(barf, 0, 4096 * sizeof(float), stream);
    hipMemsetAsync(hsf_h[0], 0, B_ * H_ * sizeof(u16), stream);
    hipMemsetAsync(hsf_l[0], 0, B_ * H_ * sizeof(u16), stream);
    hipMemsetAsync(hsb_h[0], 0, B_ * H_ * sizeof(u16), stream);
    hipMemsetAsync(hsb_l[0], 0, B_ * H_ * sizeof(u16), stream);

    // ---- embeddings ----
    k_embed_src_split<<<S_ * B_, 128, 0, stream>>>(src, emb, semb_h, semb_l);
    k_embed_dec_split<<<T_ * B_, 128, 0, stream>>>(src, trg, emb, demb_h, demb_l);

    // ---- weight splits ----
    k_split<<<dim3(1, H3), 256, 0, stream>>>(Wih_f, E_, E_ / 4, wihf_h, wihf_l);
    k_split<<<dim3(1, H3), 256, 0, stream>>>(Wih_b, E_, E_ / 4, wihb_h, wihb_l);
    k_split<<<dim3(1, H3), 256, 0, stream>>>(Wih_d, EH, E_ / 4, wihd_h, wihd_l);
    k_split<<<dim3(1, H_), 256, 0, stream>>>(Wa + H_, H2, H_ / 4, wae_h, wae_l);
    k_split<<<dim3(1, H_), 256, 0, stream>>>(Wa, H2, H_ / 4, wah, wal);
    k_wsplit_perm<<<H3, 256, 0, stream>>>(Whh_f, H_, 0, whhf_h, whhf_l);
    k_wsplit_perm<<<H3, 256, 0, stream>>>(Whh_b, H_, 0, whhb_h, whhb_l);
    k_wsplit_perm<<<H3, 256, 0, stream>>>(Whh_d, H_, 0, wgh, wgl);
    k_wsplit_perm<<<H3, 256, 0, stream>>>(Wih_d, EH, E_, wdh, wdl);

    // ---- encoder input projections ----
    k_gemm_mfma3<<<dim3(16, 24), 256, 0, stream>>>(semb_h, semb_l, wihf_h, wihf_l,
                                                   bih_f, gi_f, H3, E_);
    k_gemm_mfma3<<<dim3(16, 24), 256, 0, stream>>>(semb_h, semb_l, wihb_h, wihb_l,
                                                   bih_b, gi_b, H3, E_);

    // ---- encoder: persistent, direction-local barriers ----
    k_enc_persist<<<128, 256, 0, stream>>>(
        whhf_h, whhf_l, whhb_h, whhb_l, gi_f, gi_b, bhh_f, bhh_b,
        hsf_h[0], hsf_l[0], hsf_h[1], hsf_l[1],
        hsb_h[0], hsb_l[0], hsb_h[1], hsb_l[1],
        enc_f, enc_b, cntE, flagE);

    // ---- merge enc dirs + split; ep precompute; decoder emb projection ----
    k_split_sum_enc<<<dim3(1, B_ * S_), 256, 0, stream>>>(enc_f, enc_b, enc, enc_h, enc_l);
    k_gemm_mfma3<<<dim3(16, 8), 256, 0, stream>>>(enc_h, enc_l, wae_h, wae_l,
                                                  ba, ep, H_, H_);
    k_gemm_mfma3<<<dim3(16, 24), 256, 0, stream>>>(demb_h, demb_l, wihd_h, wihd_l,
                                                   bih_d, gi_e, H3, E_);

    // ---- decoder: persistent, 2 global + 2 group barriers/step ----
    k_dec_persist<<<256, 256, 0, stream>>>(
        wah, wal, wgh, wgl, wdh, wdl, gi_e, bhh_d, ep, vv, enc,
        hsf_h[0], hsf_l[0], hwa, scores, ctx_h, ctx_l, states, cntD, flagD, grpD);

    // ---- output head: single launch over full vocab ----
    k_split<<<dim3(2, T_ * B_), 256, 0, stream>>>(states, H2, H2 / 4, st_h, st_l);
    k_gemm_n2f<<<dim3(16, 125), 256, 0, stream>>>(st_h, st_l, Wout, bout, out, V_, H2);
}

// Round 17
// 3997.102 us; speedup vs baseline: 1.1900x; 1.0002x over previous
//
#include <hip/hip_runtime.h>
#include <hip/hip_bf16.h>

#define S_ 64
#define T_ 64
#define B_ 32
#define E_ 512
#define H_ 1024
#define V_ 32000
#define H3 3072
#define H2 2048
#define EH 1536

typedef unsigned short u16;
typedef unsigned int u32;
typedef unsigned long long u64;
typedef __attribute__((ext_vector_type(8))) short bf16x8;
typedef __attribute__((ext_vector_type(4))) float f32x4;

#define MFMA3(ACC, AH_, AL_, BH_, BL_)                                              \
    ACC = __builtin_amdgcn_mfma_f32_16x16x32_bf16(AL_, BH_, ACC, 0, 0, 0);          \
    ACC = __builtin_amdgcn_mfma_f32_16x16x32_bf16(AH_, BL_, ACC, 0, 0, 0);          \
    ACC = __builtin_amdgcn_mfma_f32_16x16x32_bf16(AH_, BH_, ACC, 0, 0, 0);

__device__ __forceinline__ void splitf(float x, u16& h, u16& l) {
    u32 xb = __float_as_uint(x);
    u32 hb = (xb + 0x7FFFu + ((xb >> 16) & 1u)) & 0xFFFF0000u;  // RNE bf16 (as f32 bits)
    h = (u16)(hb >> 16);
    float lf = x - __uint_as_float(hb);                          // exact residual
    u32 lb = __float_as_uint(lf);
    l = (u16)((lb + 0x7FFFu + ((lb >> 16) & 1u)) >> 16);
}

__device__ __forceinline__ float bf2f(u16 v) { return __uint_as_float(((u32)v) << 16); }

__device__ __forceinline__ void load_lds16(const void* g, void* l) {
    __builtin_amdgcn_global_load_lds((const __attribute__((address_space(1))) u32*)g,
                                     (__attribute__((address_space(3))) u32*)l, 16, 0, 0);
}

// ---- system-scope (coherence-point) accessors: bypass L1/L2, no fences needed ----
__device__ __forceinline__ bf16x8 ld_sys16(const u16* p) {
    union { bf16x8 v; u64 q[2]; } u;
    const u64* q = (const u64*)p;
    u.q[0] = __hip_atomic_load(q,     __ATOMIC_RELAXED, __HIP_MEMORY_SCOPE_SYSTEM);
    u.q[1] = __hip_atomic_load(q + 1, __ATOMIC_RELAXED, __HIP_MEMORY_SCOPE_SYSTEM);
    return u.v;
}
__device__ __forceinline__ float ld_sysf(const float* p) {
    return __hip_atomic_load(p, __ATOMIC_RELAXED, __HIP_MEMORY_SCOPE_SYSTEM);
}
__device__ __forceinline__ void st_sysf(float* p, float v) {
    __hip_atomic_store(p, v, __ATOMIC_RELAXED, __HIP_MEMORY_SCOPE_SYSTEM);
}
__device__ __forceinline__ void st_sysu16(u16* p, u16 v) {
    __hip_atomic_store(p, v, __ATOMIC_RELAXED, __HIP_MEMORY_SCOPE_SYSTEM);
}

// Fence-free GLOBAL grid barrier (R11-proven: ~4us).
__device__ __forceinline__ void gbar(int* cnt, int* flag, int nblk, int blk, int& gen) {
    __syncthreads();
    if (threadIdx.x == 0) {
        gen += 1;
        asm volatile("s_waitcnt vmcnt(0)" ::: "memory");
        __hip_atomic_fetch_add(&cnt[(blk & 7) << 5], 1, __ATOMIC_RELAXED,
                               __HIP_MEMORY_SCOPE_SYSTEM);
        if (blk == 0) {
            const int target = nblk * gen;
            for (;;) {
                int sum = 0;
#pragma unroll
                for (int j = 0; j < 8; ++j)
                    sum += __hip_atomic_load(&cnt[j << 5], __ATOMIC_RELAXED,
                                             __HIP_MEMORY_SCOPE_SYSTEM);
                if (sum >= target) break;
                __builtin_amdgcn_s_sleep(2);
            }
#pragma unroll
            for (int j = 0; j < 8; ++j)
                __hip_atomic_store(&flag[j << 5], gen, __ATOMIC_RELAXED,
                                   __HIP_MEMORY_SCOPE_SYSTEM);
        } else {
            while (__hip_atomic_load(&flag[(blk & 7) << 5], __ATOMIC_RELAXED,
                                     __HIP_MEMORY_SCOPE_SYSTEM) < gen)
                __builtin_amdgcn_s_sleep(2);
        }
    }
    __syncthreads();
}

// GROUP barrier (R16-proven): n blocks of one group arrive+poll a single cacheline.
__device__ __forceinline__ void gbar_grp(int* cnt, int grp, int n, int& gen) {
    __syncthreads();
    if (threadIdx.x == 0) {
        gen += 1;
        asm volatile("s_waitcnt vmcnt(0)" ::: "memory");
        __hip_atomic_fetch_add(&cnt[grp << 5], 1, __ATOMIC_RELAXED,
                               __HIP_MEMORY_SCOPE_SYSTEM);
        const int target = n * gen;
        while (__hip_atomic_load(&cnt[grp << 5], __ATOMIC_RELAXED,
                                 __HIP_MEMORY_SCOPE_SYSTEM) < target)
            __builtin_amdgcn_s_sleep(1);
    }
    __syncthreads();
}

// ---------------- embedding gather + split (src side; dec side folded into encoder) ----------------
__global__ void k_embed_src_split(const int* __restrict__ src, const float* __restrict__ emb,
                                  u16* __restrict__ hi, u16* __restrict__ lo) {
    int row = blockIdx.x;              // s*B + b
    int tok = src[row];
    int c = threadIdx.x * 4;
    float4 v = *reinterpret_cast<const float4*>(emb + (size_t)tok * E_ + c);
    ushort4 h, l;
    splitf(v.x, h.x, l.x); splitf(v.y, h.y, l.y);
    splitf(v.z, h.z, l.z); splitf(v.w, h.w, l.w);
    *reinterpret_cast<ushort4*>(hi + (size_t)row * E_ + c) = h;
    *reinterpret_cast<ushort4*>(lo + (size_t)row * E_ + c) = l;
}

// ---------------- generic f32 -> bf16 hi/lo split ----------------
__global__ __launch_bounds__(256) void k_split(const float* __restrict__ in, int ld, int cols4,
                                               u16* __restrict__ hi, u16* __restrict__ lo) {
    int c4 = blockIdx.x * 256 + threadIdx.x;
    if (c4 >= cols4) return;
    size_t r = blockIdx.y;
    float4 v = *reinterpret_cast<const float4*>(in + r * ld + (size_t)c4 * 4);
    ushort4 h, l;
    splitf(v.x, h.x, l.x); splitf(v.y, h.y, l.y);
    splitf(v.z, h.z, l.z); splitf(v.w, h.w, l.w);
    size_t o = (r * cols4 + c4) * 4;
    *reinterpret_cast<ushort4*>(hi + o) = h;
    *reinterpret_cast<ushort4*>(lo + o) = l;
}

// ---------------- enc = enc_f + enc_b, plus split ----------------
__global__ __launch_bounds__(256) void k_split_sum_enc(
    const float* __restrict__ ef, const float* __restrict__ eb, float* __restrict__ es,
    u16* __restrict__ hi, u16* __restrict__ lo) {
    size_t r = blockIdx.y;
    int c4 = threadIdx.x * 4;
    float4 va = *reinterpret_cast<const float4*>(ef + r * H_ + c4);
    float4 vb = *reinterpret_cast<const float4*>(eb + r * H_ + c4);
    float4 v; v.x = va.x + vb.x; v.y = va.y + vb.y; v.z = va.z + vb.z; v.w = va.w + vb.w;
    *reinterpret_cast<float4*>(es + r * H_ + c4) = v;
    ushort4 h, l;
    splitf(v.x, h.x, l.x); splitf(v.y, h.y, l.y);
    splitf(v.z, h.z, l.z); splitf(v.w, h.w, l.w);
    *reinterpret_cast<ushort4*>(hi + r * H_ + c4) = h;
    *reinterpret_cast<ushort4*>(lo + r * H_ + c4) = l;
}

// ---------------- gate-interleaved weight split (encoder-side Whh_f/Whh_b only) ----------------
__global__ void k_wsplit_perm(const float* __restrict__ src, int ld, int coff,
                              u16* __restrict__ hi, u16* __restrict__ lo) {
    int r = blockIdx.x;                // permuted row: 3i+g
    int i = r / 3, g = r - i * 3;
    const float* p = src + (size_t)(g * H_ + i) * ld + coff;
    int c = threadIdx.x * 4;
    float4 v = *reinterpret_cast<const float4*>(p + c);
    ushort4 h, l;
    splitf(v.x, h.x, l.x); splitf(v.y, h.y, l.y);
    splitf(v.z, h.z, l.z); splitf(v.w, h.w, l.w);
    *reinterpret_cast<ushort4*>(hi + (size_t)r * H_ + c) = h;
    *reinterpret_cast<ushort4*>(lo + (size_t)r * H_ + c) = l;
}

// ---------------- big split-bf16 MFMA GEMM (proven R2-R16) ----------------
__global__ __launch_bounds__(256, 2) void k_gemm_mfma3(
    const u16* __restrict__ Ah, const u16* __restrict__ Al,
    const u16* __restrict__ Bh, const u16* __restrict__ Bl,
    const float* __restrict__ bias, float* __restrict__ C,
    int ldc, int K)
{
    __shared__ u16 ls[4][128 * 32];
    const int tid = threadIdx.x;
    const int lane = tid & 63, w = tid >> 6;
    const int wr = w >> 1, wc = w & 1;
    const size_t m0 = (size_t)blockIdx.x * 128, n0 = (size_t)blockIdx.y * 128;

    const int c0 = (w * 2) * 64 + lane;
    const int r0 = c0 >> 2, kc0 = (c0 & 3) << 3;
    const size_t rstep = (size_t)16 * K;
    const u16* gAh = Ah + (m0 + r0) * K + kc0;
    const u16* gAl = Al + (m0 + r0) * K + kc0;
    const u16* gBh = Bh + (n0 + r0) * K + kc0;
    const u16* gBl = Bl + (n0 + r0) * K + kc0;
    const int lo0 = c0 * 8;

    const int frow = lane & 15, fk = (lane >> 4) << 3;
    const int offA = (wr * 64 + frow) * 32 + fk;
    const int offB = (wc * 64 + frow) * 32 + fk;

    f32x4 acc[4][4] = {};

    for (int k0 = 0; k0 < K; k0 += 32) {
        load_lds16(gAh + k0, &ls[0][lo0]);
        load_lds16(gAh + rstep + k0, &ls[0][lo0 + 512]);
        load_lds16(gAl + k0, &ls[1][lo0]);
        load_lds16(gAl + rstep + k0, &ls[1][lo0 + 512]);
        load_lds16(gBh + k0, &ls[2][lo0]);
        load_lds16(gBh + rstep + k0, &ls[2][lo0 + 512]);
        load_lds16(gBl + k0, &ls[3][lo0]);
        load_lds16(gBl + rstep + k0, &ls[3][lo0 + 512]);
        __syncthreads();

        bf16x8 fAh[4], fAl[4], fBh[4], fBl[4];
#pragma unroll
        for (int m = 0; m < 4; ++m) {
            fAh[m] = *reinterpret_cast<const bf16x8*>(&ls[0][offA + m * 512]);
            fAl[m] = *reinterpret_cast<const bf16x8*>(&ls[1][offA + m * 512]);
        }
#pragma unroll
        for (int n = 0; n < 4; ++n) {
            fBh[n] = *reinterpret_cast<const bf16x8*>(&ls[2][offB + n * 512]);
            fBl[n] = *reinterpret_cast<const bf16x8*>(&ls[3][offB + n * 512]);
        }
#pragma unroll
        for (int m = 0; m < 4; ++m)
#pragma unroll
            for (int n = 0; n < 4; ++n) {
                MFMA3(acc[m][n], fAh[m], fAl[m], fBh[n], fBl[n]);
            }
        __syncthreads();
    }

    const int crow0 = wr * 64 + ((lane >> 4) << 2);
    const int ccol0 = wc * 64 + (lane & 15);
#pragma unroll
    for (int n = 0; n < 4; ++n) {
        const size_t col = n0 + ccol0 + n * 16;
        const float bv = bias ? bias[col] : 0.f;
#pragma unroll
        for (int m = 0; m < 4; ++m)
#pragma unroll
            for (int r = 0; r < 4; ++r)
                C[(m0 + crow0 + m * 16 + r) * (size_t)ldc + col] = acc[m][n][r] + bv;
    }
}

// ---------------- head GEMM (R14/R15, proven): 128x256 tile, B f32 + split in-kernel ----------------
__global__ __launch_bounds__(256, 2) void k_gemm_n2f(
    const u16* __restrict__ Ah, const u16* __restrict__ Al,
    const float* __restrict__ Bf,
    const float* __restrict__ bias, float* __restrict__ C,
    int ldc, int K)
{
    __shared__ u16 lsA[2][128 * 32];
    __shared__ u16 lsBh[256 * 32];
    __shared__ u16 lsBl[256 * 32];
    const int tid = threadIdx.x;
    const int lane = tid & 63, w = tid >> 6;
    const int wr = w >> 1, wc = w & 1;
    const size_t m0 = (size_t)blockIdx.x * 128, n0 = (size_t)blockIdx.y * 256;

    const int frow = lane & 15, fk = (lane >> 4) << 3;
    const int offA = (wr * 64 + frow) * 32 + fk;
    const int offB = (wc * 128 + frow) * 32 + fk;

    f32x4 acc[4][8] = {};

    for (int k0 = 0; k0 < K; k0 += 32) {
#pragma unroll
        for (int q = 0; q < 4; ++q) {
            const int chunk = (w + q * 4) * 64 + lane;
            const int local = chunk & 511;
            const u16* A = (chunk < 512) ? Ah : Al;
            load_lds16(A + (m0 + (local >> 2)) * K + k0 + ((local & 3) << 3),
                       &lsA[chunk >> 9][local * 8]);
        }
#pragma unroll
        for (int q = 0; q < 4; ++q) {
            const int c = tid + q * 256;
            const int row = c >> 2, k8 = (c & 3) << 3;
            const float* src = Bf + (size_t)(n0 + row) * K + k0 + k8;
            float4 v0 = *reinterpret_cast<const float4*>(src);
            float4 v1 = *reinterpret_cast<const float4*>(src + 4);
            union { ushort4 s[2]; bf16x8 v; } hh, ll;
            splitf(v0.x, hh.s[0].x, ll.s[0].x); splitf(v0.y, hh.s[0].y, ll.s[0].y);
            splitf(v0.z, hh.s[0].z, ll.s[0].z); splitf(v0.w, hh.s[0].w, ll.s[0].w);
            splitf(v1.x, hh.s[1].x, ll.s[1].x); splitf(v1.y, hh.s[1].y, ll.s[1].y);
            splitf(v1.z, hh.s[1].z, ll.s[1].z); splitf(v1.w, hh.s[1].w, ll.s[1].w);
            *reinterpret_cast<bf16x8*>(&lsBh[row * 32 + k8]) = hh.v;
            *reinterpret_cast<bf16x8*>(&lsBl[row * 32 + k8]) = ll.v;
        }
        __syncthreads();

        bf16x8 fAh[4], fAl[4];
#pragma unroll
        for (int m = 0; m < 4; ++m) {
            fAh[m] = *reinterpret_cast<const bf16x8*>(&lsA[0][offA + m * 512]);
            fAl[m] = *reinterpret_cast<const bf16x8*>(&lsA[1][offA + m * 512]);
        }
#pragma unroll
        for (int n = 0; n < 8; ++n) {
            bf16x8 fBh = *reinterpret_cast<const bf16x8*>(&lsBh[offB + n * 512]);
            bf16x8 fBl = *reinterpret_cast<const bf16x8*>(&lsBl[offB + n * 512]);
#pragma unroll
            for (int m = 0; m < 4; ++m) {
                MFMA3(acc[m][n], fAh[m], fAl[m], fBh, fBl);
            }
        }
        __syncthreads();
    }

    const int crow0 = wr * 64 + ((lane >> 4) << 2);
    const int ccol0 = wc * 128 + (lane & 15);
#pragma unroll
    for (int n = 0; n < 8; ++n) {
        const size_t col = n0 + ccol0 + n * 16;
        const float bv = bias ? bias[col] : 0.f;
#pragma unroll
        for (int m = 0; m < 4; ++m)
#pragma unroll
            for (int r = 0; r < 4; ++r)
                C[(m0 + crow0 + m * 16 + r) * (size_t)ldc + col] = acc[m][n][r] + bv;
    }
}

// ================= persistent encoder + side-prep blocks (R17) =================
// grid 256: blk<128 = encoder (R16 body, direction-local barriers, unchanged);
// blk>=128 = 128 side blocks grid-striding the decoder-side prep, then exit.
__global__ __launch_bounds__(256) void k_enc_persist(
    const u16* __restrict__ whhf_h, const u16* __restrict__ whhf_l,
    const u16* __restrict__ whhb_h, const u16* __restrict__ whhb_l,
    const float* __restrict__ gi_f, const float* __restrict__ gi_b,
    const float* __restrict__ bhh_f, const float* __restrict__ bhh_b,
    u16* __restrict__ hfH0, u16* __restrict__ hfL0,
    u16* __restrict__ hfH1, u16* __restrict__ hfL1,
    u16* __restrict__ hbH0, u16* __restrict__ hbL0,
    u16* __restrict__ hbH1, u16* __restrict__ hbL1,
    float* __restrict__ enc_f, float* __restrict__ enc_b,
    int* __restrict__ cnt, int* __restrict__ flag,
    // side-prep inputs/outputs:
    const int* __restrict__ src, const int* __restrict__ trg,
    const float* __restrict__ emb, const float* __restrict__ Wih_d,
    const float* __restrict__ Wa, const float* __restrict__ Whh_d,
    u16* __restrict__ demb_h, u16* __restrict__ demb_l,
    u16* __restrict__ wihd_h, u16* __restrict__ wihd_l,
    u16* __restrict__ wae_h,  u16* __restrict__ wae_l,
    u16* __restrict__ wahp,   u16* __restrict__ walp,
    u16* __restrict__ wghp,   u16* __restrict__ wglp,
    u16* __restrict__ wdhp,   u16* __restrict__ wdlp)
{
    __shared__ __align__(16) char smem[145792];
    u16* lAh  = (u16*)smem;                    // [32][1024] staged h hi, XOR-swizzled
    u16* lAl  = (u16*)(smem + 65536);          // lo
    float* ex0 = (float*)(smem + 131072);      // [48][33] k-half 0
    float* ex1 = (float*)(smem + 137408);      // [48][33] k-half 1
    float* hloc = (float*)(smem + 143744);     // [32][16] f32 state

    const int blk = blockIdx.x, tid = threadIdx.x;

    if (blk >= 128) {
        // ---------- side-prep: 6 independent tasks, outputs consumed by later launches ----------
        const int gt = (blk - 128) * 256 + tid;
        const int NT = 128 * 256;
        // 1) dec-embed split: 2048 rows x 128 f4 (E=512)
        for (int it = gt; it < 2048 * 128; it += NT) {
            int row = it >> 7, c = (it & 127) << 2;
            int tt = row >> 5, b = row & 31;
            int tok = (tt == 0) ? src[(S_ - 1) * B_ + b] : trg[(tt - 1) * B_ + b];
            float4 v = *(const float4*)(emb + (size_t)tok * E_ + c);
            ushort4 h, l;
            splitf(v.x, h.x, l.x); splitf(v.y, h.y, l.y);
            splitf(v.z, h.z, l.z); splitf(v.w, h.w, l.w);
            *(ushort4*)(demb_h + (size_t)row * E_ + c) = h;
            *(ushort4*)(demb_l + (size_t)row * E_ + c) = l;
        }
        // 2) wihd (emb part) split: 3072 rows x 128 f4 (ld=EH)
        for (int it = gt; it < 3072 * 128; it += NT) {
            int row = it >> 7, c = (it & 127) << 2;
            float4 v = *(const float4*)(Wih_d + (size_t)row * EH + c);
            ushort4 h, l;
            splitf(v.x, h.x, l.x); splitf(v.y, h.y, l.y);
            splitf(v.z, h.z, l.z); splitf(v.w, h.w, l.w);
            *(ushort4*)(wihd_h + (size_t)row * E_ + c) = h;
            *(ushort4*)(wihd_l + (size_t)row * E_ + c) = l;
        }
        // 3) wae split (Wa enc part): 1024 rows x 256 f4 (ld=H2)
        for (int it = gt; it < 1024 * 256; it += NT) {
            int row = it >> 8, c = (it & 255) << 2;
            float4 v = *(const float4*)(Wa + (size_t)row * H2 + H_ + c);
            ushort4 h, l;
            splitf(v.x, h.x, l.x); splitf(v.y, h.y, l.y);
            splitf(v.z, h.z, l.z); splitf(v.w, h.w, l.w);
            *(ushort4*)(wae_h + (size_t)row * H_ + c) = h;
            *(ushort4*)(wae_l + (size_t)row * H_ + c) = l;
        }
        // 4) wah split (Wa h part): 1024 rows x 256 f4
        for (int it = gt; it < 1024 * 256; it += NT) {
            int row = it >> 8, c = (it & 255) << 2;
            float4 v = *(const float4*)(Wa + (size_t)row * H2 + c);
            ushort4 h, l;
            splitf(v.x, h.x, l.x); splitf(v.y, h.y, l.y);
            splitf(v.z, h.z, l.z); splitf(v.w, h.w, l.w);
            *(ushort4*)(wahp + (size_t)row * H_ + c) = h;
            *(ushort4*)(walp + (size_t)row * H_ + c) = l;
        }
        // 5) wgh perm split (Whh_d, ld=H_): row 3i+g <- g*1024+i
        for (int it = gt; it < 3072 * 256; it += NT) {
            int row = it >> 8, c = (it & 255) << 2;
            int i = row / 3, g = row - i * 3;
            float4 v = *(const float4*)(Whh_d + (size_t)(g * H_ + i) * H_ + c);
            ushort4 h, l;
            splitf(v.x, h.x, l.x); splitf(v.y, h.y, l.y);
            splitf(v.z, h.z, l.z); splitf(v.w, h.w, l.w);
            *(ushort4*)(wghp + (size_t)row * H_ + c) = h;
            *(ushort4*)(wglp + (size_t)row * H_ + c) = l;
        }
        // 6) wdh perm split (Wih_d ctx part, ld=EH, coff=E_)
        for (int it = gt; it < 3072 * 256; it += NT) {
            int row = it >> 8, c = (it & 255) << 2;
            int i = row / 3, g = row - i * 3;
            float4 v = *(const float4*)(Wih_d + (size_t)(g * H_ + i) * EH + E_ + c);
            ushort4 h, l;
            splitf(v.x, h.x, l.x); splitf(v.y, h.y, l.y);
            splitf(v.z, h.z, l.z); splitf(v.w, h.w, l.w);
            *(ushort4*)(wdhp + (size_t)row * H_ + c) = h;
            *(ushort4*)(wdlp + (size_t)row * H_ + c) = l;
        }
        return;
    }

    const int lane = tid & 63, w = tid >> 6;
    const int dir = blk >> 6, c = blk & 63;
    const int i0 = c * 16;
    const u16* WH = (dir ? whhb_h : whhf_h) + (size_t)c * 48 * 1024;
    const u16* WL = (dir ? whhb_l : whhf_l) + (size_t)c * 48 * 1024;
    const float* gi = dir ? gi_b : gi_f;
    const float* bhh = dir ? bhh_b : bhh_f;
    float* encd = dir ? enc_b : enc_f;
    int* cntd  = cnt + dir * 256;
    int* flagd = flag + dir * 256;
    int gen = 0;

    for (int q = tid; q < 512; q += 256) hloc[q] = 0.f;

    const int frow = lane & 15, fk8 = (lane >> 4) << 3;
    const int cb = lane & 15, rb0 = (lane >> 4) << 2;

    for (int t = 0; t < 64; ++t) {
        const int a = t & 1;
        const u16* rH = dir ? (a ? hbH1 : hbH0) : (a ? hfH1 : hfH0);
        const u16* rL = dir ? (a ? hbL1 : hbL0) : (a ? hfL1 : hfL0);
        u16* oH = dir ? (a ? hbH0 : hbH1) : (a ? hfH0 : hfH1);
        u16* oL = dir ? (a ? hbL0 : hbL1) : (a ? hfL0 : hfL1);
        const int s = dir ? 63 - t : t;

#pragma unroll
        for (int ch0 = 0; ch0 < 4096; ch0 += 256) {
            int ch = ch0 + tid;
            int r = ch >> 7, kc = (ch & 127) << 3;
            int sw = kc ^ ((r & 7) << 3);
            *(bf16x8*)&lAh[r * 1024 + sw] = ld_sys16(&rH[r * 1024 + kc]);
            *(bf16x8*)&lAl[r * 1024 + sw] = ld_sys16(&rL[r * 1024 + kc]);
        }
        __syncthreads();

#pragma unroll
        for (int jj = 0; jj < 3; ++jj) {
            const int j = w * 3 + jj;
            const int m = j & 1;
            const int n = (j >> 1) % 3;
            const int kh = j / 6;
            const int arow = m * 16 + frow;
            const int asw = (arow & 7) << 3;
            const u16* gBh = WH + (size_t)(n * 16 + frow) * 1024;
            const u16* gBl = WL + (size_t)(n * 16 + frow) * 1024;
            f32x4 acc = {};
            const int ke = kh * 512 + 512;
#pragma unroll 4
            for (int k0 = kh * 512; k0 < ke; k0 += 32) {
                int kc = k0 + fk8;
                bf16x8 aH = *(const bf16x8*)&lAh[arow * 1024 + (kc ^ asw)];
                bf16x8 aL = *(const bf16x8*)&lAl[arow * 1024 + (kc ^ asw)];
                bf16x8 bH = *(const bf16x8*)&gBh[kc];
                bf16x8 bL = *(const bf16x8*)&gBl[kc];
                MFMA3(acc, aH, aL, bH, bL);
            }
            float* exd = kh ? ex1 : ex0;
            const int pc = n * 16 + cb;
#pragma unroll
            for (int r = 0; r < 4; ++r)
                exd[pc * 33 + m * 16 + rb0 + r] = acc[r];
        }
        __syncthreads();

        {
            const int il = tid & 15, bb = tid >> 4;
            const int i = i0 + il;
#pragma unroll
            for (int q = 0; q < 2; ++q) {
                int b = bb + q * 16;
                float ghr = ex0[(3 * il + 0) * 33 + b] + ex1[(3 * il + 0) * 33 + b] + bhh[i];
                float ghz = ex0[(3 * il + 1) * 33 + b] + ex1[(3 * il + 1) * 33 + b] + bhh[H_ + i];
                float ghn = ex0[(3 * il + 2) * 33 + b] + ex1[(3 * il + 2) * 33 + b] + bhh[2 * H_ + i];
                size_t gio = (size_t)(s * B_ + b) * H3 + i;
                float gir = gi[gio], giz = gi[gio + H_], gin = gi[gio + 2 * H_];
                float rr = 1.f / (1.f + expf(-(gir + ghr)));
                float zz = 1.f / (1.f + expf(-(giz + ghz)));
                float nn = tanhf(gin + rr * ghn);
                float hold = hloc[b * 16 + il];
                float hnew = (1.f - zz) * nn + zz * hold;
                hloc[b * 16 + il] = hnew;
                u16 hh, hl; splitf(hnew, hh, hl);
                st_sysu16(&oH[b * 1024 + i], hh);
                st_sysu16(&oL[b * 1024 + i], hl);
                encd[((size_t)b * 64 + s) * H_ + i] = hnew;
            }
        }
        gbar(cntd, flagd, 64, c, gen);
    }
}

// ================= persistent decoder (R16 body; R17: writes st_h/st_l directly) =================
__global__ __launch_bounds__(256) void k_dec_persist(
    const u16* __restrict__ wah, const u16* __restrict__ wal,
    const u16* __restrict__ wgh, const u16* __restrict__ wgl,
    const u16* __restrict__ wdh, const u16* __restrict__ wdl,
    const float* __restrict__ gi_e, const float* __restrict__ bhh_d,
    const float* __restrict__ ep, const float* __restrict__ vvec,
    const float* __restrict__ enc,
    u16* __restrict__ hH, u16* __restrict__ hL,
    float* __restrict__ hwa, float* __restrict__ scores,
    u16* __restrict__ ctxH, u16* __restrict__ ctxL,
    u16* __restrict__ st_h, u16* __restrict__ st_l,
    int* __restrict__ cnt, int* __restrict__ flag, int* __restrict__ grpc)
{
    __shared__ __align__(16) char smem[140288];
    u16* lWH  = (u16*)smem;                    // [16][1024] rows 0-3 hWa, 4-15 ghd (swizzled)
    u16* lWL  = (u16*)(smem + 32768);
    u16* lDH  = (u16*)(smem + 65536);          // [16][1024] wdc hi (12 + 4 pad)
    float* lenc = (float*)(smem + 98304);      // [64][128]
    float* ex1a = (float*)(smem + 131072);     // [32][16] PhA partial (k-half 0)
    float* ex1b = (float*)(smem + 133120);
    float* ex2a = (float*)(smem + 135168);     // PhD partials
    float* ex2b = (float*)(smem + 137216);
    float* aw   = (float*)(smem + 139264);     // [64]
    float* hloc = (float*)(smem + 139520);     // [128] f32 state for owned (b,u)

    const int bid = blockIdx.x, tid = threadIdx.x;
    const int lane = tid & 63, w = tid >> 6;
    const int frow = lane & 15, fk8 = (lane >> 4) << 3;
    const int b3 = bid >> 3, sl = bid & 7;
    int gen = 0, genG = 0;

    for (int ch = tid; ch < 2048; ch += 256) {
        int r = ch >> 7, kc = (ch & 127) << 3;
        int sw = kc ^ ((r & 7) << 3);
        const u16 *sH, *sL;
        if (r < 4) { sH = wah + ((size_t)bid * 4 + r) * 1024;
                     sL = wal + ((size_t)bid * 4 + r) * 1024; }
        else       { sH = wgh + ((size_t)bid * 12 + r - 4) * 1024;
                     sL = wgl + ((size_t)bid * 12 + r - 4) * 1024; }
        *(bf16x8*)&lWH[r * 1024 + sw] = *(const bf16x8*)&sH[kc];
        *(bf16x8*)&lWL[r * 1024 + sw] = *(const bf16x8*)&sL[kc];
    }
    for (int ch = tid; ch < 2048; ch += 256) {
        int r = ch >> 7, kc = (ch & 127) << 3;
        int sw = kc ^ ((r & 7) << 3);
        int rowg = (r < 12) ? bid * 12 + r : bid * 12;
        *(bf16x8*)&lDH[r * 1024 + sw] = *(const bf16x8*)&wdh[(size_t)rowg * 1024 + kc];
    }
    for (int ch = tid; ch < 2048; ch += 256) {
        int s = ch >> 5, c4 = (ch & 31) << 2;
        *(float4*)&lenc[s * 128 + c4] =
            *(const float4*)&enc[((size_t)b3 * 64 + s) * 1024 + sl * 128 + c4];
    }
    if (tid < 128) {
        int b = tid >> 2, u = bid * 4 + (tid & 3);
        hloc[tid] = bf2f(hH[b * 1024 + u]) + bf2f(hL[b * 1024 + u]);
    }
    float vreg[16];
#pragma unroll
    for (int i = 0; i < 16; ++i) vreg[i] = vvec[lane + i * 64];
    __syncthreads();

    const int mt = w & 1, kh = w >> 1;
    const int bsw = (frow & 7) << 3;
    const int rowg = (frow < 12) ? bid * 12 + frow : bid * 12;
    const u16* gDl = wdl + (size_t)rowg * 1024;
    const int exw = (mt * 16 + ((lane >> 4) << 2)) * 16 + frow;
    const float* epr0 = ep + ((size_t)b3 * 64 + sl * 8 + w * 2) * 1024;
    const float* epr1 = epr0 + 1024;

    for (int t = 0; t < 64; ++t) {
        // ---- PhA (+ overlapped ep prefetch for PhB) ----
        float pe0[16], pe1[16];
#pragma unroll
        for (int i = 0; i < 16; ++i) pe0[i] = epr0[lane + i * 64];
#pragma unroll
        for (int i = 0; i < 16; ++i) pe1[i] = epr1[lane + i * 64];
        {
            float* exA = kh ? ex1b : ex1a;
            f32x4 acc = {};
            const int ar0 = (mt * 16 + frow) * 1024;
            const int ke = kh * 512 + 512;
#pragma unroll 4
            for (int k0 = kh * 512; k0 < ke; k0 += 32) {
                int kc = k0 + fk8;
                bf16x8 aH = ld_sys16(&hH[ar0 + kc]);
                bf16x8 aL = ld_sys16(&hL[ar0 + kc]);
                bf16x8 bH = *(const bf16x8*)&lWH[frow * 1024 + (kc ^ bsw)];
                bf16x8 bL = *(const bf16x8*)&lWL[frow * 1024 + (kc ^ bsw)];
                MFMA3(acc, aH, aL, bH, bL);
            }
#pragma unroll
            for (int r = 0; r < 4; ++r) exA[exw + r * 16] = acc[r];
        }
        __syncthreads();
        if (tid < 128) {
            int b = tid >> 2, col = tid & 3;
            st_sysf(&hwa[b * 1024 + bid * 4 + col],
                    ex1a[b * 16 + col] + ex1b[b * 16 + col]);
        }
        gbar(cnt, flag, 256, bid, gen);      // BAR1 (global): hwa all-to-all

        // ---- PhB (hwa hoisted; ep from prefetched registers) ----
        {
            float hreg[16];
#pragma unroll
            for (int i = 0; i < 16; ++i)
                hreg[i] = ld_sysf(&hwa[b3 * 1024 + lane + i * 64]);
            float a2 = 0.f, a3 = 0.f;
#pragma unroll
            for (int i = 0; i < 16; ++i) {
                a2 += fmaxf(hreg[i] + pe0[i], 0.f) * vreg[i];
                a3 += fmaxf(hreg[i] + pe1[i], 0.f) * vreg[i];
            }
            for (int off = 32; off; off >>= 1) a2 += __shfl_down(a2, off);
            for (int off = 32; off; off >>= 1) a3 += __shfl_down(a3, off);
            if (lane == 0) {
                st_sysf(&scores[b3 * 64 + sl * 8 + w * 2], a2);
                st_sysf(&scores[b3 * 64 + sl * 8 + w * 2 + 1], a3);
            }
        }
        gbar_grp(grpc, b3, 8, genG);         // BAR2 (group): scores group-internal

        // ---- PhC ----
        if (tid < 64) {
            float sc = ld_sysf(&scores[b3 * 64 + tid]);
            float m = sc;
            for (int off = 32; off; off >>= 1) m = fmaxf(m, __shfl_xor(m, off));
            float e = expf(sc - m);
            float sum = e;
            for (int off = 32; off; off >>= 1) sum += __shfl_xor(sum, off);
            aw[tid] = e / sum;
        }
        __syncthreads();
        if (tid < 128) {
            int c = tid;
            float x = 0.f;
#pragma unroll 8
            for (int s = 0; s < 64; ++s) x += aw[s] * lenc[s * 128 + c];
            u16 hh, hl; splitf(x, hh, hl);
            size_t so = ((size_t)t * 32 + b3) * 2048 + 1024 + sl * 128 + c;
            st_h[so] = hh; st_l[so] = hl;                 // head A-operand (plain)
            st_sysu16(&ctxH[b3 * 1024 + sl * 128 + c], hh);
            st_sysu16(&ctxL[b3 * 1024 + sl * 128 + c], hl);
        }
        gbar_grp(grpc, b3, 8, genG);         // BAR3 (group): ctx group-internal

        // ---- PhD ----
        {
            float* exD = kh ? ex2b : ex2a;
            f32x4 acc = {};
            const int ar0 = (mt * 16 + frow) * 1024;
            const int ke = kh * 512 + 512;
#pragma unroll 4
            for (int k0 = kh * 512; k0 < ke; k0 += 32) {
                int kc = k0 + fk8;
                bf16x8 aH = ld_sys16(&ctxH[ar0 + kc]);
                bf16x8 aL = ld_sys16(&ctxL[ar0 + kc]);
                bf16x8 bH = *(const bf16x8*)&lDH[frow * 1024 + (kc ^ bsw)];
                bf16x8 bL = *(const bf16x8*)&gDl[kc];
                MFMA3(acc, aH, aL, bH, bL);
            }
#pragma unroll
            for (int r = 0; r < 4; ++r) exD[exw + r * 16] = acc[r];
        }
        __syncthreads();
        if (tid < 128) {
            int b = tid >> 2, ui = tid & 3;
            int u = bid * 4 + ui;
            float gicr = ex2a[b * 16 + 3 * ui + 0] + ex2b[b * 16 + 3 * ui + 0];
            float gicz = ex2a[b * 16 + 3 * ui + 1] + ex2b[b * 16 + 3 * ui + 1];
            float gicn = ex2a[b * 16 + 3 * ui + 2] + ex2b[b * 16 + 3 * ui + 2];
            float ghr = ex1a[b * 16 + 4 + 3 * ui + 0] + ex1b[b * 16 + 4 + 3 * ui + 0] + bhh_d[u];
            float ghz = ex1a[b * 16 + 4 + 3 * ui + 1] + ex1b[b * 16 + 4 + 3 * ui + 1] + bhh_d[H_ + u];
            float ghn = ex1a[b * 16 + 4 + 3 * ui + 2] + ex1b[b * 16 + 4 + 3 * ui + 2] + bhh_d[2 * H_ + u];
            size_t ge = ((size_t)t * 32 + b) * 3072;
            float gir = gi_e[ge + u] + gicr;
            float giz = gi_e[ge + 1024 + u] + gicz;
            float gin = gi_e[ge + 2048 + u] + gicn;
            float rr = 1.f / (1.f + expf(-(gir + ghr)));
            float zz = 1.f / (1.f + expf(-(giz + ghz)));
            float nn = tanhf(gin + rr * ghn);
            float hold = hloc[tid];
            float hnew = (1.f - zz) * nn + zz * hold;
            hloc[tid] = hnew;
            u16 hh, hl; splitf(hnew, hh, hl);
            st_sysu16(&hH[b * 1024 + u], hh);
            st_sysu16(&hL[b * 1024 + u], hl);
            size_t so = ((size_t)t * 32 + b) * 2048 + u;
            st_h[so] = hh; st_l[so] = hl;                 // head A-operand (plain)
        }
        gbar(cnt, flag, 256, bid, gen);      // BAR4 (global): h all-to-all
    }
}

extern "C" void kernel_launch(void* const* d_in, const int* in_sizes, int n_in,
                              void* d_out, int out_size, void* d_ws, size_t ws_size,
                              hipStream_t stream) {
    const int*   src   = (const int*)d_in[0];
    const int*   trg   = (const int*)d_in[1];
    const float* emb   = (const float*)d_in[2];
    const float* Wih_f = (const float*)d_in[3];
    const float* Whh_f = (const float*)d_in[4];
    const float* bih_f = (const float*)d_in[5];
    const float* bhh_f = (const float*)d_in[6];
    const float* Wih_b = (const float*)d_in[7];
    const float* Whh_b = (const float*)d_in[8];
    const float* bih_b = (const float*)d_in[9];
    const float* bhh_b = (const float*)d_in[10];
    const float* Wa    = (const float*)d_in[11];
    const float* ba    = (const float*)d_in[12];
    const float* vv    = (const float*)d_in[13];
    const float* Wih_d = (const float*)d_in[14];
    const float* Whh_d = (const float*)d_in[15];
    const float* bih_d = (const float*)d_in[16];
    const float* bhh_d = (const float*)d_in[17];
    const float* Wout  = (const float*)d_in[18];
    const float* bout  = (const float*)d_in[19];
    float* out = (float*)d_out;
    (void)in_sizes; (void)n_in; (void)out_size; (void)ws_size;

    float* w = (float*)d_ws;
    size_t o = 0;
    auto alloc = [&](size_t n) { float* p = w + o; o += n; return p; };
    float* gi_f  = alloc((size_t)S_ * B_ * H3);      // encoder fwd gi; reused as gi_e
    float* gi_b  = alloc((size_t)S_ * B_ * H3);
    float* enc_f = alloc((size_t)B_ * S_ * H_);
    float* enc_b = alloc((size_t)B_ * S_ * H_);
    float* enc   = alloc((size_t)B_ * S_ * H_);
    float* ep    = alloc((size_t)B_ * S_ * H_);
    float* hwa   = alloc((size_t)B_ * H_);
    float* scores = alloc(B_ * S_);
    float* barf  = alloc(4096);
    int* cntE  = (int*)barf;          // 16 lines (8 per direction)
    int* flagE = cntE + 512;
    int* cntD  = cntE + 1024;
    int* flagD = cntE + 1280;
    int* grpD  = cntE + 1536;
    float* gi_e   = gi_f;

    u16* wu = (u16*)(w + o);
    size_t ou = 0;
    auto alloc16 = [&](size_t n) { u16* p = wu + ou; ou += n; return p; };
    u16* semb_h  = alloc16((size_t)S_ * B_ * E_);  u16* semb_l  = alloc16((size_t)S_ * B_ * E_);
    u16* demb_h  = alloc16((size_t)T_ * B_ * E_);  u16* demb_l  = alloc16((size_t)T_ * B_ * E_);
    u16* wihf_h  = alloc16((size_t)H3 * E_);       u16* wihf_l  = alloc16((size_t)H3 * E_);
    u16* wihb_h  = alloc16((size_t)H3 * E_);       u16* wihb_l  = alloc16((size_t)H3 * E_);
    u16* wihd_h  = alloc16((size_t)H3 * E_);       u16* wihd_l  = alloc16((size_t)H3 * E_);
    u16* wae_h   = alloc16((size_t)H_ * H_);       u16* wae_l   = alloc16((size_t)H_ * H_);
    u16* enc_h   = alloc16((size_t)B_ * S_ * H_);  u16* enc_l   = alloc16((size_t)B_ * S_ * H_);
    u16* st_h    = alloc16((size_t)T_ * B_ * H2);  u16* st_l    = alloc16((size_t)T_ * B_ * H2);
    u16* whhf_h  = alloc16((size_t)H3 * H_);       u16* whhf_l  = alloc16((size_t)H3 * H_);
    u16* whhb_h  = alloc16((size_t)H3 * H_);       u16* whhb_l  = alloc16((size_t)H3 * H_);
    u16* wgh     = alloc16((size_t)H3 * H_);       u16* wgl     = alloc16((size_t)H3 * H_);   // Whh_d perm
    u16* wdh     = alloc16((size_t)H3 * H_);       u16* wdl     = alloc16((size_t)H3 * H_);   // Wihd ctx perm
    u16* wah     = alloc16((size_t)H_ * H_);       u16* wal     = alloc16((size_t)H_ * H_);   // Wa h-part
    u16* hsf_h[2] = {alloc16(B_ * H_), alloc16(B_ * H_)};
    u16* hsf_l[2] = {alloc16(B_ * H_), alloc16(B_ * H_)};
    u16* hsb_h[2] = {alloc16(B_ * H_), alloc16(B_ * H_)};
    u16* hsb_l[2] = {alloc16(B_ * H_), alloc16(B_ * H_)};
    u16* ctx_h   = alloc16(B_ * H_);               u16* ctx_l   = alloc16(B_ * H_);

    // ---- init ----
    hipMemsetAsync(barf, 0, 4096 * sizeof(float), stream);
    hipMemsetAsync(hsf_h[0], 0, B_ * H_ * sizeof(u16), stream);
    hipMemsetAsync(hsf_l[0], 0, B_ * H_ * sizeof(u16), stream);
    hipMemsetAsync(hsb_h[0], 0, B_ * H_ * sizeof(u16), stream);
    hipMemsetAsync(hsb_l[0], 0, B_ * H_ * sizeof(u16), stream);

    // ---- encoder-side prep (must precede encoder) ----
    k_embed_src_split<<<S_ * B_, 128, 0, stream>>>(src, emb, semb_h, semb_l);
    k_split<<<dim3(1, H3), 256, 0, stream>>>(Wih_f, E_, E_ / 4, wihf_h, wihf_l);
    k_split<<<dim3(1, H3), 256, 0, stream>>>(Wih_b, E_, E_ / 4, wihb_h, wihb_l);
    k_wsplit_perm<<<H3, 256, 0, stream>>>(Whh_f, H_, 0, whhf_h, whhf_l);
    k_wsplit_perm<<<H3, 256, 0, stream>>>(Whh_b, H_, 0, whhb_h, whhb_l);
    k_gemm_mfma3<<<dim3(16, 24), 256, 0, stream>>>(semb_h, semb_l, wihf_h, wihf_l,
                                                   bih_f, gi_f, H3, E_);
    k_gemm_mfma3<<<dim3(16, 24), 256, 0, stream>>>(semb_h, semb_l, wihb_h, wihb_l,
                                                   bih_b, gi_b, H3, E_);

    // ---- encoder (128 blocks) + decoder-side prep (128 side blocks), one launch ----
    k_enc_persist<<<256, 256, 0, stream>>>(
        whhf_h, whhf_l, whhb_h, whhb_l, gi_f, gi_b, bhh_f, bhh_b,
        hsf_h[0], hsf_l[0], hsf_h[1], hsf_l[1],
        hsb_h[0], hsb_l[0], hsb_h[1], hsb_l[1],
        enc_f, enc_b, cntE, flagE,
        src, trg, emb, Wih_d, Wa, Whh_d,
        demb_h, demb_l, wihd_h, wihd_l, wae_h, wae_l,
        wah, wal, wgh, wgl, wdh, wdl);

    // ---- merge enc dirs + split; ep precompute; decoder emb projection ----
    k_split_sum_enc<<<dim3(1, B_ * S_), 256, 0, stream>>>(enc_f, enc_b, enc, enc_h, enc_l);
    k_gemm_mfma3<<<dim3(16, 8), 256, 0, stream>>>(enc_h, enc_l, wae_h, wae_l,
                                                  ba, ep, H_, H_);
    k_gemm_mfma3<<<dim3(16, 24), 256, 0, stream>>>(demb_h, demb_l, wihd_h, wihd_l,
                                                   bih_d, gi_e, H3, E_);

    // ---- decoder: persistent, 2 global + 2 group barriers/step; writes st_h/st_l ----
    k_dec_persist<<<256, 256, 0, stream>>>(
        wah, wal, wgh, wgl, wdh, wdl, gi_e, bhh_d, ep, vv, enc,
        hsf_h[0], hsf_l[0], hwa, scores, ctx_h, ctx_l, st_h, st_l,
        cntD, flagD, grpD);

    // ---- output head: single launch over full vocab ----
    k_gemm_n2f<<<dim3(16, 125), 256, 0, stream>>>(st_h, st_l, Wout, bout, out, V_, H2);
}